// Round 4
// baseline (1304.530 us; speedup 1.0000x reference)
//
#include <hip/hip_runtime.h>

// GWNet on MI355X — round 4.
// - P = exp(relu(Z Z^T) - 48) materialized ONCE in bf16 (134 MB, L3-resident),
//   column sums fused into the same kernel; both layers' attention become pure
//   bf16 MFMA GEMMs (no exp/cvt in loop). Guarded by ws_size with fallback to
//   the round-3 fused k_attn2 path.
// - GEMM LDS tiles stored chunk-major [c][row]: frag ds_read_b128 lands on
//   8 distinct banks (2-way max = free), staging stays linear-dest gload_lds.
// - spmm vectorized to float4 gathers; k_cheb fuses (-Y + A.Y + 2A(A.Y)) accum.

#define NN 8192
#define NNZE 131072
#define CSHIFT 48.0f

typedef float4 f4;
typedef __attribute__((ext_vector_type(8))) short bf16x8;
typedef __attribute__((ext_vector_type(4))) float f32x4;

typedef __attribute__((address_space(3))) short lds_short;
typedef __attribute__((address_space(1))) const short glb_short;

__device__ inline short f2b(float x){
  unsigned u = __float_as_uint(x);
  unsigned r = (u + 0x7fffu + ((u >> 16) & 1u)) >> 16;
  return (short)r;
}
__device__ inline float b2f(unsigned short b){
  return __uint_as_float(((unsigned)b) << 16);
}

// ---------------- CSR build ----------------
__global__ __launch_bounds__(256) void k_count(const int* __restrict__ idx, int* __restrict__ cnt){
  int e = blockIdx.x*256 + threadIdx.x;
  if (e < NNZE) atomicAdd(&cnt[idx[e]], 1);
}

__global__ __launch_bounds__(1024) void k_scan(const int* __restrict__ cnt, int* __restrict__ ptr){
  __shared__ int sums[1024];
  int t = threadIdx.x;
  int loc[8]; int s = 0;
  #pragma unroll
  for (int i=0;i<8;i++){ loc[i]=s; s += cnt[t*8+i]; }
  sums[t]=s; __syncthreads();
  for (int off=1; off<1024; off<<=1){
    int v = (t>=off) ? sums[t-off] : 0;
    __syncthreads();
    sums[t] += v;
    __syncthreads();
  }
  int excl = sums[t]-s;
  #pragma unroll
  for (int i=0;i<8;i++) ptr[t*8+i] = excl + loc[i];
  if (t==1023) ptr[NN] = sums[1023];
}

__global__ __launch_bounds__(256) void k_fill(const int* __restrict__ idx, const float* __restrict__ vals,
                                              int* __restrict__ cur, int* __restrict__ cidx, float* __restrict__ cval){
  int e = blockIdx.x*256 + threadIdx.x;
  if (e < NNZE){
    int r = idx[e], c = idx[NNZE+e];
    int p = atomicAdd(&cur[r], 1);
    cidx[p] = c; cval[p] = vals[e];
  }
}

// ---------------- transpose X (R, NN) -> (NN, R) ----------------
template<int R>
__global__ __launch_bounds__(256) void k_transpose(const float* __restrict__ src, float* __restrict__ dst){
  __shared__ float tile[32][33];
  int tx = threadIdx.x & 31, ty = threadIdx.x >> 5;
  int j0 = blockIdx.x*32, f0 = blockIdx.y*32;
  #pragma unroll
  for (int u=0;u<32;u+=8) tile[ty+u][tx] = src[(size_t)(f0+ty+u)*NN + j0+tx];
  __syncthreads();
  #pragma unroll
  for (int u=0;u<32;u+=8) dst[(size_t)(j0+ty+u)*R + f0+tx] = tile[tx][ty+u];
}

// ---------------- Z -> bf16 ----------------
__global__ __launch_bounds__(256) void k_zb(const float* __restrict__ Z, short* __restrict__ Zb){
  int i = blockIdx.x*256 + threadIdx.x;
  Zb[i] = f2b(Z[i]);
}

// ---------------- P build: Psm[i][j] = exp(relu(zi.zj)-C) bf16, + column sums ----------------
// 128x128 tile per block, 512 threads = 8 waves (wave w: rows w*16..+16).
__global__ __launch_bounds__(512) void k_pexp(const short* __restrict__ Zb,
                                              short* __restrict__ Psm, float* __restrict__ sb){
  __shared__ short tile[128*136];   // pitch 136 shorts = 272 B (16B-multiple)
  int t = threadIdx.x;
  int w = t >> 6, l = t & 63;
  int lo = l & 15, g = l >> 4;
  int i0 = blockIdx.x*128, j0 = blockIdx.y*128;
  const bf16x8* Zb8 = (const bf16x8*)Zb;
  int zirow = i0 + w*16 + lo;
  bf16x8 a0 = Zb8[(size_t)zirow*8 + g];
  bf16x8 a1 = Zb8[(size_t)zirow*8 + g + 4];
  #pragma unroll
  for (int jg=0; jg<8; jg++){
    int j = j0 + jg*16 + lo;
    bf16x8 b0 = Zb8[(size_t)j*8 + g];
    bf16x8 b1 = Zb8[(size_t)j*8 + g + 4];
    f32x4 s = (f32x4){0.f,0.f,0.f,0.f};
    s = __builtin_amdgcn_mfma_f32_16x16x32_bf16(a0, b0, s, 0,0,0);
    s = __builtin_amdgcn_mfma_f32_16x16x32_bf16(a1, b1, s, 0,0,0);
    int irow = w*16 + g*4;
    #pragma unroll
    for (int r=0;r<4;r++)
      tile[(irow+r)*136 + jg*16 + lo] = f2b(__expf(fmaxf(s[r],0.f) - CSHIFT));
  }
  __syncthreads();
  // column sums from the bf16 tile (consistent with what GEMM will consume)
  {
    int col = t & 127, seg = t >> 7;   // 4 segs x 32 rows
    float sm = 0.f;
    #pragma unroll 8
    for (int r=seg*32; r<seg*32+32; r++) sm += b2f((unsigned short)tile[r*136 + col]);
    atomicAdd(&sb[j0 + col], sm);
  }
  // coalesced store: 128 rows x 256 B
  #pragma unroll
  for (int u=0; u<4; u++){
    int cc = u*512 + t;
    int row = cc >> 4, c8 = cc & 15;
    *(f4*)(Psm + (size_t)(i0+row)*NN + j0 + c8*8) = *(const f4*)&tile[row*136 + c8*8];
  }
}

// ---------------- fallback column sums via MFMA (round-3, no P materialization) ----------------
__global__ __launch_bounds__(512) void k_colsum_mfma(const short* __restrict__ Zb, float* __restrict__ sb){
  int t = threadIdx.x;
  int w = t >> 6, l = t & 63;
  int lo = l & 15, g = l >> 4;
  int j = blockIdx.x*128 + w*16 + lo;
  const bf16x8* Zb8 = (const bf16x8*)Zb;
  bf16x8 bj0 = Zb8[j*8 + g];
  bf16x8 bj1 = Zb8[j*8 + g + 4];
  int i0 = blockIdx.y * (NN/8);
  float sum = 0.f;
  for (int i = i0; i < i0 + NN/8; i += 16){
    bf16x8 a0 = Zb8[(size_t)(i+lo)*8 + g];
    bf16x8 a1 = Zb8[(size_t)(i+lo)*8 + g + 4];
    f32x4 s = (f32x4){0.f,0.f,0.f,0.f};
    s = __builtin_amdgcn_mfma_f32_16x16x32_bf16(a0, bj0, s, 0,0,0);
    s = __builtin_amdgcn_mfma_f32_16x16x32_bf16(a1, bj1, s, 0,0,0);
    #pragma unroll
    for (int r=0;r<4;r++) sum += __expf(fmaxf(s[r],0.f) - CSHIFT);
  }
  sum += __shfl_xor(sum, 16);
  sum += __shfl_xor(sum, 32);
  if (g == 0) atomicAdd(sb + j, sum);
}

__global__ __launch_bounds__(256) void k_recip(float* s){
  int i = blockIdx.x*256 + threadIdx.x;
  if (i < NN) s[i] = 1.0f/s[i];
}

// ---------------- spmm (float4 gather): out = A . in ----------------
template<int F>
__global__ __launch_bounds__(256) void k_spmm4(const int* __restrict__ ptr, const int* __restrict__ cidx,
                                               const float* __restrict__ cval, const float* __restrict__ in,
                                               float* __restrict__ out){
  int t = threadIdx.x;
  int r, ts;
  if (F == 1024){ r = blockIdx.x; ts = t; }
  else          { r = blockIdx.x*2 + (t>>7); ts = t & 127; }
  const f4* in4 = (const f4*)in;
  int p0 = ptr[r], p1 = ptr[r+1];
  f4 a = {0,0,0,0};
  for (int p=p0; p<p1; p++){
    int c = cidx[p]; float v = cval[p];
    f4 x = in4[(size_t)c*(F/4) + ts];
    a.x += v*x.x; a.y += v*x.y; a.z += v*x.z; a.w += v*x.w;
  }
  ((f4*)out)[(size_t)r*(F/4) + ts] = a;
}

// ---------------- cheb epilogue: T (=/+=) TMP + 2*A.TMP (+ -Y if FIRST) ----------------
template<int F, bool FIRST>
__global__ __launch_bounds__(256) void k_cheb(const int* __restrict__ ptr, const int* __restrict__ cidx,
                                              const float* __restrict__ cval, const float* __restrict__ tmp,
                                              const float* __restrict__ y, float* __restrict__ T){
  int t = threadIdx.x;
  int r, ts;
  if (F == 1024){ r = blockIdx.x; ts = t; }
  else          { r = blockIdx.x*2 + (t>>7); ts = t & 127; }
  const f4* tmp4 = (const f4*)tmp;
  int p0 = ptr[r], p1 = ptr[r+1];
  f4 a = {0,0,0,0};
  for (int p=p0; p<p1; p++){
    int c = cidx[p]; float v = cval[p];
    f4 x = tmp4[(size_t)c*(F/4) + ts];
    a.x += v*x.x; a.y += v*x.y; a.z += v*x.z; a.w += v*x.w;
  }
  size_t o = (size_t)r*(F/4) + ts;
  f4 tm = tmp4[o];
  f4 res;
  if (FIRST){
    f4 yv = ((const f4*)y)[o];
    res.x = tm.x + 2.f*a.x - yv.x; res.y = tm.y + 2.f*a.y - yv.y;
    res.z = tm.z + 2.f*a.z - yv.z; res.w = tm.w + 2.f*a.w - yv.w;
  } else {
    f4 tv = ((f4*)T)[o];
    res.x = tv.x + tm.x + 2.f*a.x; res.y = tv.y + tm.y + 2.f*a.y;
    res.z = tv.z + tm.z + 2.f*a.z; res.w = tv.w + tm.w + 2.f*a.w;
  }
  ((f4*)T)[o] = res;
}

// ---------------- Y -> Yt: transpose, scale by sinv[k], cvt bf16. Yt[n][k] ----------------
template<int F>
__global__ __launch_bounds__(256) void k_downt(const float* __restrict__ Y, const float* __restrict__ sinv,
                                               short* __restrict__ Yt){
  __shared__ float tile[32][33];
  int tx = threadIdx.x & 31, ty = threadIdx.x >> 5;
  int k0 = blockIdx.x*32, n0 = blockIdx.y*32;
  #pragma unroll
  for (int u=0;u<32;u+=8) tile[ty+u][tx] = Y[(size_t)(k0+ty+u)*F + n0+tx];
  __syncthreads();
  float sv = sinv[k0+tx];
  #pragma unroll
  for (int u=0;u<32;u+=8) Yt[(size_t)(n0+ty+u)*NN + k0+tx] = f2b(tile[tx][ty+u] * sv);
}

// ---------------- pure GEMM: out (+)= P @ Ys   (P[m][k] bf16, Ys as Yt[n][k] bf16) ----------------
// BM=128, BN=256, BK=32, 512 threads = 8 waves (2M x 4N). Chunk-major LDS tiles:
// aL[c][row] (c=0..3 chunks of 8 shorts), bL[c][nrow] — frag b128 reads conflict-free.
template<int F>
__global__ __launch_bounds__(512, 4) void k_gemm(
    const short* __restrict__ Psm,  // [NN][NN] bf16
    const short* __restrict__ Ytg,  // [F][NN]  bf16 (pre-scaled by sinv)
    float* __restrict__ T0,
    float* __restrict__ P1, float* __restrict__ P2, float* __restrict__ P3,
    int ksize)
{
  __shared__ __align__(16) short aL[2][128*32];   // 8 KB each
  __shared__ __align__(16) short bL[2][256*32];   // 16 KB each
  int t = threadIdx.x;
  int w = t >> 6, l = t & 63;
  int lo = l & 15, g = l >> 4;
  int m0 = blockIdx.x * 128;
  int n0 = blockIdx.y * 256;
  int kz = blockIdx.z;
  int kbeg = kz * ksize, kend = kbeg + ksize;
  int wm = w >> 2, wn = w & 3;

  f32x4 acc[4][4];
  #pragma unroll
  for (int i=0;i<4;i++)
    #pragma unroll
    for (int j=0;j<4;j++) acc[i][j] = (f32x4){0.f,0.f,0.f,0.f};

  auto STAGE = [&](int b, int kk){
    // A: 512 chunks = [c=t>>7][row=t&127]
    {
      const short* src = Psm + (size_t)(m0 + (t & 127))*NN + kk + ((t >> 7) << 3);
      __builtin_amdgcn_global_load_lds((glb_short*)src, (lds_short*)&aL[b][t*8], 16, 0, 0);
    }
    // B: 1024 chunks = [c=cc>>8][row=cc&255]
    #pragma unroll
    for (int p=0;p<2;p++){
      int cc = p*512 + t;
      const short* src = Ytg + (size_t)(n0 + (cc & 255))*NN + kk + ((cc >> 8) << 3);
      __builtin_amdgcn_global_load_lds((glb_short*)src, (lds_short*)&bL[b][cc*8], 16, 0, 0);
    }
  };

  STAGE(0, kbeg);
  __syncthreads();

  int cur = 0;
  for (int k0 = kbeg; k0 < kend; k0 += 32){
    bf16x8 aP[4], bY[4];
    #pragma unroll
    for (int mf=0; mf<4; mf++){
      int row = wm*64 + mf*16 + lo;
      aP[mf] = *(const bf16x8*)&aL[cur][(g*128 + row)*8];
    }
    #pragma unroll
    for (int nf=0; nf<4; nf++){
      int nl = wn*64 + nf*16 + lo;
      bY[nf] = *(const bf16x8*)&bL[cur][(g*256 + nl)*8];
    }
    if (k0 + 32 < kend) STAGE(cur ^ 1, k0 + 32);
    #pragma unroll
    for (int nf=0; nf<4; nf++)
      #pragma unroll
      for (int mf=0; mf<4; mf++)
        acc[mf][nf] = __builtin_amdgcn_mfma_f32_16x16x32_bf16(aP[mf], bY[nf], acc[mf][nf], 0,0,0);
    __syncthreads();
    cur ^= 1;
  }
  float* outp = (kz==0) ? T0 : (kz==1 ? P1 : (kz==2 ? P2 : P3));
  #pragma unroll
  for (int mf=0; mf<4; mf++){
    int row = m0 + wm*64 + mf*16 + g*4;
    #pragma unroll
    for (int nf=0; nf<4; nf++){
      int col = n0 + wn*64 + nf*16 + lo;
      #pragma unroll
      for (int r=0;r<4;r++){
        size_t o = (size_t)(row+r)*F + col;
        if (kz==0) outp[o] += acc[mf][nf][r];
        else       outp[o]  = acc[mf][nf][r];
      }
    }
  }
}

// ---------------- fallback fused attention (round-3, proven) ----------------
template<int F>
__global__ __launch_bounds__(512, 4) void k_attn2(
    const short* __restrict__ Zb, const short* __restrict__ Ytg,
    float* __restrict__ T0,
    float* __restrict__ P1, float* __restrict__ P2, float* __restrict__ P3,
    int ksize)
{
  __shared__ __align__(16) short zk[2][32*64];
  __shared__ __align__(16) short yt[2][256*32];
  __shared__ __align__(16) short p_lds[128*40];
  int t = threadIdx.x;
  int w = t >> 6, l = t & 63;
  int lo = l & 15, g = l >> 4;
  int m0 = blockIdx.x * 128;
  int n0 = blockIdx.y * 256;
  int kz = blockIdx.z;
  int kbeg = kz * ksize, kend = kbeg + ksize;
  int wm = w >> 2, wn = w & 3;

  const bf16x8* Zb8 = (const bf16x8*)Zb;
  int zirow = m0 + w*16 + lo;
  bf16x8 ziA0 = Zb8[(size_t)zirow*8 + g];
  bf16x8 ziA1 = Zb8[(size_t)zirow*8 + g + 4];

  f32x4 acc[4][4];
  #pragma unroll
  for (int i=0;i<4;i++)
    #pragma unroll
    for (int j=0;j<4;j++) acc[i][j] = (f32x4){0.f,0.f,0.f,0.f};

  auto STAGE = [&](int b, int kk){
    if (t < 256){
      int r = t >> 3, c = t & 7;
      const short* src = Zb + (((size_t)(kk + r)) << 6) + ((c ^ (r & 7)) << 3);
      __builtin_amdgcn_global_load_lds((glb_short*)src, (lds_short*)&zk[b][t*8], 16, 0, 0);
    }
    #pragma unroll
    for (int p=0;p<2;p++){
      int cc = p*512 + t;
      int r = cc >> 2, c = cc & 3;
      const short* src = Ytg + (size_t)(n0 + r)*NN + kk + ((c ^ (r & 3)) << 3);
      __builtin_amdgcn_global_load_lds((glb_short*)src, (lds_short*)&yt[b][cc*8], 16, 0, 0);
    }
  };

  STAGE(0, kbeg);
  __syncthreads();

  int cur = 0;
  for (int k0 = kbeg; k0 < kend; k0 += 32){
    int xa = g ^ (lo & 7), xb = (g + 4) ^ (lo & 7);
    bf16x8 b00 = *(const bf16x8*)&zk[cur][(lo*8 + xa)*8];
    bf16x8 b01 = *(const bf16x8*)&zk[cur][(lo*8 + xb)*8];
    bf16x8 b10 = *(const bf16x8*)&zk[cur][((16+lo)*8 + xa)*8];
    bf16x8 b11 = *(const bf16x8*)&zk[cur][((16+lo)*8 + xb)*8];
    f32x4 s0 = (f32x4){0.f,0.f,0.f,0.f};
    f32x4 s1 = (f32x4){0.f,0.f,0.f,0.f};
    s0 = __builtin_amdgcn_mfma_f32_16x16x32_bf16(ziA0, b00, s0, 0,0,0);
    s0 = __builtin_amdgcn_mfma_f32_16x16x32_bf16(ziA1, b01, s0, 0,0,0);
    s1 = __builtin_amdgcn_mfma_f32_16x16x32_bf16(ziA0, b10, s1, 0,0,0);
    s1 = __builtin_amdgcn_mfma_f32_16x16x32_bf16(ziA1, b11, s1, 0,0,0);
    short e0[4], e1[4];
    #pragma unroll
    for (int r=0;r<4;r++){
      e0[r] = f2b(__expf(fmaxf(s0[r],0.f) - CSHIFT));
      e1[r] = f2b(__expf(fmaxf(s1[r],0.f) - CSHIFT));
    }
    __syncthreads();
    if (k0 + 32 < kend) STAGE(cur ^ 1, k0 + 32);
    int prow = w*16 + g*4;
    #pragma unroll
    for (int r=0;r<4;r++){
      p_lds[(prow+r)*40 + lo]      = e0[r];
      p_lds[(prow+r)*40 + 16 + lo] = e1[r];
    }
    __syncthreads();
    bf16x8 aP[4];
    #pragma unroll
    for (int mf=0; mf<4; mf++)
      aP[mf] = *(const bf16x8*)&p_lds[(wm*64 + mf*16 + lo)*40 + g*8];
    #pragma unroll
    for (int nf=0; nf<4; nf++){
      int nl = wn*64 + nf*16 + lo;
      bf16x8 bY = *(const bf16x8*)&yt[cur][(nl*4 + (g ^ (nl & 3)))*8];
      #pragma unroll
      for (int mf=0; mf<4; mf++)
        acc[mf][nf] = __builtin_amdgcn_mfma_f32_16x16x32_bf16(aP[mf], bY, acc[mf][nf], 0,0,0);
    }
    cur ^= 1;
  }
  float* outp = (kz==0) ? T0 : (kz==1 ? P1 : (kz==2 ? P2 : P3));
  #pragma unroll
  for (int mf=0; mf<4; mf++){
    int row = m0 + wm*64 + mf*16 + g*4;
    #pragma unroll
    for (int nf=0; nf<4; nf++){
      int col = n0 + wn*64 + nf*16 + lo;
      #pragma unroll
      for (int r=0;r<4;r++){
        size_t o = (size_t)(row+r)*F + col;
        if (kz==0) outp[o] += acc[mf][nf][r];
        else       outp[o]  = acc[mf][nf][r];
      }
    }
  }
}

// ---------------- partial merges ----------------
__global__ __launch_bounds__(256) void k_acc1(const f4* __restrict__ a, f4* __restrict__ o, int n4){
  for (int i = blockIdx.x*256 + threadIdx.x; i < n4; i += gridDim.x*256){
    f4 x=a[i], r=o[i];
    r.x+=x.x; r.y+=x.y; r.z+=x.z; r.w+=x.w;
    o[i]=r;
  }
}
__global__ __launch_bounds__(256) void k_acc3(const f4* __restrict__ a, const f4* __restrict__ b,
                                              const f4* __restrict__ c, f4* __restrict__ o, int n4){
  for (int i = blockIdx.x*256 + threadIdx.x; i < n4; i += gridDim.x*256){
    f4 x=a[i], y=b[i], z=c[i], r=o[i];
    r.x+=x.x+y.x+z.x; r.y+=x.y+y.y+z.y; r.z+=x.z+y.z+z.z; r.w+=x.w+y.w+z.w;
    o[i]=r;
  }
}

// ---------------- head GEMM ----------------
template<int DIN, int FIN>
__global__ __launch_bounds__(256) void k_head(const float* __restrict__ T, const float* __restrict__ W,
                                              float* __restrict__ Hout){
  __shared__ float tt[16*DIN];
  int t = threadIdx.x;
  int j0 = blockIdx.x*16, b = blockIdx.y;
  const f4* T4 = (const f4*)T;
  for (int u=t; u<16*DIN/4; u+=256){
    int jj = u / (DIN/4), kq = u % (DIN/4);
    ((f4*)tt)[u] = T4[((size_t)(j0+jj)*FIN + b*DIN)/4 + kq];
  }
  __syncthreads();
  int oq = t & 31, jg = t >> 5;
  f4 a0 = {0,0,0,0}, a1 = {0,0,0,0};
  const f4* W4 = (const f4*)W;
  for (int k=0;k<DIN;k++){
    f4 wv = W4[k*32 + oq];
    float t0 = tt[(jg*2+0)*DIN + k];
    float t1 = tt[(jg*2+1)*DIN + k];
    a0.x += t0*wv.x; a0.y += t0*wv.y; a0.z += t0*wv.z; a0.w += t0*wv.w;
    a1.x += t1*wv.x; a1.y += t1*wv.y; a1.z += t1*wv.z; a1.w += t1*wv.w;
  }
  a0.x=fmaxf(a0.x,0.f); a0.y=fmaxf(a0.y,0.f); a0.z=fmaxf(a0.z,0.f); a0.w=fmaxf(a0.w,0.f);
  a1.x=fmaxf(a1.x,0.f); a1.y=fmaxf(a1.y,0.f); a1.z=fmaxf(a1.z,0.f); a1.w=fmaxf(a1.w,0.f);
  f4* H4 = (f4*)Hout;
  H4[(size_t)(j0+jg*2+0)*256 + b*32 + oq] = a0;
  H4[(size_t)(j0+jg*2+1)*256 + b*32 + oq] = a1;
}

// ---------------- final mean over nodes ----------------
__global__ __launch_bounds__(256) void k_reduce(const float* __restrict__ A, float* __restrict__ out){
  __shared__ float accl[1024];
  int t = threadIdx.x;
  for (int u=t; u<1024; u+=256) accl[u]=0.f;
  __syncthreads();
  int j0 = blockIdx.x*128;
  for (int j=j0; j<j0+128; j++){
    for (int u=t; u<1024; u+=256) accl[u] += A[(size_t)j*1024 + u];
  }
  __syncthreads();
  for (int u=t; u<1024; u+=256) atomicAdd(&out[u], accl[u]*(1.f/8192.f));
}

// ---------------- launcher ----------------
extern "C" void kernel_launch(void* const* d_in, const int* in_sizes, int n_in,
                              void* d_out, int out_size, void* d_ws, size_t ws_size,
                              hipStream_t stream){
  const int*   A1i = (const int*)d_in[0];
  const float* A1v = (const float*)d_in[1];
  const int*   A2i = (const int*)d_in[2];
  const float* A2v = (const float*)d_in[3];
  const float* X   = (const float*)d_in[4];
  const float* Z   = (const float*)d_in[5];
  const float* W1  = (const float*)d_in[6];
  const float* W2  = (const float*)d_in[7];
  float* out = (float*)d_out;

  char* w = (char*)d_ws;
  size_t off = 0;
  auto alloc = [&](size_t b)->char* {
    char* p = w + off;
    off += (b + 1023) & ~(size_t)1023;
    return p;
  };
  float* sb    = (float*)alloc(NN*4);
  int*   ptr1  = (int*)  alloc((NN+1)*4);
  int*   ptr2  = (int*)  alloc((NN+1)*4);
  int*   cnt   = (int*)  alloc(NN*4);
  int*   cidx1 = (int*)  alloc(NNZE*4);
  float* cval1 = (float*)alloc(NNZE*4);
  int*   cidx2 = (int*)  alloc(NNZE*4);
  float* cval2 = (float*)alloc(NNZE*4);
  short* Zbf   = (short*)alloc((size_t)NN*64*2);
  float* XT1   = (float*)alloc((size_t)NN*512*4);
  float* T1    = (float*)alloc((size_t)NN*512*4);    // adjacent to XT1
  float* HT    = (float*)alloc((size_t)NN*1024*4);
  float* TMP   = (float*)alloc((size_t)NN*1024*4);
  size_t base_need = off;
  short* Psm   = (short*)alloc((size_t)NN*NN*2);     // 134 MB (P path only)
  bool   bigws = (off <= ws_size);

  float* T2   = XT1;            // layer-2 T overlays XT1+T1 (32 MB contiguous)
  short* Ysbt = (short*)TMP;    // Yt bf16 at TMP base
  float* P1a  = HT;             // layer1 partials: HT dead until k_head
  float* P1b  = HT + (size_t)NN*512;
  float* P1c  = (float*)((char*)TMP + (size_t)NN*512*2);  // after 8MB Yt
  float* P2a  = HT;             // layer2 partial: HT dead after k_downt
  (void)base_need;

  // CSR for A1, A2
  hipMemsetAsync(cnt, 0, NN*4, stream);
  k_count<<<NNZE/256, 256, 0, stream>>>(A1i, cnt);
  k_scan<<<1, 1024, 0, stream>>>(cnt, ptr1);
  hipMemcpyAsync(cnt, ptr1, NN*4, hipMemcpyDeviceToDevice, stream);
  k_fill<<<NNZE/256, 256, 0, stream>>>(A1i, A1v, cnt, cidx1, cval1);

  hipMemsetAsync(cnt, 0, NN*4, stream);
  k_count<<<NNZE/256, 256, 0, stream>>>(A2i, cnt);
  k_scan<<<1, 1024, 0, stream>>>(cnt, ptr2);
  hipMemcpyAsync(cnt, ptr2, NN*4, hipMemcpyDeviceToDevice, stream);
  k_fill<<<NNZE/256, 256, 0, stream>>>(A2i, A2v, cnt, cidx2, cval2);

  // Xt (node-major), Z bf16
  k_transpose<512><<<dim3(NN/32, 512/32), 256, 0, stream>>>(X, XT1);
  k_zb<<<NN*64/256, 256, 0, stream>>>(Z, Zbf);

  hipMemsetAsync(sb, 0, NN*4, stream);
  if (bigws){
    k_pexp<<<dim3(NN/128, NN/128), 512, 0, stream>>>(Zbf, Psm, sb);   // P + column sums
  } else {
    k_colsum_mfma<<<dim3(NN/128, 8), 512, 0, stream>>>(Zbf, sb);
  }
  k_recip<<<NN/256, 256, 0, stream>>>(sb);

  // ---- layer 1 (F=512) ----
  k_spmm4<512><<<NN/2, 256, 0, stream>>>(ptr1, cidx1, cval1, XT1, TMP);
  k_cheb<512,true><<<NN/2, 256, 0, stream>>>(ptr1, cidx1, cval1, TMP, XT1, T1);
  k_spmm4<512><<<NN/2, 256, 0, stream>>>(ptr2, cidx2, cval2, XT1, TMP);
  k_cheb<512,false><<<NN/2, 256, 0, stream>>>(ptr2, cidx2, cval2, TMP, XT1, T1);
  k_downt<512><<<dim3(NN/32, 512/32), 256, 0, stream>>>(XT1, sb, Ysbt);
  if (bigws)
    k_gemm<512><<<dim3(NN/128, 2, 4), 512, 0, stream>>>(Psm, Ysbt, T1, P1a, P1b, P1c, NN/4);
  else
    k_attn2<512><<<dim3(NN/128, 2, 4), 512, 0, stream>>>(Zbf, Ysbt, T1, P1a, P1b, P1c, NN/4);
  k_acc3<<<1024, 256, 0, stream>>>((const f4*)P1a, (const f4*)P1b, (const f4*)P1c, (f4*)T1, NN*512/4);
  k_head<64,512><<<dim3(NN/16, 8), 256, 0, stream>>>(T1, W1, HT);

  // ---- layer 2 (F=1024), T2 overlays XT1/T1 ----
  k_spmm4<1024><<<NN, 256, 0, stream>>>(ptr1, cidx1, cval1, HT, TMP);
  k_cheb<1024,true><<<NN, 256, 0, stream>>>(ptr1, cidx1, cval1, TMP, HT, T2);
  k_spmm4<1024><<<NN, 256, 0, stream>>>(ptr2, cidx2, cval2, HT, TMP);
  k_cheb<1024,false><<<NN, 256, 0, stream>>>(ptr2, cidx2, cval2, TMP, HT, T2);
  k_downt<1024><<<dim3(NN/32, 1024/32), 256, 0, stream>>>(HT, sb, Ysbt);   // HT now dead
  if (bigws)
    k_gemm<1024><<<dim3(NN/128, 4, 2), 512, 0, stream>>>(Psm, Ysbt, T2, P2a, P2a, P2a, NN/2);
  else
    k_attn2<1024><<<dim3(NN/128, 4, 2), 512, 0, stream>>>(Zbf, Ysbt, T2, P2a, P2a, P2a, NN/2);
  k_acc1<<<2048, 256, 0, stream>>>((const f4*)P2a, (f4*)T2, NN*1024/4);
  k_head<128,1024><<<dim3(NN/16, 8), 256, 0, stream>>>(T2, W2, HT);

  hipMemsetAsync(out, 0, 1024*4, stream);
  k_reduce<<<64, 256, 0, stream>>>(HT, out);
}

// Round 5
// 1133.822 us; speedup vs baseline: 1.1506x; 1.1506x over previous
//
#include <hip/hip_runtime.h>

// GWNet on MI355X — round 5.
// - Attention GEMMs: 256x256 tile, BK=32, 8 waves, 32 MFMA/thread/K-step
//   (128 B staged per wave-MFMA, 1.5x round-4 intensity), 2-phase loop.
// - Chebyshev spmm chain in bf16 (halved gather bytes) with 2-deep edge
//   unroll; outputs stay f32. Final mean over 8192 nodes averages the
//   independent bf16 rounding noise away.
// - P = exp(relu(Z Z^T)-48) bf16 materialized once (ws-guarded w/ fallback).

#define NN 8192
#define NNZE 131072
#define CSHIFT 48.0f

typedef float4 f4;
typedef __attribute__((ext_vector_type(8))) short bf16x8;
typedef __attribute__((ext_vector_type(4))) float f32x4;

typedef __attribute__((address_space(3))) short lds_short;
typedef __attribute__((address_space(1))) const short glb_short;

__device__ inline short f2b(float x){
  unsigned u = __float_as_uint(x);
  unsigned r = (u + 0x7fffu + ((u >> 16) & 1u)) >> 16;
  return (short)r;
}
__device__ inline float b2f(unsigned short b){
  return __uint_as_float(((unsigned)b) << 16);
}

// ---------------- CSR build ----------------
__global__ __launch_bounds__(256) void k_count(const int* __restrict__ idx, int* __restrict__ cnt){
  int e = blockIdx.x*256 + threadIdx.x;
  if (e < NNZE) atomicAdd(&cnt[idx[e]], 1);
}

__global__ __launch_bounds__(1024) void k_scan(const int* __restrict__ cnt, int* __restrict__ ptr){
  __shared__ int sums[1024];
  int t = threadIdx.x;
  int loc[8]; int s = 0;
  #pragma unroll
  for (int i=0;i<8;i++){ loc[i]=s; s += cnt[t*8+i]; }
  sums[t]=s; __syncthreads();
  for (int off=1; off<1024; off<<=1){
    int v = (t>=off) ? sums[t-off] : 0;
    __syncthreads();
    sums[t] += v;
    __syncthreads();
  }
  int excl = sums[t]-s;
  #pragma unroll
  for (int i=0;i<8;i++) ptr[t*8+i] = excl + loc[i];
  if (t==1023) ptr[NN] = sums[1023];
}

__global__ __launch_bounds__(256) void k_fill(const int* __restrict__ idx, const float* __restrict__ vals,
                                              int* __restrict__ cur, int* __restrict__ cidx, float* __restrict__ cval){
  int e = blockIdx.x*256 + threadIdx.x;
  if (e < NNZE){
    int r = idx[e], c = idx[NNZE+e];
    int p = atomicAdd(&cur[r], 1);
    cidx[p] = c; cval[p] = vals[e];
  }
}

// ---------------- transpose X (R, NN) -> (NN, R) ----------------
template<int R>
__global__ __launch_bounds__(256) void k_transpose(const float* __restrict__ src, float* __restrict__ dst){
  __shared__ float tile[32][33];
  int tx = threadIdx.x & 31, ty = threadIdx.x >> 5;
  int j0 = blockIdx.x*32, f0 = blockIdx.y*32;
  #pragma unroll
  for (int u=0;u<32;u+=8) tile[ty+u][tx] = src[(size_t)(f0+ty+u)*NN + j0+tx];
  __syncthreads();
  #pragma unroll
  for (int u=0;u<32;u+=8) dst[(size_t)(j0+ty+u)*R + f0+tx] = tile[tx][ty+u];
}

// ---------------- f32 -> bf16 stream ----------------
__global__ __launch_bounds__(256) void k_tobf(const float* __restrict__ src, short* __restrict__ dst, int n8){
  for (int i = blockIdx.x*256 + threadIdx.x; i < n8; i += gridDim.x*256){
    f4 x = ((const f4*)src)[2*i], y = ((const f4*)src)[2*i+1];
    bf16x8 o;
    o[0]=f2b(x.x); o[1]=f2b(x.y); o[2]=f2b(x.z); o[3]=f2b(x.w);
    o[4]=f2b(y.x); o[5]=f2b(y.y); o[6]=f2b(y.z); o[7]=f2b(y.w);
    ((bf16x8*)dst)[i] = o;
  }
}

// ---------------- Z -> bf16 ----------------
__global__ __launch_bounds__(256) void k_zb(const float* __restrict__ Z, short* __restrict__ Zb){
  int i = blockIdx.x*256 + threadIdx.x;
  Zb[i] = f2b(Z[i]);
}

// ---------------- P build: Psm[i][j] = exp(relu(zi.zj)-C) bf16, + column sums ----------------
__global__ __launch_bounds__(512) void k_pexp(const short* __restrict__ Zb,
                                              short* __restrict__ Psm, float* __restrict__ sb){
  __shared__ short tile[128*136];
  int t = threadIdx.x;
  int w = t >> 6, l = t & 63;
  int lo = l & 15, g = l >> 4;
  int i0 = blockIdx.x*128, j0 = blockIdx.y*128;
  const bf16x8* Zb8 = (const bf16x8*)Zb;
  int zirow = i0 + w*16 + lo;
  bf16x8 a0 = Zb8[(size_t)zirow*8 + g];
  bf16x8 a1 = Zb8[(size_t)zirow*8 + g + 4];
  #pragma unroll
  for (int jg=0; jg<8; jg++){
    int j = j0 + jg*16 + lo;
    bf16x8 b0 = Zb8[(size_t)j*8 + g];
    bf16x8 b1 = Zb8[(size_t)j*8 + g + 4];
    f32x4 s = (f32x4){0.f,0.f,0.f,0.f};
    s = __builtin_amdgcn_mfma_f32_16x16x32_bf16(a0, b0, s, 0,0,0);
    s = __builtin_amdgcn_mfma_f32_16x16x32_bf16(a1, b1, s, 0,0,0);
    int irow = w*16 + g*4;
    #pragma unroll
    for (int r=0;r<4;r++)
      tile[(irow+r)*136 + jg*16 + lo] = f2b(__expf(fmaxf(s[r],0.f) - CSHIFT));
  }
  __syncthreads();
  {
    int col = t & 127, seg = t >> 7;
    float sm = 0.f;
    #pragma unroll 8
    for (int r=seg*32; r<seg*32+32; r++) sm += b2f((unsigned short)tile[r*136 + col]);
    atomicAdd(&sb[j0 + col], sm);
  }
  #pragma unroll
  for (int u=0; u<4; u++){
    int cc = u*512 + t;
    int row = cc >> 4, c8 = cc & 15;
    *(f4*)(Psm + (size_t)(i0+row)*NN + j0 + c8*8) = *(const f4*)&tile[row*136 + c8*8];
  }
}

// ---------------- fallback column sums (no P materialization) ----------------
__global__ __launch_bounds__(512) void k_colsum_mfma(const short* __restrict__ Zb, float* __restrict__ sb){
  int t = threadIdx.x;
  int w = t >> 6, l = t & 63;
  int lo = l & 15, g = l >> 4;
  int j = blockIdx.x*128 + w*16 + lo;
  const bf16x8* Zb8 = (const bf16x8*)Zb;
  bf16x8 bj0 = Zb8[j*8 + g];
  bf16x8 bj1 = Zb8[j*8 + g + 4];
  int i0 = blockIdx.y * (NN/8);
  float sum = 0.f;
  for (int i = i0; i < i0 + NN/8; i += 16){
    bf16x8 a0 = Zb8[(size_t)(i+lo)*8 + g];
    bf16x8 a1 = Zb8[(size_t)(i+lo)*8 + g + 4];
    f32x4 s = (f32x4){0.f,0.f,0.f,0.f};
    s = __builtin_amdgcn_mfma_f32_16x16x32_bf16(a0, bj0, s, 0,0,0);
    s = __builtin_amdgcn_mfma_f32_16x16x32_bf16(a1, bj1, s, 0,0,0);
    #pragma unroll
    for (int r=0;r<4;r++) sum += __expf(fmaxf(s[r],0.f) - CSHIFT);
  }
  sum += __shfl_xor(sum, 16);
  sum += __shfl_xor(sum, 32);
  if (g == 0) atomicAdd(sb + j, sum);
}

__global__ __launch_bounds__(256) void k_recip(float* s){
  int i = blockIdx.x*256 + threadIdx.x;
  if (i < NN) s[i] = 1.0f/s[i];
}

// ---------------- bf16 spmm: outb[r][:] = bf16( sum_e v * Yb[c][:] ) ----------------
// 8 bf16 feats per lane; F=1024: 2 rows/block, F=512: 4 rows/block.
template<int F>
__global__ __launch_bounds__(256) void k_spmmb(const int* __restrict__ ptr, const int* __restrict__ cidx,
                                               const float* __restrict__ cval, const short* __restrict__ Yb,
                                               short* __restrict__ outb){
  constexpr int LPR = F/8;
  int t = threadIdx.x;
  int r = blockIdx.x*(256/LPR) + t/LPR;
  int ts = t % LPR;
  const bf16x8* Y8 = (const bf16x8*)Yb;
  int p0 = ptr[r], p1 = ptr[r+1];
  float a[8];
  #pragma unroll
  for (int j=0;j<8;j++) a[j]=0.f;
  int p = p0;
  for (; p+1 < p1; p += 2){
    int c0 = cidx[p],   c1 = cidx[p+1];
    float v0 = cval[p], v1 = cval[p+1];
    bf16x8 x0 = Y8[(size_t)c0*LPR + ts];
    bf16x8 x1 = Y8[(size_t)c1*LPR + ts];
    #pragma unroll
    for (int j=0;j<8;j++) a[j] += v0*b2f((unsigned short)x0[j]);
    #pragma unroll
    for (int j=0;j<8;j++) a[j] += v1*b2f((unsigned short)x1[j]);
  }
  if (p < p1){
    int c0 = cidx[p]; float v0 = cval[p];
    bf16x8 x0 = Y8[(size_t)c0*LPR + ts];
    #pragma unroll
    for (int j=0;j<8;j++) a[j] += v0*b2f((unsigned short)x0[j]);
  }
  bf16x8 o;
  #pragma unroll
  for (int j=0;j<8;j++) o[j] = f2b(a[j]);
  ((bf16x8*)outb)[(size_t)r*LPR + ts] = o;
}

// ---------------- cheb epilogue: T (=/+=) x1 + 2*A.x1 (+ -Y if FIRST), f32 out ----------------
template<int F, bool FIRST>
__global__ __launch_bounds__(256) void k_chebb(const int* __restrict__ ptr, const int* __restrict__ cidx,
                                               const float* __restrict__ cval, const short* __restrict__ X1b,
                                               const float* __restrict__ Yf, float* __restrict__ T){
  constexpr int LPR = F/8;
  int t = threadIdx.x;
  int r = blockIdx.x*(256/LPR) + t/LPR;
  int ts = t % LPR;
  const bf16x8* X8 = (const bf16x8*)X1b;
  int p0 = ptr[r], p1 = ptr[r+1];
  float a[8];
  #pragma unroll
  for (int j=0;j<8;j++) a[j]=0.f;
  int p = p0;
  for (; p+1 < p1; p += 2){
    int c0 = cidx[p],   c1 = cidx[p+1];
    float v0 = cval[p], v1 = cval[p+1];
    bf16x8 x0 = X8[(size_t)c0*LPR + ts];
    bf16x8 x1 = X8[(size_t)c1*LPR + ts];
    #pragma unroll
    for (int j=0;j<8;j++) a[j] += v0*b2f((unsigned short)x0[j]);
    #pragma unroll
    for (int j=0;j<8;j++) a[j] += v1*b2f((unsigned short)x1[j]);
  }
  if (p < p1){
    int c0 = cidx[p]; float v0 = cval[p];
    bf16x8 x0 = X8[(size_t)c0*LPR + ts];
    #pragma unroll
    for (int j=0;j<8;j++) a[j] += v0*b2f((unsigned short)x0[j]);
  }
  bf16x8 tm = X8[(size_t)r*LPR + ts];       // x1 self term
  size_t o4 = ((size_t)r*F + ts*8) >> 2;
  f4 r0, r1;
  if (FIRST){
    f4 y0 = ((const f4*)Yf)[o4], y1 = ((const f4*)Yf)[o4+1];
    r0.x = b2f((unsigned short)tm[0]) + 2.f*a[0] - y0.x;
    r0.y = b2f((unsigned short)tm[1]) + 2.f*a[1] - y0.y;
    r0.z = b2f((unsigned short)tm[2]) + 2.f*a[2] - y0.z;
    r0.w = b2f((unsigned short)tm[3]) + 2.f*a[3] - y0.w;
    r1.x = b2f((unsigned short)tm[4]) + 2.f*a[4] - y1.x;
    r1.y = b2f((unsigned short)tm[5]) + 2.f*a[5] - y1.y;
    r1.z = b2f((unsigned short)tm[6]) + 2.f*a[6] - y1.z;
    r1.w = b2f((unsigned short)tm[7]) + 2.f*a[7] - y1.w;
  } else {
    f4 t0 = ((const f4*)T)[o4], t1 = ((const f4*)T)[o4+1];
    r0.x = t0.x + b2f((unsigned short)tm[0]) + 2.f*a[0];
    r0.y = t0.y + b2f((unsigned short)tm[1]) + 2.f*a[1];
    r0.z = t0.z + b2f((unsigned short)tm[2]) + 2.f*a[2];
    r0.w = t0.w + b2f((unsigned short)tm[3]) + 2.f*a[3];
    r1.x = t1.x + b2f((unsigned short)tm[4]) + 2.f*a[4];
    r1.y = t1.y + b2f((unsigned short)tm[5]) + 2.f*a[5];
    r1.z = t1.z + b2f((unsigned short)tm[6]) + 2.f*a[6];
    r1.w = t1.w + b2f((unsigned short)tm[7]) + 2.f*a[7];
  }
  ((f4*)T)[o4]   = r0;
  ((f4*)T)[o4+1] = r1;
}

// ---------------- Y -> Yt: transpose, scale by sinv[k], cvt bf16. Yt[n][k] ----------------
template<int F>
__global__ __launch_bounds__(256) void k_downt(const float* __restrict__ Y, const float* __restrict__ sinv,
                                               short* __restrict__ Yt){
  __shared__ float tile[32][33];
  int tx = threadIdx.x & 31, ty = threadIdx.x >> 5;
  int k0 = blockIdx.x*32, n0 = blockIdx.y*32;
  #pragma unroll
  for (int u=0;u<32;u+=8) tile[ty+u][tx] = Y[(size_t)(k0+ty+u)*F + n0+tx];
  __syncthreads();
  float sv = sinv[k0+tx];
  #pragma unroll
  for (int u=0;u<32;u+=8) Yt[(size_t)(n0+ty+u)*NN + k0+tx] = f2b(tile[tx][ty+u] * sv);
}

// ---------------- 256x256 GEMM: out (+)= P @ Ys ----------------
// BM=BN=256, BK=32, 512 threads = 8 waves (2M x 4N), per-wave 128x64 out,
// 32 MFMA/thread/K-step vs 32 KB staged. Chunk-major LDS, 2-phase loop.
template<int F>
__global__ __launch_bounds__(512, 2) void k_gemm2(
    const short* __restrict__ Psm,  // [NN][NN] bf16
    const short* __restrict__ Ytg,  // [F][NN]  bf16 (pre-scaled by sinv)
    float* __restrict__ T0,
    float* __restrict__ P1, float* __restrict__ P2, float* __restrict__ P3,
    int ksize)
{
  __shared__ __align__(16) short aL[2][256*32];   // 16 KB each
  __shared__ __align__(16) short bL[2][256*32];   // 16 KB each
  int t = threadIdx.x;
  int w = t >> 6, l = t & 63;
  int lo = l & 15, g = l >> 4;
  int m0 = blockIdx.x * 256;
  int n0 = blockIdx.y * 256;
  int kz = blockIdx.z;
  int kbeg = kz * ksize, kend = kbeg + ksize;
  int wm = w >> 2, wn = w & 3;

  f32x4 acc[8][4];
  #pragma unroll
  for (int i=0;i<8;i++)
    #pragma unroll
    for (int j=0;j<4;j++) acc[i][j] = (f32x4){0.f,0.f,0.f,0.f};

  auto STAGE = [&](int b, int kk){
    #pragma unroll
    for (int p=0;p<2;p++){
      int cc = p*512 + t;
      int row = cc & 255, c = cc >> 8;
      const short* srcA = Psm + (size_t)(m0 + row)*NN + kk + (c << 3);
      __builtin_amdgcn_global_load_lds((glb_short*)srcA, (lds_short*)&aL[b][cc*8], 16, 0, 0);
      const short* srcB = Ytg + (size_t)(n0 + row)*NN + kk + (c << 3);
      __builtin_amdgcn_global_load_lds((glb_short*)srcB, (lds_short*)&bL[b][cc*8], 16, 0, 0);
    }
  };

  STAGE(0, kbeg);
  __syncthreads();

  int cur = 0;
  for (int k0 = kbeg; k0 < kend; k0 += 32){
    bf16x8 aP[8], bY[4];
    #pragma unroll
    for (int mf=0; mf<8; mf++)
      aP[mf] = *(const bf16x8*)&aL[cur][(g*256 + wm*128 + mf*16 + lo)*8];
    #pragma unroll
    for (int nf=0; nf<4; nf++)
      bY[nf] = *(const bf16x8*)&bL[cur][(g*256 + wn*64 + nf*16 + lo)*8];
    if (k0 + 32 < kend) STAGE(cur ^ 1, k0 + 32);
    __builtin_amdgcn_s_setprio(1);
    #pragma unroll
    for (int nf=0; nf<4; nf++)
      #pragma unroll
      for (int mf=0; mf<8; mf++)
        acc[mf][nf] = __builtin_amdgcn_mfma_f32_16x16x32_bf16(aP[mf], bY[nf], acc[mf][nf], 0,0,0);
    __builtin_amdgcn_s_setprio(0);
    __syncthreads();
    cur ^= 1;
  }
  float* outp = (kz==0) ? T0 : (kz==1 ? P1 : (kz==2 ? P2 : P3));
  #pragma unroll
  for (int mf=0; mf<8; mf++){
    int row = m0 + wm*128 + mf*16 + g*4;
    #pragma unroll
    for (int nf=0; nf<4; nf++){
      int col = n0 + wn*64 + nf*16 + lo;
      #pragma unroll
      for (int r=0;r<4;r++){
        size_t o = (size_t)(row+r)*F + col;
        if (kz==0) outp[o] += acc[mf][nf][r];
        else       outp[o]  = acc[mf][nf][r];
      }
    }
  }
}

// ---------------- fallback fused attention (round-3, proven) ----------------
template<int F>
__global__ __launch_bounds__(512, 4) void k_attn2(
    const short* __restrict__ Zb, const short* __restrict__ Ytg,
    float* __restrict__ T0,
    float* __restrict__ P1, float* __restrict__ P2, float* __restrict__ P3,
    int ksize)
{
  __shared__ __align__(16) short zk[2][32*64];
  __shared__ __align__(16) short yt[2][256*32];
  __shared__ __align__(16) short p_lds[128*40];
  int t = threadIdx.x;
  int w = t >> 6, l = t & 63;
  int lo = l & 15, g = l >> 4;
  int m0 = blockIdx.x * 128;
  int n0 = blockIdx.y * 256;
  int kz = blockIdx.z;
  int kbeg = kz * ksize, kend = kbeg + ksize;
  int wm = w >> 2, wn = w & 3;

  const bf16x8* Zb8 = (const bf16x8*)Zb;
  int zirow = m0 + w*16 + lo;
  bf16x8 ziA0 = Zb8[(size_t)zirow*8 + g];
  bf16x8 ziA1 = Zb8[(size_t)zirow*8 + g + 4];

  f32x4 acc[4][4];
  #pragma unroll
  for (int i=0;i<4;i++)
    #pragma unroll
    for (int j=0;j<4;j++) acc[i][j] = (f32x4){0.f,0.f,0.f,0.f};

  auto STAGE = [&](int b, int kk){
    if (t < 256){
      int r = t >> 3, c = t & 7;
      const short* src = Zb + (((size_t)(kk + r)) << 6) + ((c ^ (r & 7)) << 3);
      __builtin_amdgcn_global_load_lds((glb_short*)src, (lds_short*)&zk[b][t*8], 16, 0, 0);
    }
    #pragma unroll
    for (int p=0;p<2;p++){
      int cc = p*512 + t;
      int r = cc >> 2, c = cc & 3;
      const short* src = Ytg + (size_t)(n0 + r)*NN + kk + ((c ^ (r & 3)) << 3);
      __builtin_amdgcn_global_load_lds((glb_short*)src, (lds_short*)&yt[b][cc*8], 16, 0, 0);
    }
  };

  STAGE(0, kbeg);
  __syncthreads();

  int cur = 0;
  for (int k0 = kbeg; k0 < kend; k0 += 32){
    int xa = g ^ (lo & 7), xb = (g + 4) ^ (lo & 7);
    bf16x8 b00 = *(const bf16x8*)&zk[cur][(lo*8 + xa)*8];
    bf16x8 b01 = *(const bf16x8*)&zk[cur][(lo*8 + xb)*8];
    bf16x8 b10 = *(const bf16x8*)&zk[cur][((16+lo)*8 + xa)*8];
    bf16x8 b11 = *(const bf16x8*)&zk[cur][((16+lo)*8 + xb)*8];
    f32x4 s0 = (f32x4){0.f,0.f,0.f,0.f};
    f32x4 s1 = (f32x4){0.f,0.f,0.f,0.f};
    s0 = __builtin_amdgcn_mfma_f32_16x16x32_bf16(ziA0, b00, s0, 0,0,0);
    s0 = __builtin_amdgcn_mfma_f32_16x16x32_bf16(ziA1, b01, s0, 0,0,0);
    s1 = __builtin_amdgcn_mfma_f32_16x16x32_bf16(ziA0, b10, s1, 0,0,0);
    s1 = __builtin_amdgcn_mfma_f32_16x16x32_bf16(ziA1, b11, s1, 0,0,0);
    short e0[4], e1[4];
    #pragma unroll
    for (int r=0;r<4;r++){
      e0[r] = f2b(__expf(fmaxf(s0[r],0.f) - CSHIFT));
      e1[r] = f2b(__expf(fmaxf(s1[r],0.f) - CSHIFT));
    }
    __syncthreads();
    if (k0 + 32 < kend) STAGE(cur ^ 1, k0 + 32);
    int prow = w*16 + g*4;
    #pragma unroll
    for (int r=0;r<4;r++){
      p_lds[(prow+r)*40 + lo]      = e0[r];
      p_lds[(prow+r)*40 + 16 + lo] = e1[r];
    }
    __syncthreads();
    bf16x8 aP[4];
    #pragma unroll
    for (int mf=0; mf<4; mf++)
      aP[mf] = *(const bf16x8*)&p_lds[(wm*64 + mf*16 + lo)*40 + g*8];
    #pragma unroll
    for (int nf=0; nf<4; nf++){
      int nl = wn*64 + nf*16 + lo;
      bf16x8 bY = *(const bf16x8*)&yt[cur][(nl*4 + (g ^ (nl & 3)))*8];
      #pragma unroll
      for (int mf=0; mf<4; mf++)
        acc[mf][nf] = __builtin_amdgcn_mfma_f32_16x16x32_bf16(aP[mf], bY, acc[mf][nf], 0,0,0);
    }
    cur ^= 1;
  }
  float* outp = (kz==0) ? T0 : (kz==1 ? P1 : (kz==2 ? P2 : P3));
  #pragma unroll
  for (int mf=0; mf<4; mf++){
    int row = m0 + wm*64 + mf*16 + g*4;
    #pragma unroll
    for (int nf=0; nf<4; nf++){
      int col = n0 + wn*64 + nf*16 + lo;
      #pragma unroll
      for (int r=0;r<4;r++){
        size_t o = (size_t)(row+r)*F + col;
        if (kz==0) outp[o] += acc[mf][nf][r];
        else       outp[o]  = acc[mf][nf][r];
      }
    }
  }
}

// ---------------- partial merges ----------------
__global__ __launch_bounds__(256) void k_acc1(const f4* __restrict__ a, f4* __restrict__ o, int n4){
  for (int i = blockIdx.x*256 + threadIdx.x; i < n4; i += gridDim.x*256){
    f4 x=a[i], r=o[i];
    r.x+=x.x; r.y+=x.y; r.z+=x.z; r.w+=x.w;
    o[i]=r;
  }
}
__global__ __launch_bounds__(256) void k_acc3(const f4* __restrict__ a, const f4* __restrict__ b,
                                              const f4* __restrict__ c, f4* __restrict__ o, int n4){
  for (int i = blockIdx.x*256 + threadIdx.x; i < n4; i += gridDim.x*256){
    f4 x=a[i], y=b[i], z=c[i], r=o[i];
    r.x+=x.x+y.x+z.x; r.y+=x.y+y.y+z.y; r.z+=x.z+y.z+z.z; r.w+=x.w+y.w+z.w;
    o[i]=r;
  }
}

// ---------------- head GEMM ----------------
template<int DIN, int FIN>
__global__ __launch_bounds__(256) void k_head(const float* __restrict__ T, const float* __restrict__ W,
                                              float* __restrict__ Hout){
  __shared__ float tt[16*DIN];
  int t = threadIdx.x;
  int j0 = blockIdx.x*16, b = blockIdx.y;
  const f4* T4 = (const f4*)T;
  for (int u=t; u<16*DIN/4; u+=256){
    int jj = u / (DIN/4), kq = u % (DIN/4);
    ((f4*)tt)[u] = T4[((size_t)(j0+jj)*FIN + b*DIN)/4 + kq];
  }
  __syncthreads();
  int oq = t & 31, jg = t >> 5;
  f4 a0 = {0,0,0,0}, a1 = {0,0,0,0};
  const f4* W4 = (const f4*)W;
  for (int k=0;k<DIN;k++){
    f4 wv = W4[k*32 + oq];
    float t0 = tt[(jg*2+0)*DIN + k];
    float t1 = tt[(jg*2+1)*DIN + k];
    a0.x += t0*wv.x; a0.y += t0*wv.y; a0.z += t0*wv.z; a0.w += t0*wv.w;
    a1.x += t1*wv.x; a1.y += t1*wv.y; a1.z += t1*wv.z; a1.w += t1*wv.w;
  }
  a0.x=fmaxf(a0.x,0.f); a0.y=fmaxf(a0.y,0.f); a0.z=fmaxf(a0.z,0.f); a0.w=fmaxf(a0.w,0.f);
  a1.x=fmaxf(a1.x,0.f); a1.y=fmaxf(a1.y,0.f); a1.z=fmaxf(a1.z,0.f); a1.w=fmaxf(a1.w,0.f);
  f4* H4 = (f4*)Hout;
  H4[(size_t)(j0+jg*2+0)*256 + b*32 + oq] = a0;
  H4[(size_t)(j0+jg*2+1)*256 + b*32 + oq] = a1;
}

// ---------------- final mean over nodes ----------------
__global__ __launch_bounds__(256) void k_reduce(const float* __restrict__ A, float* __restrict__ out){
  __shared__ float accl[1024];
  int t = threadIdx.x;
  for (int u=t; u<1024; u+=256) accl[u]=0.f;
  __syncthreads();
  int j0 = blockIdx.x*128;
  for (int j=j0; j<j0+128; j++){
    for (int u=t; u<1024; u+=256) accl[u] += A[(size_t)j*1024 + u];
  }
  __syncthreads();
  for (int u=t; u<1024; u+=256) atomicAdd(&out[u], accl[u]*(1.f/8192.f));
}

// ---------------- launcher ----------------
extern "C" void kernel_launch(void* const* d_in, const int* in_sizes, int n_in,
                              void* d_out, int out_size, void* d_ws, size_t ws_size,
                              hipStream_t stream){
  const int*   A1i = (const int*)d_in[0];
  const float* A1v = (const float*)d_in[1];
  const int*   A2i = (const int*)d_in[2];
  const float* A2v = (const float*)d_in[3];
  const float* X   = (const float*)d_in[4];
  const float* Z   = (const float*)d_in[5];
  const float* W1  = (const float*)d_in[6];
  const float* W2  = (const float*)d_in[7];
  float* out = (float*)d_out;

  char* w = (char*)d_ws;
  size_t off = 0;
  auto alloc = [&](size_t b)->char* {
    char* p = w + off;
    off += (b + 1023) & ~(size_t)1023;
    return p;
  };
  float* sb    = (float*)alloc(NN*4);
  int*   ptr1  = (int*)  alloc((NN+1)*4);
  int*   ptr2  = (int*)  alloc((NN+1)*4);
  int*   cnt   = (int*)  alloc(NN*4);
  int*   cidx1 = (int*)  alloc(NNZE*4);
  float* cval1 = (float*)alloc(NNZE*4);
  int*   cidx2 = (int*)  alloc(NNZE*4);
  float* cval2 = (float*)alloc(NNZE*4);
  short* Zbf   = (short*)alloc((size_t)NN*64*2);
  float* XT1   = (float*)alloc((size_t)NN*512*4);
  float* T1    = (float*)alloc((size_t)NN*512*4);    // adjacent to XT1
  float* HT    = (float*)alloc((size_t)NN*1024*4);
  float* TMP   = (float*)alloc((size_t)NN*1024*4);
  short* Psm   = (short*)alloc((size_t)NN*NN*2);     // 134 MB (P path only)
  bool   bigws = (off <= ws_size);

  float* T2   = XT1;                       // layer-2 T overlays XT1+T1
  short* Ysbt = (short*)TMP;               // Yt bf16 at TMP base
  // bf16 spmm buffers (carved from dead regions):
  short* XT1b  = (short*)HT;                              // 8 MB, layer1 Y bf16
  short* X1b1  = (short*)((char*)HT + (size_t)8*1024*1024);   // 8 MB, layer1 X1 bf16
  short* HTb   = (short*)TMP;                             // 16 MB, layer2 Y bf16
  short* X1b2  = (short*)((char*)TMP + (size_t)16*1024*1024); // 16 MB, layer2 X1 bf16
  // GEMM K-split partials:
  float* P1a = HT;                         // layer1: HT dead during gemm
  float* P1b = HT + (size_t)NN*512;
  float* P1c = (float*)((char*)TMP + (size_t)NN*512*2);   // after 8MB Ysbt
  float* P2a = HT;                         // layer2: HT dead after k_downt

  // CSR for A1, A2
  hipMemsetAsync(cnt, 0, NN*4, stream);
  k_count<<<NNZE/256, 256, 0, stream>>>(A1i, cnt);
  k_scan<<<1, 1024, 0, stream>>>(cnt, ptr1);
  hipMemcpyAsync(cnt, ptr1, NN*4, hipMemcpyDeviceToDevice, stream);
  k_fill<<<NNZE/256, 256, 0, stream>>>(A1i, A1v, cnt, cidx1, cval1);

  hipMemsetAsync(cnt, 0, NN*4, stream);
  k_count<<<NNZE/256, 256, 0, stream>>>(A2i, cnt);
  k_scan<<<1, 1024, 0, stream>>>(cnt, ptr2);
  hipMemcpyAsync(cnt, ptr2, NN*4, hipMemcpyDeviceToDevice, stream);
  k_fill<<<NNZE/256, 256, 0, stream>>>(A2i, A2v, cnt, cidx2, cval2);

  // Xt (node-major), Z bf16
  k_transpose<512><<<dim3(NN/32, 512/32), 256, 0, stream>>>(X, XT1);
  k_zb<<<NN*64/256, 256, 0, stream>>>(Z, Zbf);

  hipMemsetAsync(sb, 0, NN*4, stream);
  if (bigws){
    k_pexp<<<dim3(NN/128, NN/128), 512, 0, stream>>>(Zbf, Psm, sb);
  } else {
    k_colsum_mfma<<<dim3(NN/128, 8), 512, 0, stream>>>(Zbf, sb);
  }
  k_recip<<<NN/256, 256, 0, stream>>>(sb);

  // ---- layer 1 (F=512) ----
  k_tobf<<<2048, 256, 0, stream>>>(XT1, XT1b, NN*512/8);
  k_spmmb<512><<<NN/4, 256, 0, stream>>>(ptr1, cidx1, cval1, XT1b, X1b1);
  k_chebb<512,true><<<NN/4, 256, 0, stream>>>(ptr1, cidx1, cval1, X1b1, XT1, T1);
  k_spmmb<512><<<NN/4, 256, 0, stream>>>(ptr2, cidx2, cval2, XT1b, X1b1);
  k_chebb<512,false><<<NN/4, 256, 0, stream>>>(ptr2, cidx2, cval2, X1b1, XT1, T1);
  k_downt<512><<<dim3(NN/32, 512/32), 256, 0, stream>>>(XT1, sb, Ysbt);
  if (bigws)
    k_gemm2<512><<<dim3(NN/256, 2, 4), 512, 0, stream>>>(Psm, Ysbt, T1, P1a, P1b, P1c, NN/4);
  else
    k_attn2<512><<<dim3(NN/128, 2, 4), 512, 0, stream>>>(Zbf, Ysbt, T1, P1a, P1b, P1c, NN/4);
  k_acc3<<<1024, 256, 0, stream>>>((const f4*)P1a, (const f4*)P1b, (const f4*)P1c, (f4*)T1, NN*512/4);
  k_head<64,512><<<dim3(NN/16, 8), 256, 0, stream>>>(T1, W1, HT);

  // ---- layer 2 (F=1024), T2 overlays XT1/T1 ----
  k_tobf<<<2048, 256, 0, stream>>>(HT, HTb, NN*1024/8);
  k_spmmb<1024><<<NN/2, 256, 0, stream>>>(ptr1, cidx1, cval1, HTb, X1b2);
  k_chebb<1024,true><<<NN/2, 256, 0, stream>>>(ptr1, cidx1, cval1, X1b2, HT, T2);
  k_spmmb<1024><<<NN/2, 256, 0, stream>>>(ptr2, cidx2, cval2, HTb, X1b2);
  k_chebb<1024,false><<<NN/2, 256, 0, stream>>>(ptr2, cidx2, cval2, X1b2, HT, T2);
  k_downt<1024><<<dim3(NN/32, 1024/32), 256, 0, stream>>>(HT, sb, Ysbt);   // HT now dead
  if (bigws)
    k_gemm2<1024><<<dim3(NN/256, 4, 2), 512, 0, stream>>>(Psm, Ysbt, T2, P2a, P2a, P2a, NN/2);
  else
    k_attn2<1024><<<dim3(NN/128, 4, 2), 512, 0, stream>>>(Zbf, Ysbt, T2, P2a, P2a, P2a, NN/2);
  k_acc1<<<2048, 256, 0, stream>>>((const f4*)P2a, (f4*)T2, NN*1024/4);
  k_head<128,1024><<<dim3(NN/16, 8), 256, 0, stream>>>(T2, W2, HT);

  hipMemsetAsync(out, 0, 1024*4, stream);
  k_reduce<<<64, 256, 0, stream>>>(HT, out);
}

// Round 6
// 1003.974 us; speedup vs baseline: 1.2994x; 1.1293x over previous
//
#include <hip/hip_runtime.h>

// GWNet on MI355X — round 6.
// - REVERT attention to the round-3 fused k_attn2 (687 TF measured vs 443-496
//   for the P-materialized pure GEMMs): exp/VALU fills the barrier-drain
//   stall, and no P-matrix HBM traffic. Psm/k_pexp dropped.
// - Occupancy fix: deeper K-split (1024 blocks = 4/CU vs LDS cap 3/CU;
//   round-3 grid was 2/CU). Partials merged by k_accp (multi-src add).
// - Keep round-5 bf16 spmm/Chebyshev chain (halved gather bytes).

#define NN 8192
#define NNZE 131072
#define CSHIFT 48.0f

typedef float4 f4;
typedef __attribute__((ext_vector_type(8))) short bf16x8;
typedef __attribute__((ext_vector_type(4))) float f32x4;

typedef __attribute__((address_space(3))) short lds_short;
typedef __attribute__((address_space(1))) const short glb_short;

struct P8 { float* p[8]; };

__device__ inline short f2b(float x){
  unsigned u = __float_as_uint(x);
  unsigned r = (u + 0x7fffu + ((u >> 16) & 1u)) >> 16;
  return (short)r;
}
__device__ inline float b2f(unsigned short b){
  return __uint_as_float(((unsigned)b) << 16);
}

// ---------------- CSR build ----------------
__global__ __launch_bounds__(256) void k_count(const int* __restrict__ idx, int* __restrict__ cnt){
  int e = blockIdx.x*256 + threadIdx.x;
  if (e < NNZE) atomicAdd(&cnt[idx[e]], 1);
}

__global__ __launch_bounds__(1024) void k_scan(const int* __restrict__ cnt, int* __restrict__ ptr){
  __shared__ int sums[1024];
  int t = threadIdx.x;
  int loc[8]; int s = 0;
  #pragma unroll
  for (int i=0;i<8;i++){ loc[i]=s; s += cnt[t*8+i]; }
  sums[t]=s; __syncthreads();
  for (int off=1; off<1024; off<<=1){
    int v = (t>=off) ? sums[t-off] : 0;
    __syncthreads();
    sums[t] += v;
    __syncthreads();
  }
  int excl = sums[t]-s;
  #pragma unroll
  for (int i=0;i<8;i++) ptr[t*8+i] = excl + loc[i];
  if (t==1023) ptr[NN] = sums[1023];
}

__global__ __launch_bounds__(256) void k_fill(const int* __restrict__ idx, const float* __restrict__ vals,
                                              int* __restrict__ cur, int* __restrict__ cidx, float* __restrict__ cval){
  int e = blockIdx.x*256 + threadIdx.x;
  if (e < NNZE){
    int r = idx[e], c = idx[NNZE+e];
    int p = atomicAdd(&cur[r], 1);
    cidx[p] = c; cval[p] = vals[e];
  }
}

// ---------------- transpose X (R, NN) -> (NN, R) ----------------
template<int R>
__global__ __launch_bounds__(256) void k_transpose(const float* __restrict__ src, float* __restrict__ dst){
  __shared__ float tile[32][33];
  int tx = threadIdx.x & 31, ty = threadIdx.x >> 5;
  int j0 = blockIdx.x*32, f0 = blockIdx.y*32;
  #pragma unroll
  for (int u=0;u<32;u+=8) tile[ty+u][tx] = src[(size_t)(f0+ty+u)*NN + j0+tx];
  __syncthreads();
  #pragma unroll
  for (int u=0;u<32;u+=8) dst[(size_t)(j0+ty+u)*R + f0+tx] = tile[tx][ty+u];
}

// ---------------- f32 -> bf16 stream ----------------
__global__ __launch_bounds__(256) void k_tobf(const float* __restrict__ src, short* __restrict__ dst, int n8){
  for (int i = blockIdx.x*256 + threadIdx.x; i < n8; i += gridDim.x*256){
    f4 x = ((const f4*)src)[2*i], y = ((const f4*)src)[2*i+1];
    bf16x8 o;
    o[0]=f2b(x.x); o[1]=f2b(x.y); o[2]=f2b(x.z); o[3]=f2b(x.w);
    o[4]=f2b(y.x); o[5]=f2b(y.y); o[6]=f2b(y.z); o[7]=f2b(y.w);
    ((bf16x8*)dst)[i] = o;
  }
}

// ---------------- Z -> bf16 ----------------
__global__ __launch_bounds__(256) void k_zb(const float* __restrict__ Z, short* __restrict__ Zb){
  int i = blockIdx.x*256 + threadIdx.x;
  Zb[i] = f2b(Z[i]);
}

// ---------------- column sums via MFMA: sb[j] = sum_i exp(relu(zi.zj) - C) ----------------
__global__ __launch_bounds__(512) void k_colsum_mfma(const short* __restrict__ Zb, float* __restrict__ sb){
  int t = threadIdx.x;
  int w = t >> 6, l = t & 63;
  int lo = l & 15, g = l >> 4;
  int j = blockIdx.x*128 + w*16 + lo;
  const bf16x8* Zb8 = (const bf16x8*)Zb;
  bf16x8 bj0 = Zb8[j*8 + g];
  bf16x8 bj1 = Zb8[j*8 + g + 4];
  int i0 = blockIdx.y * (NN/8);
  float sum = 0.f;
  for (int i = i0; i < i0 + NN/8; i += 16){
    bf16x8 a0 = Zb8[(size_t)(i+lo)*8 + g];
    bf16x8 a1 = Zb8[(size_t)(i+lo)*8 + g + 4];
    f32x4 s = (f32x4){0.f,0.f,0.f,0.f};
    s = __builtin_amdgcn_mfma_f32_16x16x32_bf16(a0, bj0, s, 0,0,0);
    s = __builtin_amdgcn_mfma_f32_16x16x32_bf16(a1, bj1, s, 0,0,0);
    #pragma unroll
    for (int r=0;r<4;r++) sum += __expf(fmaxf(s[r],0.f) - CSHIFT);
  }
  sum += __shfl_xor(sum, 16);
  sum += __shfl_xor(sum, 32);
  if (g == 0) atomicAdd(sb + j, sum);
}

__global__ __launch_bounds__(256) void k_recip(float* s){
  int i = blockIdx.x*256 + threadIdx.x;
  if (i < NN) s[i] = 1.0f/s[i];
}

// ---------------- bf16 spmm: outb[r][:] = bf16( sum_e v * Yb[c][:] ) ----------------
template<int F>
__global__ __launch_bounds__(256) void k_spmmb(const int* __restrict__ ptr, const int* __restrict__ cidx,
                                               const float* __restrict__ cval, const short* __restrict__ Yb,
                                               short* __restrict__ outb){
  constexpr int LPR = F/8;
  int t = threadIdx.x;
  int r = blockIdx.x*(256/LPR) + t/LPR;
  int ts = t % LPR;
  const bf16x8* Y8 = (const bf16x8*)Yb;
  int p0 = ptr[r], p1 = ptr[r+1];
  float a[8];
  #pragma unroll
  for (int j=0;j<8;j++) a[j]=0.f;
  int p = p0;
  for (; p+1 < p1; p += 2){
    int c0 = cidx[p],   c1 = cidx[p+1];
    float v0 = cval[p], v1 = cval[p+1];
    bf16x8 x0 = Y8[(size_t)c0*LPR + ts];
    bf16x8 x1 = Y8[(size_t)c1*LPR + ts];
    #pragma unroll
    for (int j=0;j<8;j++) a[j] += v0*b2f((unsigned short)x0[j]);
    #pragma unroll
    for (int j=0;j<8;j++) a[j] += v1*b2f((unsigned short)x1[j]);
  }
  if (p < p1){
    int c0 = cidx[p]; float v0 = cval[p];
    bf16x8 x0 = Y8[(size_t)c0*LPR + ts];
    #pragma unroll
    for (int j=0;j<8;j++) a[j] += v0*b2f((unsigned short)x0[j]);
  }
  bf16x8 o;
  #pragma unroll
  for (int j=0;j<8;j++) o[j] = f2b(a[j]);
  ((bf16x8*)outb)[(size_t)r*LPR + ts] = o;
}

// ---------------- cheb epilogue: T (=/+=) x1 + 2*A.x1 (+ -Y if FIRST), f32 out ----------------
template<int F, bool FIRST>
__global__ __launch_bounds__(256) void k_chebb(const int* __restrict__ ptr, const int* __restrict__ cidx,
                                               const float* __restrict__ cval, const short* __restrict__ X1b,
                                               const float* __restrict__ Yf, float* __restrict__ T){
  constexpr int LPR = F/8;
  int t = threadIdx.x;
  int r = blockIdx.x*(256/LPR) + t/LPR;
  int ts = t % LPR;
  const bf16x8* X8 = (const bf16x8*)X1b;
  int p0 = ptr[r], p1 = ptr[r+1];
  float a[8];
  #pragma unroll
  for (int j=0;j<8;j++) a[j]=0.f;
  int p = p0;
  for (; p+1 < p1; p += 2){
    int c0 = cidx[p],   c1 = cidx[p+1];
    float v0 = cval[p], v1 = cval[p+1];
    bf16x8 x0 = X8[(size_t)c0*LPR + ts];
    bf16x8 x1 = X8[(size_t)c1*LPR + ts];
    #pragma unroll
    for (int j=0;j<8;j++) a[j] += v0*b2f((unsigned short)x0[j]);
    #pragma unroll
    for (int j=0;j<8;j++) a[j] += v1*b2f((unsigned short)x1[j]);
  }
  if (p < p1){
    int c0 = cidx[p]; float v0 = cval[p];
    bf16x8 x0 = X8[(size_t)c0*LPR + ts];
    #pragma unroll
    for (int j=0;j<8;j++) a[j] += v0*b2f((unsigned short)x0[j]);
  }
  bf16x8 tm = X8[(size_t)r*LPR + ts];
  size_t o4 = ((size_t)r*F + ts*8) >> 2;
  f4 r0, r1;
  if (FIRST){
    f4 y0 = ((const f4*)Yf)[o4], y1 = ((const f4*)Yf)[o4+1];
    r0.x = b2f((unsigned short)tm[0]) + 2.f*a[0] - y0.x;
    r0.y = b2f((unsigned short)tm[1]) + 2.f*a[1] - y0.y;
    r0.z = b2f((unsigned short)tm[2]) + 2.f*a[2] - y0.z;
    r0.w = b2f((unsigned short)tm[3]) + 2.f*a[3] - y0.w;
    r1.x = b2f((unsigned short)tm[4]) + 2.f*a[4] - y1.x;
    r1.y = b2f((unsigned short)tm[5]) + 2.f*a[5] - y1.y;
    r1.z = b2f((unsigned short)tm[6]) + 2.f*a[6] - y1.z;
    r1.w = b2f((unsigned short)tm[7]) + 2.f*a[7] - y1.w;
  } else {
    f4 t0 = ((const f4*)T)[o4], t1 = ((const f4*)T)[o4+1];
    r0.x = t0.x + b2f((unsigned short)tm[0]) + 2.f*a[0];
    r0.y = t0.y + b2f((unsigned short)tm[1]) + 2.f*a[1];
    r0.z = t0.z + b2f((unsigned short)tm[2]) + 2.f*a[2];
    r0.w = t0.w + b2f((unsigned short)tm[3]) + 2.f*a[3];
    r1.x = t1.x + b2f((unsigned short)tm[4]) + 2.f*a[4];
    r1.y = t1.y + b2f((unsigned short)tm[5]) + 2.f*a[5];
    r1.z = t1.z + b2f((unsigned short)tm[6]) + 2.f*a[6];
    r1.w = t1.w + b2f((unsigned short)tm[7]) + 2.f*a[7];
  }
  ((f4*)T)[o4]   = r0;
  ((f4*)T)[o4+1] = r1;
}

// ---------------- Y -> Yt: transpose, scale by sinv[k], cvt bf16. Yt[n][k] ----------------
template<int F>
__global__ __launch_bounds__(256) void k_downt(const float* __restrict__ Y, const float* __restrict__ sinv,
                                               short* __restrict__ Yt){
  __shared__ float tile[32][33];
  int tx = threadIdx.x & 31, ty = threadIdx.x >> 5;
  int k0 = blockIdx.x*32, n0 = blockIdx.y*32;
  #pragma unroll
  for (int u=0;u<32;u+=8) tile[ty+u][tx] = Y[(size_t)(k0+ty+u)*F + n0+tx];
  __syncthreads();
  float sv = sinv[k0+tx];
  #pragma unroll
  for (int u=0;u<32;u+=8) Yt[(size_t)(n0+ty+u)*NN + k0+tx] = f2b(tile[tx][ty+u] * sv);
}

// ---------------- fused attention (round-3 proven): out (+)= P @ Ys ----------------
// BM=128, BN=256, BK=32, 512 threads = 8 waves (2M x 4N). K-split via blockIdx.z;
// kz==0 accumulates into pp.p[0], kz>0 stores to pp.p[kz].
template<int F>
__global__ __launch_bounds__(512, 4) void k_attn2(
    const short* __restrict__ Zb, const short* __restrict__ Ytg,
    P8 pp, int ksize)
{
  __shared__ __align__(16) short zk[2][32*64];
  __shared__ __align__(16) short yt[2][256*32];
  __shared__ __align__(16) short p_lds[128*40];
  int t = threadIdx.x;
  int w = t >> 6, l = t & 63;
  int lo = l & 15, g = l >> 4;
  int m0 = blockIdx.x * 128;
  int n0 = blockIdx.y * 256;
  int kz = blockIdx.z;
  int kbeg = kz * ksize, kend = kbeg + ksize;
  int wm = w >> 2, wn = w & 3;

  const bf16x8* Zb8 = (const bf16x8*)Zb;
  int zirow = m0 + w*16 + lo;
  bf16x8 ziA0 = Zb8[(size_t)zirow*8 + g];
  bf16x8 ziA1 = Zb8[(size_t)zirow*8 + g + 4];

  f32x4 acc[4][4];
  #pragma unroll
  for (int i=0;i<4;i++)
    #pragma unroll
    for (int j=0;j<4;j++) acc[i][j] = (f32x4){0.f,0.f,0.f,0.f};

  auto STAGE = [&](int b, int kk){
    if (t < 256){
      int r = t >> 3, c = t & 7;
      const short* src = Zb + (((size_t)(kk + r)) << 6) + ((c ^ (r & 7)) << 3);
      __builtin_amdgcn_global_load_lds((glb_short*)src, (lds_short*)&zk[b][t*8], 16, 0, 0);
    }
    #pragma unroll
    for (int p=0;p<2;p++){
      int cc = p*512 + t;
      int r = cc >> 2, c = cc & 3;
      const short* src = Ytg + (size_t)(n0 + r)*NN + kk + ((c ^ (r & 3)) << 3);
      __builtin_amdgcn_global_load_lds((glb_short*)src, (lds_short*)&yt[b][cc*8], 16, 0, 0);
    }
  };

  STAGE(0, kbeg);
  __syncthreads();

  int cur = 0;
  for (int k0 = kbeg; k0 < kend; k0 += 32){
    int xa = g ^ (lo & 7), xb = (g + 4) ^ (lo & 7);
    bf16x8 b00 = *(const bf16x8*)&zk[cur][(lo*8 + xa)*8];
    bf16x8 b01 = *(const bf16x8*)&zk[cur][(lo*8 + xb)*8];
    bf16x8 b10 = *(const bf16x8*)&zk[cur][((16+lo)*8 + xa)*8];
    bf16x8 b11 = *(const bf16x8*)&zk[cur][((16+lo)*8 + xb)*8];
    f32x4 s0 = (f32x4){0.f,0.f,0.f,0.f};
    f32x4 s1 = (f32x4){0.f,0.f,0.f,0.f};
    s0 = __builtin_amdgcn_mfma_f32_16x16x32_bf16(ziA0, b00, s0, 0,0,0);
    s0 = __builtin_amdgcn_mfma_f32_16x16x32_bf16(ziA1, b01, s0, 0,0,0);
    s1 = __builtin_amdgcn_mfma_f32_16x16x32_bf16(ziA0, b10, s1, 0,0,0);
    s1 = __builtin_amdgcn_mfma_f32_16x16x32_bf16(ziA1, b11, s1, 0,0,0);
    short e0[4], e1[4];
    #pragma unroll
    for (int r=0;r<4;r++){
      e0[r] = f2b(__expf(fmaxf(s0[r],0.f) - CSHIFT));
      e1[r] = f2b(__expf(fmaxf(s1[r],0.f) - CSHIFT));
    }
    __syncthreads();
    if (k0 + 32 < kend) STAGE(cur ^ 1, k0 + 32);
    int prow = w*16 + g*4;
    #pragma unroll
    for (int r=0;r<4;r++){
      p_lds[(prow+r)*40 + lo]      = e0[r];
      p_lds[(prow+r)*40 + 16 + lo] = e1[r];
    }
    __syncthreads();
    bf16x8 aP[4];
    #pragma unroll
    for (int mf=0; mf<4; mf++)
      aP[mf] = *(const bf16x8*)&p_lds[(wm*64 + mf*16 + lo)*40 + g*8];
    #pragma unroll
    for (int nf=0; nf<4; nf++){
      int nl = wn*64 + nf*16 + lo;
      bf16x8 bY = *(const bf16x8*)&yt[cur][(nl*4 + (g ^ (nl & 3)))*8];
      #pragma unroll
      for (int mf=0; mf<4; mf++)
        acc[mf][nf] = __builtin_amdgcn_mfma_f32_16x16x32_bf16(aP[mf], bY, acc[mf][nf], 0,0,0);
    }
    cur ^= 1;
  }
  float* outp = pp.p[kz];
  #pragma unroll
  for (int mf=0; mf<4; mf++){
    int row = m0 + wm*64 + mf*16 + g*4;
    #pragma unroll
    for (int nf=0; nf<4; nf++){
      int col = n0 + wn*64 + nf*16 + lo;
      #pragma unroll
      for (int r=0;r<4;r++){
        size_t o = (size_t)(row+r)*F + col;
        if (kz==0) outp[o] += acc[mf][nf][r];
        else       outp[o]  = acc[mf][nf][r];
      }
    }
  }
}

// ---------------- partial merge: o += sum of ns partial buffers ----------------
__global__ __launch_bounds__(256) void k_accp(P8 s, int ns, f4* __restrict__ o, int n4){
  for (int i = blockIdx.x*256 + threadIdx.x; i < n4; i += gridDim.x*256){
    f4 r = o[i];
    for (int j=0;j<ns;j++){
      f4 x = ((const f4*)s.p[j])[i];
      r.x+=x.x; r.y+=x.y; r.z+=x.z; r.w+=x.w;
    }
    o[i] = r;
  }
}

// ---------------- head GEMM ----------------
template<int DIN, int FIN>
__global__ __launch_bounds__(256) void k_head(const float* __restrict__ T, const float* __restrict__ W,
                                              float* __restrict__ Hout){
  __shared__ float tt[16*DIN];
  int t = threadIdx.x;
  int j0 = blockIdx.x*16, b = blockIdx.y;
  const f4* T4 = (const f4*)T;
  for (int u=t; u<16*DIN/4; u+=256){
    int jj = u / (DIN/4), kq = u % (DIN/4);
    ((f4*)tt)[u] = T4[((size_t)(j0+jj)*FIN + b*DIN)/4 + kq];
  }
  __syncthreads();
  int oq = t & 31, jg = t >> 5;
  f4 a0 = {0,0,0,0}, a1 = {0,0,0,0};
  const f4* W4 = (const f4*)W;
  for (int k=0;k<DIN;k++){
    f4 wv = W4[k*32 + oq];
    float t0 = tt[(jg*2+0)*DIN + k];
    float t1 = tt[(jg*2+1)*DIN + k];
    a0.x += t0*wv.x; a0.y += t0*wv.y; a0.z += t0*wv.z; a0.w += t0*wv.w;
    a1.x += t1*wv.x; a1.y += t1*wv.y; a1.z += t1*wv.z; a1.w += t1*wv.w;
  }
  a0.x=fmaxf(a0.x,0.f); a0.y=fmaxf(a0.y,0.f); a0.z=fmaxf(a0.z,0.f); a0.w=fmaxf(a0.w,0.f);
  a1.x=fmaxf(a1.x,0.f); a1.y=fmaxf(a1.y,0.f); a1.z=fmaxf(a1.z,0.f); a1.w=fmaxf(a1.w,0.f);
  f4* H4 = (f4*)Hout;
  H4[(size_t)(j0+jg*2+0)*256 + b*32 + oq] = a0;
  H4[(size_t)(j0+jg*2+1)*256 + b*32 + oq] = a1;
}

// ---------------- final mean over nodes ----------------
__global__ __launch_bounds__(256) void k_reduce(const float* __restrict__ A, float* __restrict__ out){
  __shared__ float accl[1024];
  int t = threadIdx.x;
  for (int u=t; u<1024; u+=256) accl[u]=0.f;
  __syncthreads();
  int j0 = blockIdx.x*128;
  for (int j=j0; j<j0+128; j++){
    for (int u=t; u<1024; u+=256) accl[u] += A[(size_t)j*1024 + u];
  }
  __syncthreads();
  for (int u=t; u<1024; u+=256) atomicAdd(&out[u], accl[u]*(1.f/8192.f));
}

// ---------------- launcher ----------------
extern "C" void kernel_launch(void* const* d_in, const int* in_sizes, int n_in,
                              void* d_out, int out_size, void* d_ws, size_t ws_size,
                              hipStream_t stream){
  const int*   A1i = (const int*)d_in[0];
  const float* A1v = (const float*)d_in[1];
  const int*   A2i = (const int*)d_in[2];
  const float* A2v = (const float*)d_in[3];
  const float* X   = (const float*)d_in[4];
  const float* Z   = (const float*)d_in[5];
  const float* W1  = (const float*)d_in[6];
  const float* W2  = (const float*)d_in[7];
  float* out = (float*)d_out;

  char* w = (char*)d_ws;
  size_t off = 0;
  auto alloc = [&](size_t b)->char* {
    char* p = w + off;
    off += (b + 1023) & ~(size_t)1023;
    return p;
  };
  float* sb    = (float*)alloc(NN*4);
  int*   ptr1  = (int*)  alloc((NN+1)*4);
  int*   ptr2  = (int*)  alloc((NN+1)*4);
  int*   cnt   = (int*)  alloc(NN*4);
  int*   cidx1 = (int*)  alloc(NNZE*4);
  float* cval1 = (float*)alloc(NNZE*4);
  int*   cidx2 = (int*)  alloc(NNZE*4);
  float* cval2 = (float*)alloc(NNZE*4);
  short* Zbf   = (short*)alloc((size_t)NN*64*2);
  float* XT1   = (float*)alloc((size_t)NN*512*4);
  float* T1    = (float*)alloc((size_t)NN*512*4);    // adjacent to XT1
  float* HT    = (float*)alloc((size_t)NN*1024*4);
  float* TMP   = (float*)alloc((size_t)NN*1024*4);
  char*  PART  = alloc((size_t)96*1024*1024);        // deep-split partials
  bool   bigws = (off <= ws_size);

  const size_t MB = 1024*1024;
  float* T2   = XT1;                       // layer-2 T overlays XT1+T1 (32MB)
  short* Ysbt = (short*)TMP;               // Yt bf16 at TMP base (8/16MB)
  // bf16 spmm buffers (dead regions):
  short* XT1b  = (short*)HT;                          // 8 MB
  short* X1b1  = (short*)((char*)HT + 8*MB);          // 8 MB
  short* HTb   = (short*)TMP;                         // 16 MB
  short* X1b2  = (short*)((char*)TMP + 16*MB);        // 16 MB

  // CSR for A1, A2
  hipMemsetAsync(cnt, 0, NN*4, stream);
  k_count<<<NNZE/256, 256, 0, stream>>>(A1i, cnt);
  k_scan<<<1, 1024, 0, stream>>>(cnt, ptr1);
  hipMemcpyAsync(cnt, ptr1, NN*4, hipMemcpyDeviceToDevice, stream);
  k_fill<<<NNZE/256, 256, 0, stream>>>(A1i, A1v, cnt, cidx1, cval1);

  hipMemsetAsync(cnt, 0, NN*4, stream);
  k_count<<<NNZE/256, 256, 0, stream>>>(A2i, cnt);
  k_scan<<<1, 1024, 0, stream>>>(cnt, ptr2);
  hipMemcpyAsync(cnt, ptr2, NN*4, hipMemcpyDeviceToDevice, stream);
  k_fill<<<NNZE/256, 256, 0, stream>>>(A2i, A2v, cnt, cidx2, cval2);

  // Xt (node-major), Z bf16, softmax column sums
  k_transpose<512><<<dim3(NN/32, 512/32), 256, 0, stream>>>(X, XT1);
  k_zb<<<NN*64/256, 256, 0, stream>>>(Z, Zbf);
  hipMemsetAsync(sb, 0, NN*4, stream);
  k_colsum_mfma<<<dim3(NN/128, 8), 512, 0, stream>>>(Zbf, sb);
  k_recip<<<NN/256, 256, 0, stream>>>(sb);

  // ---- layer 1 (F=512) ----
  k_tobf<<<2048, 256, 0, stream>>>(XT1, XT1b, NN*512/8);
  k_spmmb<512><<<NN/4, 256, 0, stream>>>(ptr1, cidx1, cval1, XT1b, X1b1);
  k_chebb<512,true><<<NN/4, 256, 0, stream>>>(ptr1, cidx1, cval1, X1b1, XT1, T1);
  k_spmmb<512><<<NN/4, 256, 0, stream>>>(ptr2, cidx2, cval2, XT1b, X1b1);
  k_chebb<512,false><<<NN/4, 256, 0, stream>>>(ptr2, cidx2, cval2, X1b1, XT1, T1);
  k_downt<512><<<dim3(NN/32, 512/32), 256, 0, stream>>>(XT1, sb, Ysbt);
  {
    P8 pp; P8 ps;
    if (bigws){
      // kz=8, 16MB partials: 2 in dead HT, 5 in PART
      pp.p[0] = T1;
      pp.p[1] = (float*)HT;            ps.p[0] = pp.p[1];
      pp.p[2] = (float*)((char*)HT + 16*MB); ps.p[1] = pp.p[2];
      for (int i=0;i<5;i++){ pp.p[3+i] = (float*)(PART + (size_t)i*16*MB); ps.p[2+i] = pp.p[3+i]; }
      k_attn2<512><<<dim3(NN/128, 2, 8), 512, 0, stream>>>(Zbf, Ysbt, pp, NN/8);
      k_accp<<<1024, 256, 0, stream>>>(ps, 7, (f4*)T1, NN*512/4);
    } else {
      // round-3 mapping: kz=4, partials in HT (2) + TMP tail (1)
      pp.p[0] = T1;
      pp.p[1] = (float*)HT;                         ps.p[0] = pp.p[1];
      pp.p[2] = (float*)((char*)HT + 16*MB);        ps.p[1] = pp.p[2];
      pp.p[3] = (float*)((char*)TMP + 16*MB);       ps.p[2] = pp.p[3];
      k_attn2<512><<<dim3(NN/128, 2, 4), 512, 0, stream>>>(Zbf, Ysbt, pp, NN/4);
      k_accp<<<1024, 256, 0, stream>>>(ps, 3, (f4*)T1, NN*512/4);
    }
  }
  k_head<64,512><<<dim3(NN/16, 8), 256, 0, stream>>>(T1, W1, HT);

  // ---- layer 2 (F=1024), T2 overlays XT1/T1 ----
  k_tobf<<<2048, 256, 0, stream>>>(HT, HTb, NN*1024/8);
  k_spmmb<1024><<<NN/2, 256, 0, stream>>>(ptr1, cidx1, cval1, HTb, X1b2);
  k_chebb<1024,true><<<NN/2, 256, 0, stream>>>(ptr1, cidx1, cval1, X1b2, HT, T2);
  k_spmmb<1024><<<NN/2, 256, 0, stream>>>(ptr2, cidx2, cval2, HTb, X1b2);
  k_chebb<1024,false><<<NN/2, 256, 0, stream>>>(ptr2, cidx2, cval2, X1b2, HT, T2);
  k_downt<1024><<<dim3(NN/32, 1024/32), 256, 0, stream>>>(HT, sb, Ysbt);   // HT now dead
  {
    P8 pp; P8 ps;
    if (bigws){
      // kz=4, 32MB partials: 3 in PART
      pp.p[0] = T2;
      for (int i=0;i<3;i++){ pp.p[1+i] = (float*)(PART + (size_t)i*32*MB); ps.p[i] = pp.p[1+i]; }
      k_attn2<1024><<<dim3(NN/128, 4, 4), 512, 0, stream>>>(Zbf, Ysbt, pp, NN/4);
      k_accp<<<2048, 256, 0, stream>>>(ps, 3, (f4*)T2, NN*1024/4);
    } else {
      // round-3 mapping: kz=2, partial in HT
      pp.p[0] = T2;
      pp.p[1] = (float*)HT;  ps.p[0] = pp.p[1];
      k_attn2<1024><<<dim3(NN/128, 4, 2), 512, 0, stream>>>(Zbf, Ysbt, pp, NN/2);
      k_accp<<<2048, 256, 0, stream>>>(ps, 1, (f4*)T2, NN*1024/4);
    }
  }
  k_head<128,1024><<<dim3(NN/16, 8), 256, 0, stream>>>(T2, W2, HT);

  hipMemsetAsync(out, 0, 1024*4, stream);
  k_reduce<<<64, 256, 0, stream>>>(HT, out);
}

// Round 7
// 946.043 us; speedup vs baseline: 1.3789x; 1.0612x over previous
//
#include <hip/hip_runtime.h>

// GWNet on MI355X — round 7.
// - Attention: round-3 K-split (512 blocks = 2/CU, no tail) + chunk-major
//   [chunk][row] LDS tiles (round-4 k_gemm layout, measured 0 bank conflicts)
//   + all-store partials (no T read-modify-write inside attn).
// - bf16 spmm/Chebyshev chain and the rest unchanged from round 6.

#define NN 8192
#define NNZE 131072
#define CSHIFT 48.0f

typedef float4 f4;
typedef __attribute__((ext_vector_type(8))) short bf16x8;
typedef __attribute__((ext_vector_type(4))) float f32x4;

typedef __attribute__((address_space(3))) short lds_short;
typedef __attribute__((address_space(1))) const short glb_short;

struct P8 { float* p[8]; };

__device__ inline short f2b(float x){
  unsigned u = __float_as_uint(x);
  unsigned r = (u + 0x7fffu + ((u >> 16) & 1u)) >> 16;
  return (short)r;
}
__device__ inline float b2f(unsigned short b){
  return __uint_as_float(((unsigned)b) << 16);
}

// ---------------- CSR build ----------------
__global__ __launch_bounds__(256) void k_count(const int* __restrict__ idx, int* __restrict__ cnt){
  int e = blockIdx.x*256 + threadIdx.x;
  if (e < NNZE) atomicAdd(&cnt[idx[e]], 1);
}

__global__ __launch_bounds__(1024) void k_scan(const int* __restrict__ cnt, int* __restrict__ ptr){
  __shared__ int sums[1024];
  int t = threadIdx.x;
  int loc[8]; int s = 0;
  #pragma unroll
  for (int i=0;i<8;i++){ loc[i]=s; s += cnt[t*8+i]; }
  sums[t]=s; __syncthreads();
  for (int off=1; off<1024; off<<=1){
    int v = (t>=off) ? sums[t-off] : 0;
    __syncthreads();
    sums[t] += v;
    __syncthreads();
  }
  int excl = sums[t]-s;
  #pragma unroll
  for (int i=0;i<8;i++) ptr[t*8+i] = excl + loc[i];
  if (t==1023) ptr[NN] = sums[1023];
}

__global__ __launch_bounds__(256) void k_fill(const int* __restrict__ idx, const float* __restrict__ vals,
                                              int* __restrict__ cur, int* __restrict__ cidx, float* __restrict__ cval){
  int e = blockIdx.x*256 + threadIdx.x;
  if (e < NNZE){
    int r = idx[e], c = idx[NNZE+e];
    int p = atomicAdd(&cur[r], 1);
    cidx[p] = c; cval[p] = vals[e];
  }
}

// ---------------- transpose X (R, NN) -> (NN, R) ----------------
template<int R>
__global__ __launch_bounds__(256) void k_transpose(const float* __restrict__ src, float* __restrict__ dst){
  __shared__ float tile[32][33];
  int tx = threadIdx.x & 31, ty = threadIdx.x >> 5;
  int j0 = blockIdx.x*32, f0 = blockIdx.y*32;
  #pragma unroll
  for (int u=0;u<32;u+=8) tile[ty+u][tx] = src[(size_t)(f0+ty+u)*NN + j0+tx];
  __syncthreads();
  #pragma unroll
  for (int u=0;u<32;u+=8) dst[(size_t)(j0+ty+u)*R + f0+tx] = tile[tx][ty+u];
}

// ---------------- f32 -> bf16 stream ----------------
__global__ __launch_bounds__(256) void k_tobf(const float* __restrict__ src, short* __restrict__ dst, int n8){
  for (int i = blockIdx.x*256 + threadIdx.x; i < n8; i += gridDim.x*256){
    f4 x = ((const f4*)src)[2*i], y = ((const f4*)src)[2*i+1];
    bf16x8 o;
    o[0]=f2b(x.x); o[1]=f2b(x.y); o[2]=f2b(x.z); o[3]=f2b(x.w);
    o[4]=f2b(y.x); o[5]=f2b(y.y); o[6]=f2b(y.z); o[7]=f2b(y.w);
    ((bf16x8*)dst)[i] = o;
  }
}

// ---------------- Z -> bf16 ----------------
__global__ __launch_bounds__(256) void k_zb(const float* __restrict__ Z, short* __restrict__ Zb){
  int i = blockIdx.x*256 + threadIdx.x;
  Zb[i] = f2b(Z[i]);
}

// ---------------- column sums via MFMA: sb[j] = sum_i exp(relu(zi.zj) - C) ----------------
__global__ __launch_bounds__(512) void k_colsum_mfma(const short* __restrict__ Zb, float* __restrict__ sb){
  int t = threadIdx.x;
  int w = t >> 6, l = t & 63;
  int lo = l & 15, g = l >> 4;
  int j = blockIdx.x*128 + w*16 + lo;
  const bf16x8* Zb8 = (const bf16x8*)Zb;
  bf16x8 bj0 = Zb8[j*8 + g];
  bf16x8 bj1 = Zb8[j*8 + g + 4];
  int i0 = blockIdx.y * (NN/8);
  float sum = 0.f;
  for (int i = i0; i < i0 + NN/8; i += 16){
    bf16x8 a0 = Zb8[(size_t)(i+lo)*8 + g];
    bf16x8 a1 = Zb8[(size_t)(i+lo)*8 + g + 4];
    f32x4 s = (f32x4){0.f,0.f,0.f,0.f};
    s = __builtin_amdgcn_mfma_f32_16x16x32_bf16(a0, bj0, s, 0,0,0);
    s = __builtin_amdgcn_mfma_f32_16x16x32_bf16(a1, bj1, s, 0,0,0);
    #pragma unroll
    for (int r=0;r<4;r++) sum += __expf(fmaxf(s[r],0.f) - CSHIFT);
  }
  sum += __shfl_xor(sum, 16);
  sum += __shfl_xor(sum, 32);
  if (g == 0) atomicAdd(sb + j, sum);
}

__global__ __launch_bounds__(256) void k_recip(float* s){
  int i = blockIdx.x*256 + threadIdx.x;
  if (i < NN) s[i] = 1.0f/s[i];
}

// ---------------- bf16 spmm: outb[r][:] = bf16( sum_e v * Yb[c][:] ) ----------------
template<int F>
__global__ __launch_bounds__(256) void k_spmmb(const int* __restrict__ ptr, const int* __restrict__ cidx,
                                               const float* __restrict__ cval, const short* __restrict__ Yb,
                                               short* __restrict__ outb){
  constexpr int LPR = F/8;
  int t = threadIdx.x;
  int r = blockIdx.x*(256/LPR) + t/LPR;
  int ts = t % LPR;
  const bf16x8* Y8 = (const bf16x8*)Yb;
  int p0 = ptr[r], p1 = ptr[r+1];
  float a[8];
  #pragma unroll
  for (int j=0;j<8;j++) a[j]=0.f;
  int p = p0;
  for (; p+1 < p1; p += 2){
    int c0 = cidx[p],   c1 = cidx[p+1];
    float v0 = cval[p], v1 = cval[p+1];
    bf16x8 x0 = Y8[(size_t)c0*LPR + ts];
    bf16x8 x1 = Y8[(size_t)c1*LPR + ts];
    #pragma unroll
    for (int j=0;j<8;j++) a[j] += v0*b2f((unsigned short)x0[j]);
    #pragma unroll
    for (int j=0;j<8;j++) a[j] += v1*b2f((unsigned short)x1[j]);
  }
  if (p < p1){
    int c0 = cidx[p]; float v0 = cval[p];
    bf16x8 x0 = Y8[(size_t)c0*LPR + ts];
    #pragma unroll
    for (int j=0;j<8;j++) a[j] += v0*b2f((unsigned short)x0[j]);
  }
  bf16x8 o;
  #pragma unroll
  for (int j=0;j<8;j++) o[j] = f2b(a[j]);
  ((bf16x8*)outb)[(size_t)r*LPR + ts] = o;
}

// ---------------- cheb epilogue: T (=/+=) x1 + 2*A.x1 (+ -Y if FIRST), f32 out ----------------
template<int F, bool FIRST>
__global__ __launch_bounds__(256) void k_chebb(const int* __restrict__ ptr, const int* __restrict__ cidx,
                                               const float* __restrict__ cval, const short* __restrict__ X1b,
                                               const float* __restrict__ Yf, float* __restrict__ T){
  constexpr int LPR = F/8;
  int t = threadIdx.x;
  int r = blockIdx.x*(256/LPR) + t/LPR;
  int ts = t % LPR;
  const bf16x8* X8 = (const bf16x8*)X1b;
  int p0 = ptr[r], p1 = ptr[r+1];
  float a[8];
  #pragma unroll
  for (int j=0;j<8;j++) a[j]=0.f;
  int p = p0;
  for (; p+1 < p1; p += 2){
    int c0 = cidx[p],   c1 = cidx[p+1];
    float v0 = cval[p], v1 = cval[p+1];
    bf16x8 x0 = X8[(size_t)c0*LPR + ts];
    bf16x8 x1 = X8[(size_t)c1*LPR + ts];
    #pragma unroll
    for (int j=0;j<8;j++) a[j] += v0*b2f((unsigned short)x0[j]);
    #pragma unroll
    for (int j=0;j<8;j++) a[j] += v1*b2f((unsigned short)x1[j]);
  }
  if (p < p1){
    int c0 = cidx[p]; float v0 = cval[p];
    bf16x8 x0 = X8[(size_t)c0*LPR + ts];
    #pragma unroll
    for (int j=0;j<8;j++) a[j] += v0*b2f((unsigned short)x0[j]);
  }
  bf16x8 tm = X8[(size_t)r*LPR + ts];
  size_t o4 = ((size_t)r*F + ts*8) >> 2;
  f4 r0, r1;
  if (FIRST){
    f4 y0 = ((const f4*)Yf)[o4], y1 = ((const f4*)Yf)[o4+1];
    r0.x = b2f((unsigned short)tm[0]) + 2.f*a[0] - y0.x;
    r0.y = b2f((unsigned short)tm[1]) + 2.f*a[1] - y0.y;
    r0.z = b2f((unsigned short)tm[2]) + 2.f*a[2] - y0.z;
    r0.w = b2f((unsigned short)tm[3]) + 2.f*a[3] - y0.w;
    r1.x = b2f((unsigned short)tm[4]) + 2.f*a[4] - y1.x;
    r1.y = b2f((unsigned short)tm[5]) + 2.f*a[5] - y1.y;
    r1.z = b2f((unsigned short)tm[6]) + 2.f*a[6] - y1.z;
    r1.w = b2f((unsigned short)tm[7]) + 2.f*a[7] - y1.w;
  } else {
    f4 t0 = ((const f4*)T)[o4], t1 = ((const f4*)T)[o4+1];
    r0.x = t0.x + b2f((unsigned short)tm[0]) + 2.f*a[0];
    r0.y = t0.y + b2f((unsigned short)tm[1]) + 2.f*a[1];
    r0.z = t0.z + b2f((unsigned short)tm[2]) + 2.f*a[2];
    r0.w = t0.w + b2f((unsigned short)tm[3]) + 2.f*a[3];
    r1.x = t1.x + b2f((unsigned short)tm[4]) + 2.f*a[4];
    r1.y = t1.y + b2f((unsigned short)tm[5]) + 2.f*a[5];
    r1.z = t1.z + b2f((unsigned short)tm[6]) + 2.f*a[6];
    r1.w = t1.w + b2f((unsigned short)tm[7]) + 2.f*a[7];
  }
  ((f4*)T)[o4]   = r0;
  ((f4*)T)[o4+1] = r1;
}

// ---------------- Y -> Yt: transpose, scale by sinv[k], cvt bf16. Yt[n][k] ----------------
template<int F>
__global__ __launch_bounds__(256) void k_downt(const float* __restrict__ Y, const float* __restrict__ sinv,
                                               short* __restrict__ Yt){
  __shared__ float tile[32][33];
  int tx = threadIdx.x & 31, ty = threadIdx.x >> 5;
  int k0 = blockIdx.x*32, n0 = blockIdx.y*32;
  #pragma unroll
  for (int u=0;u<32;u+=8) tile[ty+u][tx] = Y[(size_t)(k0+ty+u)*F + n0+tx];
  __syncthreads();
  float sv = sinv[k0+tx];
  #pragma unroll
  for (int u=0;u<32;u+=8) Yt[(size_t)(n0+ty+u)*NN + k0+tx] = f2b(tile[tx][ty+u] * sv);
}

// ---------------- fused attention: partials = P @ Ys ----------------
// BM=128, BN=256, BK=32, 512 threads = 8 waves (2M x 4N). K-split via blockIdx.z.
// Chunk-major LDS tiles zk[8c][32r], yt[4c][256r]: frag ds_read_b128 hits
// banks lo*4 mod 32 (2-way = free). All kz STORE partials (accum0 fallback).
template<int F>
__global__ __launch_bounds__(512, 4) void k_attn2(
    const short* __restrict__ Zb, const short* __restrict__ Ytg,
    P8 pp, int ksize, int accum0)
{
  __shared__ __align__(16) short zk[2][32*64];     // [c=0..7][row=0..31] 16B units
  __shared__ __align__(16) short yt[2][256*32];    // [c=0..3][row=0..255]
  __shared__ __align__(16) short p_lds[128*40];
  int t = threadIdx.x;
  int w = t >> 6, l = t & 63;
  int lo = l & 15, g = l >> 4;
  int m0 = blockIdx.x * 128;
  int n0 = blockIdx.y * 256;
  int kz = blockIdx.z;
  int kbeg = kz * ksize, kend = kbeg + ksize;
  int wm = w >> 2, wn = w & 3;

  const bf16x8* Zb8 = (const bf16x8*)Zb;
  int zirow = m0 + w*16 + lo;
  bf16x8 ziA0 = Zb8[(size_t)zirow*8 + g];
  bf16x8 ziA1 = Zb8[(size_t)zirow*8 + g + 4];

  f32x4 acc[4][4];
  #pragma unroll
  for (int i=0;i<4;i++)
    #pragma unroll
    for (int j=0;j<4;j++) acc[i][j] = (f32x4){0.f,0.f,0.f,0.f};

  auto STAGE = [&](int b, int kk){
    if (t < 256){
      // zk chunk-major: slot t -> chunk c=t>>5, row r=t&31; src row kk+r, chunk c
      const short* src = Zb + (((size_t)(kk + (t & 31))) << 6) + ((t >> 5) << 3);
      __builtin_amdgcn_global_load_lds((glb_short*)src, (lds_short*)&zk[b][t*8], 16, 0, 0);
    }
    #pragma unroll
    for (int p=0;p<2;p++){
      // yt chunk-major: slot cc -> chunk c=cc>>8, row r=cc&255
      int cc = p*512 + t;
      const short* src = Ytg + (size_t)(n0 + (cc & 255))*NN + kk + ((cc >> 8) << 3);
      __builtin_amdgcn_global_load_lds((glb_short*)src, (lds_short*)&yt[b][cc*8], 16, 0, 0);
    }
  };

  STAGE(0, kbeg);
  __syncthreads();

  int cur = 0;
  for (int k0 = kbeg; k0 < kend; k0 += 32){
    // ---- S phase: B-frags from chunk-major zk (conflict-free) ----
    bf16x8 b00 = *(const bf16x8*)&zk[cur][((g    )*32 + lo     )*8];
    bf16x8 b01 = *(const bf16x8*)&zk[cur][((g + 4)*32 + lo     )*8];
    bf16x8 b10 = *(const bf16x8*)&zk[cur][((g    )*32 + 16 + lo)*8];
    bf16x8 b11 = *(const bf16x8*)&zk[cur][((g + 4)*32 + 16 + lo)*8];
    f32x4 s0 = (f32x4){0.f,0.f,0.f,0.f};
    f32x4 s1 = (f32x4){0.f,0.f,0.f,0.f};
    s0 = __builtin_amdgcn_mfma_f32_16x16x32_bf16(ziA0, b00, s0, 0,0,0);
    s0 = __builtin_amdgcn_mfma_f32_16x16x32_bf16(ziA1, b01, s0, 0,0,0);
    s1 = __builtin_amdgcn_mfma_f32_16x16x32_bf16(ziA0, b10, s1, 0,0,0);
    s1 = __builtin_amdgcn_mfma_f32_16x16x32_bf16(ziA1, b11, s1, 0,0,0);
    short e0[4], e1[4];
    #pragma unroll
    for (int r=0;r<4;r++){
      e0[r] = f2b(__expf(fmaxf(s0[r],0.f) - CSHIFT));
      e1[r] = f2b(__expf(fmaxf(s1[r],0.f) - CSHIFT));
    }
    __syncthreads();                 // B1: all reads of both buffers retired
    if (k0 + 32 < kend) STAGE(cur ^ 1, k0 + 32);
    int prow = w*16 + g*4;
    #pragma unroll
    for (int r=0;r<4;r++){
      p_lds[(prow+r)*40 + lo]      = e0[r];
      p_lds[(prow+r)*40 + 16 + lo] = e1[r];
    }
    __syncthreads();                 // B2: staging drained, P visible
    // ---- PV phase ----
    bf16x8 aP[4];
    #pragma unroll
    for (int mf=0; mf<4; mf++)
      aP[mf] = *(const bf16x8*)&p_lds[(wm*64 + mf*16 + lo)*40 + g*8];
    #pragma unroll
    for (int nf=0; nf<4; nf++){
      int nl = wn*64 + nf*16 + lo;
      bf16x8 bY = *(const bf16x8*)&yt[cur][(g*256 + nl)*8];
      #pragma unroll
      for (int mf=0; mf<4; mf++)
        acc[mf][nf] = __builtin_amdgcn_mfma_f32_16x16x32_bf16(aP[mf], bY, acc[mf][nf], 0,0,0);
    }
    cur ^= 1;
  }
  float* outp = pp.p[kz];
  bool rmw = (accum0 && kz == 0);
  #pragma unroll
  for (int mf=0; mf<4; mf++){
    int row = m0 + wm*64 + mf*16 + g*4;
    #pragma unroll
    for (int nf=0; nf<4; nf++){
      int col = n0 + wn*64 + nf*16 + lo;
      #pragma unroll
      for (int r=0;r<4;r++){
        size_t o = (size_t)(row+r)*F + col;
        if (rmw) outp[o] += acc[mf][nf][r];
        else     outp[o]  = acc[mf][nf][r];
      }
    }
  }
}

// ---------------- partial merge: o += sum of ns partial buffers ----------------
__global__ __launch_bounds__(256) void k_accp(P8 s, int ns, f4* __restrict__ o, int n4){
  for (int i = blockIdx.x*256 + threadIdx.x; i < n4; i += gridDim.x*256){
    f4 r = o[i];
    for (int j=0;j<ns;j++){
      f4 x = ((const f4*)s.p[j])[i];
      r.x+=x.x; r.y+=x.y; r.z+=x.z; r.w+=x.w;
    }
    o[i] = r;
  }
}

// ---------------- head GEMM ----------------
template<int DIN, int FIN>
__global__ __launch_bounds__(256) void k_head(const float* __restrict__ T, const float* __restrict__ W,
                                              float* __restrict__ Hout){
  __shared__ float tt[16*DIN];
  int t = threadIdx.x;
  int j0 = blockIdx.x*16, b = blockIdx.y;
  const f4* T4 = (const f4*)T;
  for (int u=t; u<16*DIN/4; u+=256){
    int jj = u / (DIN/4), kq = u % (DIN/4);
    ((f4*)tt)[u] = T4[((size_t)(j0+jj)*FIN + b*DIN)/4 + kq];
  }
  __syncthreads();
  int oq = t & 31, jg = t >> 5;
  f4 a0 = {0,0,0,0}, a1 = {0,0,0,0};
  const f4* W4 = (const f4*)W;
  for (int k=0;k<DIN;k++){
    f4 wv = W4[k*32 + oq];
    float t0 = tt[(jg*2+0)*DIN + k];
    float t1 = tt[(jg*2+1)*DIN + k];
    a0.x += t0*wv.x; a0.y += t0*wv.y; a0.z += t0*wv.z; a0.w += t0*wv.w;
    a1.x += t1*wv.x; a1.y += t1*wv.y; a1.z += t1*wv.z; a1.w += t1*wv.w;
  }
  a0.x=fmaxf(a0.x,0.f); a0.y=fmaxf(a0.y,0.f); a0.z=fmaxf(a0.z,0.f); a0.w=fmaxf(a0.w,0.f);
  a1.x=fmaxf(a1.x,0.f); a1.y=fmaxf(a1.y,0.f); a1.z=fmaxf(a1.z,0.f); a1.w=fmaxf(a1.w,0.f);
  f4* H4 = (f4*)Hout;
  H4[(size_t)(j0+jg*2+0)*256 + b*32 + oq] = a0;
  H4[(size_t)(j0+jg*2+1)*256 + b*32 + oq] = a1;
}

// ---------------- final mean over nodes ----------------
__global__ __launch_bounds__(256) void k_reduce(const float* __restrict__ A, float* __restrict__ out){
  __shared__ float accl[1024];
  int t = threadIdx.x;
  for (int u=t; u<1024; u+=256) accl[u]=0.f;
  __syncthreads();
  int j0 = blockIdx.x*128;
  for (int j=j0; j<j0+128; j++){
    for (int u=t; u<1024; u+=256) accl[u] += A[(size_t)j*1024 + u];
  }
  __syncthreads();
  for (int u=t; u<1024; u+=256) atomicAdd(&out[u], accl[u]*(1.f/8192.f));
}

// ---------------- launcher ----------------
extern "C" void kernel_launch(void* const* d_in, const int* in_sizes, int n_in,
                              void* d_out, int out_size, void* d_ws, size_t ws_size,
                              hipStream_t stream){
  const int*   A1i = (const int*)d_in[0];
  const float* A1v = (const float*)d_in[1];
  const int*   A2i = (const int*)d_in[2];
  const float* A2v = (const float*)d_in[3];
  const float* X   = (const float*)d_in[4];
  const float* Z   = (const float*)d_in[5];
  const float* W1  = (const float*)d_in[6];
  const float* W2  = (const float*)d_in[7];
  float* out = (float*)d_out;

  char* w = (char*)d_ws;
  size_t off = 0;
  auto alloc = [&](size_t b)->char* {
    char* p = w + off;
    off += (b + 1023) & ~(size_t)1023;
    return p;
  };
  float* sb    = (float*)alloc(NN*4);
  int*   ptr1  = (int*)  alloc((NN+1)*4);
  int*   ptr2  = (int*)  alloc((NN+1)*4);
  int*   cnt   = (int*)  alloc(NN*4);
  int*   cidx1 = (int*)  alloc(NNZE*4);
  float* cval1 = (float*)alloc(NNZE*4);
  int*   cidx2 = (int*)  alloc(NNZE*4);
  float* cval2 = (float*)alloc(NNZE*4);
  short* Zbf   = (short*)alloc((size_t)NN*64*2);
  float* XT1   = (float*)alloc((size_t)NN*512*4);
  float* T1    = (float*)alloc((size_t)NN*512*4);    // adjacent to XT1
  float* HT    = (float*)alloc((size_t)NN*1024*4);
  float* TMP   = (float*)alloc((size_t)NN*1024*4);
  char*  PART  = alloc((size_t)32*1024*1024);        // 1 extra partial buffer
  bool   bigws = (off <= ws_size);

  const size_t MB = 1024*1024;
  float* T2   = XT1;                       // layer-2 T overlays XT1+T1 (32MB)
  short* Ysbt = (short*)TMP;               // Yt bf16 at TMP base (8/16MB)
  // bf16 spmm buffers (dead regions):
  short* XT1b  = (short*)HT;                          // 8 MB
  short* X1b1  = (short*)((char*)HT + 8*MB);          // 8 MB
  short* HTb   = (short*)TMP;                         // 16 MB
  short* X1b2  = (short*)((char*)TMP + 16*MB);        // 16 MB

  // CSR for A1, A2
  hipMemsetAsync(cnt, 0, NN*4, stream);
  k_count<<<NNZE/256, 256, 0, stream>>>(A1i, cnt);
  k_scan<<<1, 1024, 0, stream>>>(cnt, ptr1);
  hipMemcpyAsync(cnt, ptr1, NN*4, hipMemcpyDeviceToDevice, stream);
  k_fill<<<NNZE/256, 256, 0, stream>>>(A1i, A1v, cnt, cidx1, cval1);

  hipMemsetAsync(cnt, 0, NN*4, stream);
  k_count<<<NNZE/256, 256, 0, stream>>>(A2i, cnt);
  k_scan<<<1, 1024, 0, stream>>>(cnt, ptr2);
  hipMemcpyAsync(cnt, ptr2, NN*4, hipMemcpyDeviceToDevice, stream);
  k_fill<<<NNZE/256, 256, 0, stream>>>(A2i, A2v, cnt, cidx2, cval2);

  // Xt (node-major), Z bf16, softmax column sums
  k_transpose<512><<<dim3(NN/32, 512/32), 256, 0, stream>>>(X, XT1);
  k_zb<<<NN*64/256, 256, 0, stream>>>(Z, Zbf);
  hipMemsetAsync(sb, 0, NN*4, stream);
  k_colsum_mfma<<<dim3(NN/128, 8), 512, 0, stream>>>(Zbf, sb);
  k_recip<<<NN/256, 256, 0, stream>>>(sb);

  // ---- layer 1 (F=512) ----
  k_tobf<<<2048, 256, 0, stream>>>(XT1, XT1b, NN*512/8);
  k_spmmb<512><<<NN/4, 256, 0, stream>>>(ptr1, cidx1, cval1, XT1b, X1b1);
  k_chebb<512,true><<<NN/4, 256, 0, stream>>>(ptr1, cidx1, cval1, X1b1, XT1, T1);
  k_spmmb<512><<<NN/4, 256, 0, stream>>>(ptr2, cidx2, cval2, XT1b, X1b1);
  k_chebb<512,false><<<NN/4, 256, 0, stream>>>(ptr2, cidx2, cval2, X1b1, XT1, T1);
  k_downt<512><<<dim3(NN/32, 512/32), 256, 0, stream>>>(XT1, sb, Ysbt);
  {
    P8 pp{}; P8 ps{};
    if (bigws){
      // kz=4, all-store: 16MB partials in HT(2) + TMP tail(1) + PART(1)
      pp.p[0] = (float*)HT;                   ps.p[0] = pp.p[0];
      pp.p[1] = (float*)((char*)HT + 16*MB);  ps.p[1] = pp.p[1];
      pp.p[2] = (float*)((char*)TMP + 16*MB); ps.p[2] = pp.p[2];
      pp.p[3] = (float*)PART;                 ps.p[3] = pp.p[3];
      k_attn2<512><<<dim3(NN/128, 2, 4), 512, 0, stream>>>(Zbf, Ysbt, pp, NN/4, 0);
      k_accp<<<1024, 256, 0, stream>>>(ps, 4, (f4*)T1, NN*512/4);
    } else {
      pp.p[0] = T1;                           // accumulates (round-3 scheme)
      pp.p[1] = (float*)HT;                   ps.p[0] = pp.p[1];
      pp.p[2] = (float*)((char*)HT + 16*MB);  ps.p[1] = pp.p[2];
      pp.p[3] = (float*)((char*)TMP + 16*MB); ps.p[2] = pp.p[3];
      k_attn2<512><<<dim3(NN/128, 2, 4), 512, 0, stream>>>(Zbf, Ysbt, pp, NN/4, 1);
      k_accp<<<1024, 256, 0, stream>>>(ps, 3, (f4*)T1, NN*512/4);
    }
  }
  k_head<64,512><<<dim3(NN/16, 8), 256, 0, stream>>>(T1, W1, HT);

  // ---- layer 2 (F=1024), T2 overlays XT1/T1 ----
  k_tobf<<<2048, 256, 0, stream>>>(HT, HTb, NN*1024/8);
  k_spmmb<1024><<<NN/2, 256, 0, stream>>>(ptr1, cidx1, cval1, HTb, X1b2);
  k_chebb<1024,true><<<NN/2, 256, 0, stream>>>(ptr1, cidx1, cval1, X1b2, HT, T2);
  k_spmmb<1024><<<NN/2, 256, 0, stream>>>(ptr2, cidx2, cval2, HTb, X1b2);
  k_chebb<1024,false><<<NN/2, 256, 0, stream>>>(ptr2, cidx2, cval2, X1b2, HT, T2);
  k_downt<1024><<<dim3(NN/32, 1024/32), 256, 0, stream>>>(HT, sb, Ysbt);   // HT now dead
  {
    P8 pp{}; P8 ps{};
    if (bigws){
      // kz=2, all-store: 32MB partials in HT + PART
      pp.p[0] = (float*)HT;   ps.p[0] = pp.p[0];
      pp.p[1] = (float*)PART; ps.p[1] = pp.p[1];
      k_attn2<1024><<<dim3(NN/128, 4, 2), 512, 0, stream>>>(Zbf, Ysbt, pp, NN/2, 0);
      k_accp<<<2048, 256, 0, stream>>>(ps, 2, (f4*)T2, NN*1024/4);
    } else {
      pp.p[0] = T2;           // accumulates
      pp.p[1] = (float*)HT;   ps.p[0] = pp.p[1];
      k_attn2<1024><<<dim3(NN/128, 4, 2), 512, 0, stream>>>(Zbf, Ysbt, pp, NN/2, 1);
      k_accp<<<2048, 256, 0, stream>>>(ps, 1, (f4*)T2, NN*1024/4);
    }
  }
  k_head<128,1024><<<dim3(NN/16, 8), 256, 0, stream>>>(T2, W2, HT);

  hipMemsetAsync(out, 0, 1024*4, stream);
  k_reduce<<<64, 256, 0, stream>>>(HT, out);
}

// Round 8
// 914.106 us; speedup vs baseline: 1.4271x; 1.0349x over previous
//
#include <hip/hip_runtime.h>

// GWNet on MI355X — round 8.
// - attn: deeper K-split (1024 blocks = 3 resident/CU vs grid-limited 2),
//   bf16 all-store partials (half the partial bytes), chunk-major LDS kept.
// - Fusions: k_transpose/k_head emit bf16 copies (k_tobf deleted);
//   partial merge folded into k_head LDS-fill (k_accp deleted on main path).
// - bf16 spmm/Chebyshev chain unchanged.

#define NN 8192
#define NNZE 131072
#define CSHIFT 48.0f

typedef float4 f4;
typedef __attribute__((ext_vector_type(8))) short bf16x8;
typedef __attribute__((ext_vector_type(4))) float f32x4;

typedef __attribute__((address_space(3))) short lds_short;
typedef __attribute__((address_space(1))) const short glb_short;

struct P8s { short* p[8]; };

__device__ inline short f2b(float x){
  unsigned u = __float_as_uint(x);
  unsigned r = (u + 0x7fffu + ((u >> 16) & 1u)) >> 16;
  return (short)r;
}
__device__ inline float b2f(unsigned short b){
  return __uint_as_float(((unsigned)b) << 16);
}

// ---------------- CSR build ----------------
__global__ __launch_bounds__(256) void k_count(const int* __restrict__ idx, int* __restrict__ cnt){
  int e = blockIdx.x*256 + threadIdx.x;
  if (e < NNZE) atomicAdd(&cnt[idx[e]], 1);
}

__global__ __launch_bounds__(1024) void k_scan(const int* __restrict__ cnt, int* __restrict__ ptr){
  __shared__ int sums[1024];
  int t = threadIdx.x;
  int loc[8]; int s = 0;
  #pragma unroll
  for (int i=0;i<8;i++){ loc[i]=s; s += cnt[t*8+i]; }
  sums[t]=s; __syncthreads();
  for (int off=1; off<1024; off<<=1){
    int v = (t>=off) ? sums[t-off] : 0;
    __syncthreads();
    sums[t] += v;
    __syncthreads();
  }
  int excl = sums[t]-s;
  #pragma unroll
  for (int i=0;i<8;i++) ptr[t*8+i] = excl + loc[i];
  if (t==1023) ptr[NN] = sums[1023];
}

__global__ __launch_bounds__(256) void k_fill(const int* __restrict__ idx, const float* __restrict__ vals,
                                              int* __restrict__ cur, int* __restrict__ cidx, float* __restrict__ cval){
  int e = blockIdx.x*256 + threadIdx.x;
  if (e < NNZE){
    int r = idx[e], c = idx[NNZE+e];
    int p = atomicAdd(&cur[r], 1);
    cidx[p] = c; cval[p] = vals[e];
  }
}

// ---------------- transpose X (R,NN)->(NN,R), f32 + bf16 outputs ----------------
template<int R>
__global__ __launch_bounds__(256) void k_transpose_b(const float* __restrict__ src, float* __restrict__ dst,
                                                     short* __restrict__ dstb){
  __shared__ float tile[32][33];
  int tx = threadIdx.x & 31, ty = threadIdx.x >> 5;
  int j0 = blockIdx.x*32, f0 = blockIdx.y*32;
  #pragma unroll
  for (int u=0;u<32;u+=8) tile[ty+u][tx] = src[(size_t)(f0+ty+u)*NN + j0+tx];
  __syncthreads();
  #pragma unroll
  for (int u=0;u<32;u+=8){
    float v = tile[tx][ty+u];
    size_t o = (size_t)(j0+ty+u)*R + f0+tx;
    dst[o] = v;
    dstb[o] = f2b(v);
  }
}

// ---------------- Z -> bf16 ----------------
__global__ __launch_bounds__(256) void k_zb(const float* __restrict__ Z, short* __restrict__ Zb){
  int i = blockIdx.x*256 + threadIdx.x;
  Zb[i] = f2b(Z[i]);
}

// ---------------- column sums via MFMA: sb[j] = sum_i exp(relu(zi.zj) - C) ----------------
__global__ __launch_bounds__(512) void k_colsum_mfma(const short* __restrict__ Zb, float* __restrict__ sb){
  int t = threadIdx.x;
  int w = t >> 6, l = t & 63;
  int lo = l & 15, g = l >> 4;
  int j = blockIdx.x*128 + w*16 + lo;
  const bf16x8* Zb8 = (const bf16x8*)Zb;
  bf16x8 bj0 = Zb8[j*8 + g];
  bf16x8 bj1 = Zb8[j*8 + g + 4];
  int i0 = blockIdx.y * (NN/8);
  float sum = 0.f;
  for (int i = i0; i < i0 + NN/8; i += 16){
    bf16x8 a0 = Zb8[(size_t)(i+lo)*8 + g];
    bf16x8 a1 = Zb8[(size_t)(i+lo)*8 + g + 4];
    f32x4 s = (f32x4){0.f,0.f,0.f,0.f};
    s = __builtin_amdgcn_mfma_f32_16x16x32_bf16(a0, bj0, s, 0,0,0);
    s = __builtin_amdgcn_mfma_f32_16x16x32_bf16(a1, bj1, s, 0,0,0);
    #pragma unroll
    for (int r=0;r<4;r++) sum += __expf(fmaxf(s[r],0.f) - CSHIFT);
  }
  sum += __shfl_xor(sum, 16);
  sum += __shfl_xor(sum, 32);
  if (g == 0) atomicAdd(sb + j, sum);
}

__global__ __launch_bounds__(256) void k_recip(float* s){
  int i = blockIdx.x*256 + threadIdx.x;
  if (i < NN) s[i] = 1.0f/s[i];
}

// ---------------- bf16 spmm: outb[r][:] = bf16( sum_e v * Yb[c][:] ) ----------------
template<int F>
__global__ __launch_bounds__(256) void k_spmmb(const int* __restrict__ ptr, const int* __restrict__ cidx,
                                               const float* __restrict__ cval, const short* __restrict__ Yb,
                                               short* __restrict__ outb){
  constexpr int LPR = F/8;
  int t = threadIdx.x;
  int r = blockIdx.x*(256/LPR) + t/LPR;
  int ts = t % LPR;
  const bf16x8* Y8 = (const bf16x8*)Yb;
  int p0 = ptr[r], p1 = ptr[r+1];
  float a[8];
  #pragma unroll
  for (int j=0;j<8;j++) a[j]=0.f;
  int p = p0;
  for (; p+1 < p1; p += 2){
    int c0 = cidx[p],   c1 = cidx[p+1];
    float v0 = cval[p], v1 = cval[p+1];
    bf16x8 x0 = Y8[(size_t)c0*LPR + ts];
    bf16x8 x1 = Y8[(size_t)c1*LPR + ts];
    #pragma unroll
    for (int j=0;j<8;j++) a[j] += v0*b2f((unsigned short)x0[j]);
    #pragma unroll
    for (int j=0;j<8;j++) a[j] += v1*b2f((unsigned short)x1[j]);
  }
  if (p < p1){
    int c0 = cidx[p]; float v0 = cval[p];
    bf16x8 x0 = Y8[(size_t)c0*LPR + ts];
    #pragma unroll
    for (int j=0;j<8;j++) a[j] += v0*b2f((unsigned short)x0[j]);
  }
  bf16x8 o;
  #pragma unroll
  for (int j=0;j<8;j++) o[j] = f2b(a[j]);
  ((bf16x8*)outb)[(size_t)r*LPR + ts] = o;
}

// ---------------- cheb epilogue: T (=/+=) x1 + 2*A.x1 (+ -Y if FIRST), f32 out ----------------
template<int F, bool FIRST>
__global__ __launch_bounds__(256) void k_chebb(const int* __restrict__ ptr, const int* __restrict__ cidx,
                                               const float* __restrict__ cval, const short* __restrict__ X1b,
                                               const float* __restrict__ Yf, float* __restrict__ T){
  constexpr int LPR = F/8;
  int t = threadIdx.x;
  int r = blockIdx.x*(256/LPR) + t/LPR;
  int ts = t % LPR;
  const bf16x8* X8 = (const bf16x8*)X1b;
  int p0 = ptr[r], p1 = ptr[r+1];
  float a[8];
  #pragma unroll
  for (int j=0;j<8;j++) a[j]=0.f;
  int p = p0;
  for (; p+1 < p1; p += 2){
    int c0 = cidx[p],   c1 = cidx[p+1];
    float v0 = cval[p], v1 = cval[p+1];
    bf16x8 x0 = X8[(size_t)c0*LPR + ts];
    bf16x8 x1 = X8[(size_t)c1*LPR + ts];
    #pragma unroll
    for (int j=0;j<8;j++) a[j] += v0*b2f((unsigned short)x0[j]);
    #pragma unroll
    for (int j=0;j<8;j++) a[j] += v1*b2f((unsigned short)x1[j]);
  }
  if (p < p1){
    int c0 = cidx[p]; float v0 = cval[p];
    bf16x8 x0 = X8[(size_t)c0*LPR + ts];
    #pragma unroll
    for (int j=0;j<8;j++) a[j] += v0*b2f((unsigned short)x0[j]);
  }
  bf16x8 tm = X8[(size_t)r*LPR + ts];
  size_t o4 = ((size_t)r*F + ts*8) >> 2;
  f4 r0, r1;
  if (FIRST){
    f4 y0 = ((const f4*)Yf)[o4], y1 = ((const f4*)Yf)[o4+1];
    r0.x = b2f((unsigned short)tm[0]) + 2.f*a[0] - y0.x;
    r0.y = b2f((unsigned short)tm[1]) + 2.f*a[1] - y0.y;
    r0.z = b2f((unsigned short)tm[2]) + 2.f*a[2] - y0.z;
    r0.w = b2f((unsigned short)tm[3]) + 2.f*a[3] - y0.w;
    r1.x = b2f((unsigned short)tm[4]) + 2.f*a[4] - y1.x;
    r1.y = b2f((unsigned short)tm[5]) + 2.f*a[5] - y1.y;
    r1.z = b2f((unsigned short)tm[6]) + 2.f*a[6] - y1.z;
    r1.w = b2f((unsigned short)tm[7]) + 2.f*a[7] - y1.w;
  } else {
    f4 t0 = ((const f4*)T)[o4], t1 = ((const f4*)T)[o4+1];
    r0.x = t0.x + b2f((unsigned short)tm[0]) + 2.f*a[0];
    r0.y = t0.y + b2f((unsigned short)tm[1]) + 2.f*a[1];
    r0.z = t0.z + b2f((unsigned short)tm[2]) + 2.f*a[2];
    r0.w = t0.w + b2f((unsigned short)tm[3]) + 2.f*a[3];
    r1.x = t1.x + b2f((unsigned short)tm[4]) + 2.f*a[4];
    r1.y = t1.y + b2f((unsigned short)tm[5]) + 2.f*a[5];
    r1.z = t1.z + b2f((unsigned short)tm[6]) + 2.f*a[6];
    r1.w = t1.w + b2f((unsigned short)tm[7]) + 2.f*a[7];
  }
  ((f4*)T)[o4]   = r0;
  ((f4*)T)[o4+1] = r1;
}

// ---------------- Y -> Yt: transpose, scale by sinv[k], cvt bf16. Yt[n][k] ----------------
template<int F>
__global__ __launch_bounds__(256) void k_downt(const float* __restrict__ Y, const float* __restrict__ sinv,
                                               short* __restrict__ Yt){
  __shared__ float tile[32][33];
  int tx = threadIdx.x & 31, ty = threadIdx.x >> 5;
  int k0 = blockIdx.x*32, n0 = blockIdx.y*32;
  #pragma unroll
  for (int u=0;u<32;u+=8) tile[ty+u][tx] = Y[(size_t)(k0+ty+u)*F + n0+tx];
  __syncthreads();
  float sv = sinv[k0+tx];
  #pragma unroll
  for (int u=0;u<32;u+=8) Yt[(size_t)(n0+ty+u)*NN + k0+tx] = f2b(tile[tx][ty+u] * sv);
}

// ---------------- fused attention: bf16 partial[kz] = P @ Ys (k-slice) ----------------
// BM=128, BN=256, BK=32, 512 threads = 8 waves (2M x 4N). Chunk-major LDS.
template<int F>
__global__ __launch_bounds__(512, 4) void k_attn2(
    const short* __restrict__ Zb, const short* __restrict__ Ytg,
    P8s pp, int ksize)
{
  __shared__ __align__(16) short zk[2][32*64];     // [c=0..7][row=0..31] 16B units
  __shared__ __align__(16) short yt[2][256*32];    // [c=0..3][row=0..255]
  __shared__ __align__(16) short p_lds[128*40];
  int t = threadIdx.x;
  int w = t >> 6, l = t & 63;
  int lo = l & 15, g = l >> 4;
  int m0 = blockIdx.x * 128;
  int n0 = blockIdx.y * 256;
  int kz = blockIdx.z;
  int kbeg = kz * ksize, kend = kbeg + ksize;
  int wm = w >> 2, wn = w & 3;

  const bf16x8* Zb8 = (const bf16x8*)Zb;
  int zirow = m0 + w*16 + lo;
  bf16x8 ziA0 = Zb8[(size_t)zirow*8 + g];
  bf16x8 ziA1 = Zb8[(size_t)zirow*8 + g + 4];

  f32x4 acc[4][4];
  #pragma unroll
  for (int i=0;i<4;i++)
    #pragma unroll
    for (int j=0;j<4;j++) acc[i][j] = (f32x4){0.f,0.f,0.f,0.f};

  auto STAGE = [&](int b, int kk){
    if (t < 256){
      const short* src = Zb + (((size_t)(kk + (t & 31))) << 6) + ((t >> 5) << 3);
      __builtin_amdgcn_global_load_lds((glb_short*)src, (lds_short*)&zk[b][t*8], 16, 0, 0);
    }
    #pragma unroll
    for (int p=0;p<2;p++){
      int cc = p*512 + t;
      const short* src = Ytg + (size_t)(n0 + (cc & 255))*NN + kk + ((cc >> 8) << 3);
      __builtin_amdgcn_global_load_lds((glb_short*)src, (lds_short*)&yt[b][cc*8], 16, 0, 0);
    }
  };

  STAGE(0, kbeg);
  __syncthreads();

  int cur = 0;
  for (int k0 = kbeg; k0 < kend; k0 += 32){
    bf16x8 b00 = *(const bf16x8*)&zk[cur][((g    )*32 + lo     )*8];
    bf16x8 b01 = *(const bf16x8*)&zk[cur][((g + 4)*32 + lo     )*8];
    bf16x8 b10 = *(const bf16x8*)&zk[cur][((g    )*32 + 16 + lo)*8];
    bf16x8 b11 = *(const bf16x8*)&zk[cur][((g + 4)*32 + 16 + lo)*8];
    f32x4 s0 = (f32x4){0.f,0.f,0.f,0.f};
    f32x4 s1 = (f32x4){0.f,0.f,0.f,0.f};
    s0 = __builtin_amdgcn_mfma_f32_16x16x32_bf16(ziA0, b00, s0, 0,0,0);
    s0 = __builtin_amdgcn_mfma_f32_16x16x32_bf16(ziA1, b01, s0, 0,0,0);
    s1 = __builtin_amdgcn_mfma_f32_16x16x32_bf16(ziA0, b10, s1, 0,0,0);
    s1 = __builtin_amdgcn_mfma_f32_16x16x32_bf16(ziA1, b11, s1, 0,0,0);
    short e0[4], e1[4];
    #pragma unroll
    for (int r=0;r<4;r++){
      e0[r] = f2b(__expf(fmaxf(s0[r],0.f) - CSHIFT));
      e1[r] = f2b(__expf(fmaxf(s1[r],0.f) - CSHIFT));
    }
    __syncthreads();                 // B1: all reads of both buffers retired
    if (k0 + 32 < kend) STAGE(cur ^ 1, k0 + 32);
    int prow = w*16 + g*4;
    #pragma unroll
    for (int r=0;r<4;r++){
      p_lds[(prow+r)*40 + lo]      = e0[r];
      p_lds[(prow+r)*40 + 16 + lo] = e1[r];
    }
    __syncthreads();                 // B2: staging drained, P visible
    bf16x8 aP[4];
    #pragma unroll
    for (int mf=0; mf<4; mf++)
      aP[mf] = *(const bf16x8*)&p_lds[(wm*64 + mf*16 + lo)*40 + g*8];
    #pragma unroll
    for (int nf=0; nf<4; nf++){
      int nl = wn*64 + nf*16 + lo;
      bf16x8 bY = *(const bf16x8*)&yt[cur][(g*256 + nl)*8];
      #pragma unroll
      for (int mf=0; mf<4; mf++)
        acc[mf][nf] = __builtin_amdgcn_mfma_f32_16x16x32_bf16(aP[mf], bY, acc[mf][nf], 0,0,0);
    }
    cur ^= 1;
  }
  short* outp = pp.p[kz];
  #pragma unroll
  for (int mf=0; mf<4; mf++){
    int row = m0 + wm*64 + mf*16 + g*4;
    #pragma unroll
    for (int nf=0; nf<4; nf++){
      int col = n0 + wn*64 + nf*16 + lo;
      #pragma unroll
      for (int r=0;r<4;r++)
        outp[(size_t)(row+r)*F + col] = f2b(acc[mf][nf][r]);
    }
  }
}

// ---------------- bf16 partial merge (fallback path): o += sum partials ----------------
__global__ __launch_bounds__(256) void k_accpb(P8s s, int ns, float* __restrict__ o, int n8){
  for (int i = blockIdx.x*256 + threadIdx.x; i < n8; i += gridDim.x*256){
    f4 v0 = ((f4*)o)[2*i], v1 = ((f4*)o)[2*i+1];
    for (int j=0;j<ns;j++){
      bf16x8 p = ((const bf16x8*)s.p[j])[i];
      v0.x += b2f((unsigned short)p[0]); v0.y += b2f((unsigned short)p[1]);
      v0.z += b2f((unsigned short)p[2]); v0.w += b2f((unsigned short)p[3]);
      v1.x += b2f((unsigned short)p[4]); v1.y += b2f((unsigned short)p[5]);
      v1.z += b2f((unsigned short)p[6]); v1.w += b2f((unsigned short)p[7]);
    }
    ((f4*)o)[2*i] = v0; ((f4*)o)[2*i+1] = v1;
  }
}

// ---------------- head GEMM with fused partial merge + optional bf16 out ----------------
// Hout[j, b*128+o] = relu( sum_k (T[j,b*DIN+k] + sum_p part[p][j,b*DIN+k]) * W[k,o] )
template<int DIN, int FIN>
__global__ __launch_bounds__(256) void k_headm(const float* __restrict__ T, P8s parts, int np,
                                               const float* __restrict__ W,
                                               float* __restrict__ Hout, short* __restrict__ HoutB){
  __shared__ float tt[16*DIN];
  int t = threadIdx.x;
  int j0 = blockIdx.x*16, b = blockIdx.y;
  for (int u=t; u<16*DIN/8; u+=256){
    int jj = u / (DIN/8), k8 = u % (DIN/8);
    size_t base = (size_t)(j0+jj)*FIN + b*DIN + k8*8;
    f4 x0 = *(const f4*)(T + base);
    f4 x1 = *(const f4*)(T + base + 4);
    float v[8] = {x0.x,x0.y,x0.z,x0.w,x1.x,x1.y,x1.z,x1.w};
    for (int j=0;j<np;j++){
      bf16x8 p = *(const bf16x8*)(parts.p[j] + base);
      #pragma unroll
      for (int q=0;q<8;q++) v[q] += b2f((unsigned short)p[q]);
    }
    #pragma unroll
    for (int q=0;q<8;q++) tt[jj*DIN + k8*8 + q] = v[q];
  }
  __syncthreads();
  int oq = t & 31, jg = t >> 5;
  f4 a0 = {0,0,0,0}, a1 = {0,0,0,0};
  const f4* W4 = (const f4*)W;
  for (int k=0;k<DIN;k++){
    f4 wv = W4[k*32 + oq];
    float t0 = tt[(jg*2+0)*DIN + k];
    float t1 = tt[(jg*2+1)*DIN + k];
    a0.x += t0*wv.x; a0.y += t0*wv.y; a0.z += t0*wv.z; a0.w += t0*wv.w;
    a1.x += t1*wv.x; a1.y += t1*wv.y; a1.z += t1*wv.z; a1.w += t1*wv.w;
  }
  a0.x=fmaxf(a0.x,0.f); a0.y=fmaxf(a0.y,0.f); a0.z=fmaxf(a0.z,0.f); a0.w=fmaxf(a0.w,0.f);
  a1.x=fmaxf(a1.x,0.f); a1.y=fmaxf(a1.y,0.f); a1.z=fmaxf(a1.z,0.f); a1.w=fmaxf(a1.w,0.f);
  f4* H4 = (f4*)Hout;
  int j1 = j0 + jg*2, col = b*32 + oq;
  H4[(size_t)(j1+0)*256 + col] = a0;
  H4[(size_t)(j1+1)*256 + col] = a1;
  if (HoutB){
    short4 s0, s1;
    s0.x=f2b(a0.x); s0.y=f2b(a0.y); s0.z=f2b(a0.z); s0.w=f2b(a0.w);
    s1.x=f2b(a1.x); s1.y=f2b(a1.y); s1.z=f2b(a1.z); s1.w=f2b(a1.w);
    *(short4*)(HoutB + (size_t)(j1+0)*1024 + col*4) = s0;
    *(short4*)(HoutB + (size_t)(j1+1)*1024 + col*4) = s1;
  }
}

// ---------------- final mean over nodes ----------------
__global__ __launch_bounds__(256) void k_reduce(const float* __restrict__ A, float* __restrict__ out){
  __shared__ float accl[1024];
  int t = threadIdx.x;
  for (int u=t; u<1024; u+=256) accl[u]=0.f;
  __syncthreads();
  int j0 = blockIdx.x*128;
  for (int j=j0; j<j0+128; j++){
    for (int u=t; u<1024; u+=256) accl[u] += A[(size_t)j*1024 + u];
  }
  __syncthreads();
  for (int u=t; u<1024; u+=256) atomicAdd(&out[u], accl[u]*(1.f/8192.f));
}

// ---------------- launcher ----------------
extern "C" void kernel_launch(void* const* d_in, const int* in_sizes, int n_in,
                              void* d_out, int out_size, void* d_ws, size_t ws_size,
                              hipStream_t stream){
  const int*   A1i = (const int*)d_in[0];
  const float* A1v = (const float*)d_in[1];
  const int*   A2i = (const int*)d_in[2];
  const float* A2v = (const float*)d_in[3];
  const float* X   = (const float*)d_in[4];
  const float* Z   = (const float*)d_in[5];
  const float* W1  = (const float*)d_in[6];
  const float* W2  = (const float*)d_in[7];
  float* out = (float*)d_out;

  char* w = (char*)d_ws;
  size_t off = 0;
  auto alloc = [&](size_t b)->char* {
    char* p = w + off;
    off += (b + 1023) & ~(size_t)1023;
    return p;
  };
  float* sb    = (float*)alloc(NN*4);
  int*   ptr1  = (int*)  alloc((NN+1)*4);
  int*   ptr2  = (int*)  alloc((NN+1)*4);
  int*   cnt   = (int*)  alloc(NN*4);
  int*   cidx1 = (int*)  alloc(NNZE*4);
  float* cval1 = (float*)alloc(NNZE*4);
  int*   cidx2 = (int*)  alloc(NNZE*4);
  float* cval2 = (float*)alloc(NNZE*4);
  short* Zbf   = (short*)alloc((size_t)NN*64*2);
  float* XT1   = (float*)alloc((size_t)NN*512*4);
  float* T1    = (float*)alloc((size_t)NN*512*4);    // adjacent to XT1 (T2 = 32MB overlay)
  float* HT    = (float*)alloc((size_t)NN*1024*4);
  float* TMP   = (float*)alloc((size_t)NN*1024*4);
  char*  PART  = alloc((size_t)64*1024*1024);        // bf16 partial region
  bool   bigws = (off <= ws_size);

  const size_t MB = 1024*1024;
  float* T2   = XT1;                       // layer-2 T overlays XT1+T1 (32MB)
  short* Ysbt = (short*)TMP;               // Yt bf16 at TMP base (8/16MB)
  short* XT1b = (short*)HT;                // 8 MB (dead before head1)
  short* X1b1 = (short*)((char*)HT + 8*MB);// 8 MB
  short* HTb  = (short*)TMP;               // 16 MB (written by head1; dead before downt2)
  short* X1b2 = (short*)((char*)TMP + 16*MB); // 16 MB

  // CSR for A1, A2
  hipMemsetAsync(cnt, 0, NN*4, stream);
  k_count<<<NNZE/256, 256, 0, stream>>>(A1i, cnt);
  k_scan<<<1, 1024, 0, stream>>>(cnt, ptr1);
  hipMemcpyAsync(cnt, ptr1, NN*4, hipMemcpyDeviceToDevice, stream);
  k_fill<<<NNZE/256, 256, 0, stream>>>(A1i, A1v, cnt, cidx1, cval1);

  hipMemsetAsync(cnt, 0, NN*4, stream);
  k_count<<<NNZE/256, 256, 0, stream>>>(A2i, cnt);
  k_scan<<<1, 1024, 0, stream>>>(cnt, ptr2);
  hipMemcpyAsync(cnt, ptr2, NN*4, hipMemcpyDeviceToDevice, stream);
  k_fill<<<NNZE/256, 256, 0, stream>>>(A2i, A2v, cnt, cidx2, cval2);

  // Xt (node-major, f32 + bf16), Z bf16, softmax column sums
  k_transpose_b<512><<<dim3(NN/32, 512/32), 256, 0, stream>>>(X, XT1, XT1b);
  k_zb<<<NN*64/256, 256, 0, stream>>>(Z, Zbf);
  hipMemsetAsync(sb, 0, NN*4, stream);
  k_colsum_mfma<<<dim3(NN/128, 8), 512, 0, stream>>>(Zbf, sb);
  k_recip<<<NN/256, 256, 0, stream>>>(sb);

  // ---- layer 1 (F=512) ----
  k_spmmb<512><<<NN/4, 256, 0, stream>>>(ptr1, cidx1, cval1, XT1b, X1b1);
  k_chebb<512,true><<<NN/4, 256, 0, stream>>>(ptr1, cidx1, cval1, X1b1, XT1, T1);
  k_spmmb<512><<<NN/4, 256, 0, stream>>>(ptr2, cidx2, cval2, XT1b, X1b1);
  k_chebb<512,false><<<NN/4, 256, 0, stream>>>(ptr2, cidx2, cval2, X1b1, XT1, T1);
  k_downt<512><<<dim3(NN/32, 512/32), 256, 0, stream>>>(XT1, sb, Ysbt);
  if (bigws){
    P8s pp{};
    for (int i=0;i<8;i++) pp.p[i] = (short*)(PART + (size_t)i*8*MB);
    k_attn2<512><<<dim3(NN/128, 2, 8), 512, 0, stream>>>(Zbf, Ysbt, pp, NN/8);
    k_headm<64,512><<<dim3(NN/16, 8), 256, 0, stream>>>(T1, pp, 8, W1, HT, HTb);
  } else {
    P8s pp{};
    for (int i=0;i<4;i++) pp.p[i] = (short*)((char*)HT + (size_t)i*8*MB);
    k_attn2<512><<<dim3(NN/128, 2, 4), 512, 0, stream>>>(Zbf, Ysbt, pp, NN/4);
    k_accpb<<<1024, 256, 0, stream>>>(pp, 4, T1, NN*512/8);
    P8s np{};
    k_headm<64,512><<<dim3(NN/16, 8), 256, 0, stream>>>(T1, np, 0, W1, HT, HTb);
  }

  // ---- layer 2 (F=1024), T2 overlays XT1/T1 ----
  k_spmmb<1024><<<NN/2, 256, 0, stream>>>(ptr1, cidx1, cval1, HTb, X1b2);
  k_chebb<1024,true><<<NN/2, 256, 0, stream>>>(ptr1, cidx1, cval1, X1b2, HT, T2);
  k_spmmb<1024><<<NN/2, 256, 0, stream>>>(ptr2, cidx2, cval2, HTb, X1b2);
  k_chebb<1024,false><<<NN/2, 256, 0, stream>>>(ptr2, cidx2, cval2, X1b2, HT, T2);
  k_downt<1024><<<dim3(NN/32, 1024/32), 256, 0, stream>>>(HT, sb, Ysbt);  // HTb dead now
  if (bigws){
    P8s pp{};
    pp.p[0] = X1b2 /* TMP[16:32], dead */;
    for (int i=0;i<3;i++) pp.p[1+i] = (short*)(PART + (size_t)i*16*MB);
    k_attn2<1024><<<dim3(NN/128, 4, 4), 512, 0, stream>>>(Zbf, Ysbt, pp, NN/4);
    k_headm<128,1024><<<dim3(NN/16, 8), 256, 0, stream>>>(T2, pp, 4, W2, HT, nullptr);
  } else {
    P8s pp{};
    pp.p[0] = (short*)HT;
    pp.p[1] = (short*)((char*)HT + 16*MB);
    k_attn2<1024><<<dim3(NN/128, 4, 2), 512, 0, stream>>>(Zbf, Ysbt, pp, NN/2);
    k_accpb<<<2048, 256, 0, stream>>>(pp, 2, T2, NN*1024/8);
    P8s np{};
    k_headm<128,1024><<<dim3(NN/16, 8), 256, 0, stream>>>(T2, np, 0, W2, HT, nullptr);
  }

  hipMemsetAsync(out, 0, 1024*4, stream);
  k_reduce<<<64, 256, 0, stream>>>(HT, out);
}

// Round 9
// 864.090 us; speedup vs baseline: 1.5097x; 1.0579x over previous
//
#include <hip/hip_runtime.h>

// GWNet on MI355X — round 9.
// - Gather chain fused: k_spmm2 (both adjacencies, one launch) + k_cheb2
//   (single T pass: T = x1a + x1b + 2A1x1a + 2A2x1b - Y). 4-deep edge unroll.
// - All side streams bf16 (Y reads, H between layers, layer-1 Yt direct from X).
// - attn: round-7 grids (F=1024 kz=2, F=512 kz=4), bf16 all-store partials,
//   chunk-major LDS (structure at its 2-barrier ceiling, left unchanged).

#define NN 8192
#define NNZE 131072
#define CSHIFT 48.0f

typedef float4 f4;
typedef __attribute__((ext_vector_type(8))) short bf16x8;
typedef __attribute__((ext_vector_type(4))) float f32x4;

typedef __attribute__((address_space(3))) short lds_short;
typedef __attribute__((address_space(1))) const short glb_short;

struct P8s { short* p[8]; };

__device__ inline short f2b(float x){
  unsigned u = __float_as_uint(x);
  unsigned r = (u + 0x7fffu + ((u >> 16) & 1u)) >> 16;
  return (short)r;
}
__device__ inline float b2f(unsigned short b){
  return __uint_as_float(((unsigned)b) << 16);
}

// ---------------- CSR build ----------------
__global__ __launch_bounds__(256) void k_count(const int* __restrict__ idx, int* __restrict__ cnt){
  int e = blockIdx.x*256 + threadIdx.x;
  if (e < NNZE) atomicAdd(&cnt[idx[e]], 1);
}

__global__ __launch_bounds__(1024) void k_scan(const int* __restrict__ cnt, int* __restrict__ ptr){
  __shared__ int sums[1024];
  int t = threadIdx.x;
  int loc[8]; int s = 0;
  #pragma unroll
  for (int i=0;i<8;i++){ loc[i]=s; s += cnt[t*8+i]; }
  sums[t]=s; __syncthreads();
  for (int off=1; off<1024; off<<=1){
    int v = (t>=off) ? sums[t-off] : 0;
    __syncthreads();
    sums[t] += v;
    __syncthreads();
  }
  int excl = sums[t]-s;
  #pragma unroll
  for (int i=0;i<8;i++) ptr[t*8+i] = excl + loc[i];
  if (t==1023) ptr[NN] = sums[1023];
}

__global__ __launch_bounds__(256) void k_fill(const int* __restrict__ idx, const float* __restrict__ vals,
                                              int* __restrict__ cur, int* __restrict__ cidx, float* __restrict__ cval){
  int e = blockIdx.x*256 + threadIdx.x;
  if (e < NNZE){
    int r = idx[e], c = idx[NNZE+e];
    int p = atomicAdd(&cur[r], 1);
    cidx[p] = c; cval[p] = vals[e];
  }
}

// ---------------- transpose X (R,NN)->(NN,R) bf16 ----------------
template<int R>
__global__ __launch_bounds__(256) void k_transb(const float* __restrict__ src, short* __restrict__ dstb){
  __shared__ float tile[32][33];
  int tx = threadIdx.x & 31, ty = threadIdx.x >> 5;
  int j0 = blockIdx.x*32, f0 = blockIdx.y*32;
  #pragma unroll
  for (int u=0;u<32;u+=8) tile[ty+u][tx] = src[(size_t)(f0+ty+u)*NN + j0+tx];
  __syncthreads();
  #pragma unroll
  for (int u=0;u<32;u+=8) dstb[(size_t)(j0+ty+u)*R + f0+tx] = f2b(tile[tx][ty+u]);
}

// ---------------- Z -> bf16 ----------------
__global__ __launch_bounds__(256) void k_zb(const float* __restrict__ Z, short* __restrict__ Zb){
  int i = blockIdx.x*256 + threadIdx.x;
  Zb[i] = f2b(Z[i]);
}

// ---------------- column sums via MFMA: sb[j] = sum_i exp(relu(zi.zj) - C) ----------------
__global__ __launch_bounds__(512) void k_colsum_mfma(const short* __restrict__ Zb, float* __restrict__ sb){
  int t = threadIdx.x;
  int w = t >> 6, l = t & 63;
  int lo = l & 15, g = l >> 4;
  int j = blockIdx.x*128 + w*16 + lo;
  const bf16x8* Zb8 = (const bf16x8*)Zb;
  bf16x8 bj0 = Zb8[j*8 + g];
  bf16x8 bj1 = Zb8[j*8 + g + 4];
  int i0 = blockIdx.y * (NN/8);
  float sum = 0.f;
  for (int i = i0; i < i0 + NN/8; i += 16){
    bf16x8 a0 = Zb8[(size_t)(i+lo)*8 + g];
    bf16x8 a1 = Zb8[(size_t)(i+lo)*8 + g + 4];
    f32x4 s = (f32x4){0.f,0.f,0.f,0.f};
    s = __builtin_amdgcn_mfma_f32_16x16x32_bf16(a0, bj0, s, 0,0,0);
    s = __builtin_amdgcn_mfma_f32_16x16x32_bf16(a1, bj1, s, 0,0,0);
    #pragma unroll
    for (int r=0;r<4;r++) sum += __expf(fmaxf(s[r],0.f) - CSHIFT);
  }
  sum += __shfl_xor(sum, 16);
  sum += __shfl_xor(sum, 32);
  if (g == 0) atomicAdd(sb + j, sum);
}

__global__ __launch_bounds__(256) void k_recip(float* s){
  int i = blockIdx.x*256 + threadIdx.x;
  if (i < NN) s[i] = 1.0f/s[i];
}

// ---------------- dual spmm: out{A,B}[r][:] = bf16( A{1,2}.Yb ), 4-deep unroll ----------------
template<int F>
__global__ __launch_bounds__(256) void k_spmm2(
    const int* __restrict__ ptrA, const int* __restrict__ cidxA, const float* __restrict__ cvalA,
    const int* __restrict__ ptrB, const int* __restrict__ cidxB, const float* __restrict__ cvalB,
    const short* __restrict__ Yb, short* __restrict__ outA, short* __restrict__ outB)
{
  constexpr int LPR = F/8;
  constexpr int RPB = 256/LPR;
  int t = threadIdx.x;
  int r = blockIdx.x*RPB + t/LPR;
  int ts = t % LPR;
  const int* ptr; const int* cidx; const float* cval; short* outb;
  if (blockIdx.y == 0){ ptr=ptrA; cidx=cidxA; cval=cvalA; outb=outA; }
  else                { ptr=ptrB; cidx=cidxB; cval=cvalB; outb=outB; }
  const bf16x8* Y8 = (const bf16x8*)Yb;
  int p0 = ptr[r], p1 = ptr[r+1];
  float a[8];
  #pragma unroll
  for (int j=0;j<8;j++) a[j]=0.f;
  int p = p0;
  for (; p+3 < p1; p += 4){
    int   c0=cidx[p], c1=cidx[p+1], c2=cidx[p+2], c3=cidx[p+3];
    float v0=cval[p], v1=cval[p+1], v2=cval[p+2], v3=cval[p+3];
    bf16x8 x0 = Y8[(size_t)c0*LPR + ts];
    bf16x8 x1 = Y8[(size_t)c1*LPR + ts];
    bf16x8 x2 = Y8[(size_t)c2*LPR + ts];
    bf16x8 x3 = Y8[(size_t)c3*LPR + ts];
    #pragma unroll
    for (int j=0;j<8;j++) a[j] += v0*b2f((unsigned short)x0[j]);
    #pragma unroll
    for (int j=0;j<8;j++) a[j] += v1*b2f((unsigned short)x1[j]);
    #pragma unroll
    for (int j=0;j<8;j++) a[j] += v2*b2f((unsigned short)x2[j]);
    #pragma unroll
    for (int j=0;j<8;j++) a[j] += v3*b2f((unsigned short)x3[j]);
  }
  for (; p < p1; ++p){
    int c0 = cidx[p]; float v0 = cval[p];
    bf16x8 x0 = Y8[(size_t)c0*LPR + ts];
    #pragma unroll
    for (int j=0;j<8;j++) a[j] += v0*b2f((unsigned short)x0[j]);
  }
  bf16x8 o;
  #pragma unroll
  for (int j=0;j<8;j++) o[j] = f2b(a[j]);
  ((bf16x8*)outb)[(size_t)r*LPR + ts] = o;
}

// ---------------- fused cheb: T = x1a + x1b + 2*A1.x1a + 2*A2.x1b - Yb ----------------
template<int F>
__global__ __launch_bounds__(256) void k_cheb2(
    const int* __restrict__ ptr1, const int* __restrict__ cidx1, const float* __restrict__ cval1,
    const int* __restrict__ ptr2, const int* __restrict__ cidx2, const float* __restrict__ cval2,
    const short* __restrict__ x1a, const short* __restrict__ x1b,
    const short* __restrict__ Yb, float* __restrict__ T)
{
  constexpr int LPR = F/8;
  constexpr int RPB = 256/LPR;
  int t = threadIdx.x;
  int r = blockIdx.x*RPB + t/LPR;
  int ts = t % LPR;
  const bf16x8* Xa = (const bf16x8*)x1a;
  const bf16x8* Xb = (const bf16x8*)x1b;
  float a[8];
  #pragma unroll
  for (int j=0;j<8;j++) a[j]=0.f;
  // gather A1 . x1a
  {
    int p0 = ptr1[r], p1 = ptr1[r+1];
    int p = p0;
    for (; p+3 < p1; p += 4){
      int   c0=cidx1[p], c1=cidx1[p+1], c2=cidx1[p+2], c3=cidx1[p+3];
      float v0=cval1[p], v1=cval1[p+1], v2=cval1[p+2], v3=cval1[p+3];
      bf16x8 x0 = Xa[(size_t)c0*LPR + ts];
      bf16x8 x1 = Xa[(size_t)c1*LPR + ts];
      bf16x8 x2 = Xa[(size_t)c2*LPR + ts];
      bf16x8 x3 = Xa[(size_t)c3*LPR + ts];
      #pragma unroll
      for (int j=0;j<8;j++) a[j] += v0*b2f((unsigned short)x0[j]);
      #pragma unroll
      for (int j=0;j<8;j++) a[j] += v1*b2f((unsigned short)x1[j]);
      #pragma unroll
      for (int j=0;j<8;j++) a[j] += v2*b2f((unsigned short)x2[j]);
      #pragma unroll
      for (int j=0;j<8;j++) a[j] += v3*b2f((unsigned short)x3[j]);
    }
    for (; p < p1; ++p){
      int c0 = cidx1[p]; float v0 = cval1[p];
      bf16x8 x0 = Xa[(size_t)c0*LPR + ts];
      #pragma unroll
      for (int j=0;j<8;j++) a[j] += v0*b2f((unsigned short)x0[j]);
    }
  }
  // gather A2 . x1b
  {
    int p0 = ptr2[r], p1 = ptr2[r+1];
    int p = p0;
    for (; p+3 < p1; p += 4){
      int   c0=cidx2[p], c1=cidx2[p+1], c2=cidx2[p+2], c3=cidx2[p+3];
      float v0=cval2[p], v1=cval2[p+1], v2=cval2[p+2], v3=cval2[p+3];
      bf16x8 x0 = Xb[(size_t)c0*LPR + ts];
      bf16x8 x1 = Xb[(size_t)c1*LPR + ts];
      bf16x8 x2 = Xb[(size_t)c2*LPR + ts];
      bf16x8 x3 = Xb[(size_t)c3*LPR + ts];
      #pragma unroll
      for (int j=0;j<8;j++) a[j] += v0*b2f((unsigned short)x0[j]);
      #pragma unroll
      for (int j=0;j<8;j++) a[j] += v1*b2f((unsigned short)x1[j]);
      #pragma unroll
      for (int j=0;j<8;j++) a[j] += v2*b2f((unsigned short)x2[j]);
      #pragma unroll
      for (int j=0;j<8;j++) a[j] += v3*b2f((unsigned short)x3[j]);
    }
    for (; p < p1; ++p){
      int c0 = cidx2[p]; float v0 = cval2[p];
      bf16x8 x0 = Xb[(size_t)c0*LPR + ts];
      #pragma unroll
      for (int j=0;j<8;j++) a[j] += v0*b2f((unsigned short)x0[j]);
    }
  }
  bf16x8 sa = Xa[(size_t)r*LPR + ts];
  bf16x8 sbv = Xb[(size_t)r*LPR + ts];
  bf16x8 yv = ((const bf16x8*)Yb)[(size_t)r*LPR + ts];
  float o[8];
  #pragma unroll
  for (int j=0;j<8;j++)
    o[j] = 2.f*a[j] + b2f((unsigned short)sa[j]) + b2f((unsigned short)sbv[j]) - b2f((unsigned short)yv[j]);
  size_t o4 = ((size_t)r*F + ts*8) >> 2;
  ((f4*)T)[o4]   = (f4){o[0],o[1],o[2],o[3]};
  ((f4*)T)[o4+1] = (f4){o[4],o[5],o[6],o[7]};
}

// ---------------- layer-1 Yt: Yt[f][node] = bf16(X[f][node] * sinv[node]) ----------------
__global__ __launch_bounds__(256) void k_scaleb(const float* __restrict__ X, const float* __restrict__ sinv,
                                                short* __restrict__ Yt){
  int i = blockIdx.x*256 + threadIdx.x;     // f4 index over 512*NN/4
  int node4 = i & (NN/4 - 1);
  f4 x = ((const f4*)X)[i];
  f4 sv = ((const f4*)sinv)[node4];
  short4 o;
  o.x = f2b(x.x*sv.x); o.y = f2b(x.y*sv.y); o.z = f2b(x.z*sv.z); o.w = f2b(x.w*sv.w);
  ((short4*)Yt)[i] = o;
}

// ---------------- layer-2 Yt: transpose bf16 H, scale by sinv. Yt[f][node] ----------------
__global__ __launch_bounds__(256) void k_downt2(const short* __restrict__ Hb, const float* __restrict__ sinv,
                                                short* __restrict__ Yt){
  __shared__ float tile[32][33];
  int tx = threadIdx.x & 31, ty = threadIdx.x >> 5;
  int k0 = blockIdx.x*32, n0 = blockIdx.y*32;   // k = node, n = feat
  #pragma unroll
  for (int u=0;u<32;u+=8) tile[ty+u][tx] = b2f((unsigned short)Hb[(size_t)(k0+ty+u)*1024 + n0+tx]);
  __syncthreads();
  float sv = sinv[k0+tx];
  #pragma unroll
  for (int u=0;u<32;u+=8) Yt[(size_t)(n0+ty+u)*NN + k0+tx] = f2b(tile[tx][ty+u] * sv);
}

// ---------------- fused attention: bf16 partial[kz] = P @ Ys (k-slice) ----------------
// BM=128, BN=256, BK=32, 512 threads = 8 waves (2M x 4N). Chunk-major LDS.
template<int F>
__global__ __launch_bounds__(512, 4) void k_attn2(
    const short* __restrict__ Zb, const short* __restrict__ Ytg,
    P8s pp, int ksize)
{
  __shared__ __align__(16) short zk[2][32*64];     // [c=0..7][row=0..31] 16B units
  __shared__ __align__(16) short yt[2][256*32];    // [c=0..3][row=0..255]
  __shared__ __align__(16) short p_lds[128*40];
  int t = threadIdx.x;
  int w = t >> 6, l = t & 63;
  int lo = l & 15, g = l >> 4;
  int m0 = blockIdx.x * 128;
  int n0 = blockIdx.y * 256;
  int kz = blockIdx.z;
  int kbeg = kz * ksize, kend = kbeg + ksize;
  int wm = w >> 2, wn = w & 3;

  const bf16x8* Zb8 = (const bf16x8*)Zb;
  int zirow = m0 + w*16 + lo;
  bf16x8 ziA0 = Zb8[(size_t)zirow*8 + g];
  bf16x8 ziA1 = Zb8[(size_t)zirow*8 + g + 4];

  f32x4 acc[4][4];
  #pragma unroll
  for (int i=0;i<4;i++)
    #pragma unroll
    for (int j=0;j<4;j++) acc[i][j] = (f32x4){0.f,0.f,0.f,0.f};

  auto STAGE = [&](int b, int kk){
    if (t < 256){
      const short* src = Zb + (((size_t)(kk + (t & 31))) << 6) + ((t >> 5) << 3);
      __builtin_amdgcn_global_load_lds((glb_short*)src, (lds_short*)&zk[b][t*8], 16, 0, 0);
    }
    #pragma unroll
    for (int p=0;p<2;p++){
      int cc = p*512 + t;
      const short* src = Ytg + (size_t)(n0 + (cc & 255))*NN + kk + ((cc >> 8) << 3);
      __builtin_amdgcn_global_load_lds((glb_short*)src, (lds_short*)&yt[b][cc*8], 16, 0, 0);
    }
  };

  STAGE(0, kbeg);
  __syncthreads();

  int cur = 0;
  for (int k0 = kbeg; k0 < kend; k0 += 32){
    bf16x8 b00 = *(const bf16x8*)&zk[cur][((g    )*32 + lo     )*8];
    bf16x8 b01 = *(const bf16x8*)&zk[cur][((g + 4)*32 + lo     )*8];
    bf16x8 b10 = *(const bf16x8*)&zk[cur][((g    )*32 + 16 + lo)*8];
    bf16x8 b11 = *(const bf16x8*)&zk[cur][((g + 4)*32 + 16 + lo)*8];
    f32x4 s0 = (f32x4){0.f,0.f,0.f,0.f};
    f32x4 s1 = (f32x4){0.f,0.f,0.f,0.f};
    s0 = __builtin_amdgcn_mfma_f32_16x16x32_bf16(ziA0, b00, s0, 0,0,0);
    s0 = __builtin_amdgcn_mfma_f32_16x16x32_bf16(ziA1, b01, s0, 0,0,0);
    s1 = __builtin_amdgcn_mfma_f32_16x16x32_bf16(ziA0, b10, s1, 0,0,0);
    s1 = __builtin_amdgcn_mfma_f32_16x16x32_bf16(ziA1, b11, s1, 0,0,0);
    short e0[4], e1[4];
    #pragma unroll
    for (int r=0;r<4;r++){
      e0[r] = f2b(__expf(fmaxf(s0[r],0.f) - CSHIFT));
      e1[r] = f2b(__expf(fmaxf(s1[r],0.f) - CSHIFT));
    }
    __syncthreads();                 // B1: all reads of both buffers retired
    if (k0 + 32 < kend) STAGE(cur ^ 1, k0 + 32);
    int prow = w*16 + g*4;
    #pragma unroll
    for (int r=0;r<4;r++){
      p_lds[(prow+r)*40 + lo]      = e0[r];
      p_lds[(prow+r)*40 + 16 + lo] = e1[r];
    }
    __syncthreads();                 // B2: staging drained, P visible
    bf16x8 aP[4];
    #pragma unroll
    for (int mf=0; mf<4; mf++)
      aP[mf] = *(const bf16x8*)&p_lds[(wm*64 + mf*16 + lo)*40 + g*8];
    #pragma unroll
    for (int nf=0; nf<4; nf++){
      int nl = wn*64 + nf*16 + lo;
      bf16x8 bY = *(const bf16x8*)&yt[cur][(g*256 + nl)*8];
      #pragma unroll
      for (int mf=0; mf<4; mf++)
        acc[mf][nf] = __builtin_amdgcn_mfma_f32_16x16x32_bf16(aP[mf], bY, acc[mf][nf], 0,0,0);
    }
    cur ^= 1;
  }
  short* outp = pp.p[kz];
  #pragma unroll
  for (int mf=0; mf<4; mf++){
    int row = m0 + wm*64 + mf*16 + g*4;
    #pragma unroll
    for (int nf=0; nf<4; nf++){
      int col = n0 + wn*64 + nf*16 + lo;
      #pragma unroll
      for (int r=0;r<4;r++)
        outp[(size_t)(row+r)*F + col] = f2b(acc[mf][nf][r]);
    }
  }
}

// ---------------- head GEMM with fused partial merge; f32 and/or bf16 out ----------------
template<int DIN, int FIN>
__global__ __launch_bounds__(256) void k_headm(const float* __restrict__ T, P8s parts, int np,
                                               const float* __restrict__ W,
                                               float* __restrict__ Hout, short* __restrict__ HoutB){
  __shared__ float tt[16*DIN];
  int t = threadIdx.x;
  int j0 = blockIdx.x*16, b = blockIdx.y;
  for (int u=t; u<16*DIN/8; u+=256){
    int jj = u / (DIN/8), k8 = u % (DIN/8);
    size_t base = (size_t)(j0+jj)*FIN + b*DIN + k8*8;
    f4 x0 = *(const f4*)(T + base);
    f4 x1 = *(const f4*)(T + base + 4);
    float v[8] = {x0.x,x0.y,x0.z,x0.w,x1.x,x1.y,x1.z,x1.w};
    for (int j=0;j<np;j++){
      bf16x8 p = *(const bf16x8*)(parts.p[j] + base);
      #pragma unroll
      for (int q=0;q<8;q++) v[q] += b2f((unsigned short)p[q]);
    }
    #pragma unroll
    for (int q=0;q<8;q++) tt[jj*DIN + k8*8 + q] = v[q];
  }
  __syncthreads();
  int oq = t & 31, jg = t >> 5;
  f4 a0 = {0,0,0,0}, a1 = {0,0,0,0};
  const f4* W4 = (const f4*)W;
  for (int k=0;k<DIN;k++){
    f4 wv = W4[k*32 + oq];
    float t0 = tt[(jg*2+0)*DIN + k];
    float t1 = tt[(jg*2+1)*DIN + k];
    a0.x += t0*wv.x; a0.y += t0*wv.y; a0.z += t0*wv.z; a0.w += t0*wv.w;
    a1.x += t1*wv.x; a1.y += t1*wv.y; a1.z += t1*wv.z; a1.w += t1*wv.w;
  }
  a0.x=fmaxf(a0.x,0.f); a0.y=fmaxf(a0.y,0.f); a0.z=fmaxf(a0.z,0.f); a0.w=fmaxf(a0.w,0.f);
  a1.x=fmaxf(a1.x,0.f); a1.y=fmaxf(a1.y,0.f); a1.z=fmaxf(a1.z,0.f); a1.w=fmaxf(a1.w,0.f);
  int j1 = j0 + jg*2, col = b*32 + oq;
  if (Hout){
    f4* H4 = (f4*)Hout;
    H4[(size_t)(j1+0)*256 + col] = a0;
    H4[(size_t)(j1+1)*256 + col] = a1;
  }
  if (HoutB){
    short4 s0, s1;
    s0.x=f2b(a0.x); s0.y=f2b(a0.y); s0.z=f2b(a0.z); s0.w=f2b(a0.w);
    s1.x=f2b(a1.x); s1.y=f2b(a1.y); s1.z=f2b(a1.z); s1.w=f2b(a1.w);
    *(short4*)(HoutB + (size_t)(j1+0)*1024 + col*4) = s0;
    *(short4*)(HoutB + (size_t)(j1+1)*1024 + col*4) = s1;
  }
}

// ---------------- final mean over nodes ----------------
__global__ __launch_bounds__(256) void k_reduce(const float* __restrict__ A, float* __restrict__ out){
  __shared__ float accl[1024];
  int t = threadIdx.x;
  for (int u=t; u<1024; u+=256) accl[u]=0.f;
  __syncthreads();
  int j0 = blockIdx.x*128;
  for (int j=j0; j<j0+128; j++){
    for (int u=t; u<1024; u+=256) accl[u] += A[(size_t)j*1024 + u];
  }
  __syncthreads();
  for (int u=t; u<1024; u+=256) atomicAdd(&out[u], accl[u]*(1.f/8192.f));
}

// ---------------- launcher ----------------
extern "C" void kernel_launch(void* const* d_in, const int* in_sizes, int n_in,
                              void* d_out, int out_size, void* d_ws, size_t ws_size,
                              hipStream_t stream){
  const int*   A1i = (const int*)d_in[0];
  const float* A1v = (const float*)d_in[1];
  const int*   A2i = (const int*)d_in[2];
  const float* A2v = (const float*)d_in[3];
  const float* X   = (const float*)d_in[4];
  const float* Z   = (const float*)d_in[5];
  const float* W1  = (const float*)d_in[6];
  const float* W2  = (const float*)d_in[7];
  float* out = (float*)d_out;

  char* w = (char*)d_ws;
  size_t off = 0;
  auto alloc = [&](size_t b)->char* {
    char* p = w + off;
    off += (b + 1023) & ~(size_t)1023;
    return p;
  };
  const size_t MB = 1024*1024;
  float* sb    = (float*)alloc(NN*4);
  int*   ptr1  = (int*)  alloc((NN+1)*4);
  int*   ptr2  = (int*)  alloc((NN+1)*4);
  int*   cnt   = (int*)  alloc(NN*4);
  int*   cidx1 = (int*)  alloc(NNZE*4);
  float* cval1 = (float*)alloc(NNZE*4);
  int*   cidx2 = (int*)  alloc(NNZE*4);
  float* cval2 = (float*)alloc(NNZE*4);
  short* Zbf   = (short*)alloc((size_t)NN*64*2);      // 1 MB
  short* XT1b  = (short*)alloc((size_t)NN*512*2);     // 8 MB  X^T bf16
  short* BUFA  = (short*)alloc((size_t)NN*1024*2);    // 16 MB x1a (L1 uses 8)
  short* BUFB  = (short*)alloc((size_t)NN*1024*2);    // 16 MB x1b
  short* HTb   = (short*)alloc((size_t)NN*1024*2);    // 16 MB H bf16 (layer bridge)
  short* YS    = (short*)alloc((size_t)NN*1024*2);    // 16 MB Yt (L1 uses 8)
  float* T1    = (float*)alloc((size_t)NN*512*4);     // 16 MB
  float* T2    = (float*)alloc((size_t)NN*1024*4);    // 32 MB
  float* HT    = (float*)alloc((size_t)NN*1024*4);    // 32 MB layer-2 H f32
  char*  PART  = alloc((size_t)32*MB);                // attn bf16 partials
  (void)ws_size; // total ~170 MB; ws >= 233 MB proven (round 4 bigws path ran)

  // CSR for A1, A2
  hipMemsetAsync(cnt, 0, NN*4, stream);
  k_count<<<NNZE/256, 256, 0, stream>>>(A1i, cnt);
  k_scan<<<1, 1024, 0, stream>>>(cnt, ptr1);
  hipMemcpyAsync(cnt, ptr1, NN*4, hipMemcpyDeviceToDevice, stream);
  k_fill<<<NNZE/256, 256, 0, stream>>>(A1i, A1v, cnt, cidx1, cval1);

  hipMemsetAsync(cnt, 0, NN*4, stream);
  k_count<<<NNZE/256, 256, 0, stream>>>(A2i, cnt);
  k_scan<<<1, 1024, 0, stream>>>(cnt, ptr2);
  hipMemcpyAsync(cnt, ptr2, NN*4, hipMemcpyDeviceToDevice, stream);
  k_fill<<<NNZE/256, 256, 0, stream>>>(A2i, A2v, cnt, cidx2, cval2);

  // Z bf16, softmax column sums, X^T bf16
  k_zb<<<NN*64/256, 256, 0, stream>>>(Z, Zbf);
  hipMemsetAsync(sb, 0, NN*4, stream);
  k_colsum_mfma<<<dim3(NN/128, 8), 512, 0, stream>>>(Zbf, sb);
  k_recip<<<NN/256, 256, 0, stream>>>(sb);
  k_transb<512><<<dim3(NN/32, 512/32), 256, 0, stream>>>(X, XT1b);

  // ---- layer 1 (F=512) ----
  k_spmm2<512><<<dim3(NN/4, 2), 256, 0, stream>>>(ptr1, cidx1, cval1, ptr2, cidx2, cval2,
                                                  XT1b, BUFA, BUFB);
  k_cheb2<512><<<NN/4, 256, 0, stream>>>(ptr1, cidx1, cval1, ptr2, cidx2, cval2,
                                         BUFA, BUFB, XT1b, T1);
  k_scaleb<<<512*NN/4/256, 256, 0, stream>>>(X, sb, YS);     // Yt1 = X[f][n]*sinv[n]
  {
    P8s pp{};
    for (int i=0;i<4;i++) pp.p[i] = (short*)(PART + (size_t)i*8*MB);
    k_attn2<512><<<dim3(NN/128, 2, 4), 512, 0, stream>>>(Zbf, YS, pp, NN/4);
    k_headm<64,512><<<dim3(NN/16, 8), 256, 0, stream>>>(T1, pp, 4, W1, nullptr, HTb);
  }

  // ---- layer 2 (F=1024) ----
  k_spmm2<1024><<<dim3(NN/2, 2), 256, 0, stream>>>(ptr1, cidx1, cval1, ptr2, cidx2, cval2,
                                                   HTb, BUFA, BUFB);
  k_cheb2<1024><<<NN/2, 256, 0, stream>>>(ptr1, cidx1, cval1, ptr2, cidx2, cval2,
                                          BUFA, BUFB, HTb, T2);
  k_downt2<<<dim3(NN/32, 1024/32), 256, 0, stream>>>(HTb, sb, YS);
  {
    P8s pp{};
    pp.p[0] = (short*)PART;
    pp.p[1] = (short*)(PART + (size_t)16*MB);
    k_attn2<1024><<<dim3(NN/128, 4, 2), 512, 0, stream>>>(Zbf, YS, pp, NN/2);
    k_headm<128,1024><<<dim3(NN/16, 8), 256, 0, stream>>>(T2, pp, 2, W2, HT, nullptr);
  }

  hipMemsetAsync(out, 0, 1024*4, stream);
  k_reduce<<<64, 256, 0, stream>>>(HT, out);
}

// Round 10
// 757.253 us; speedup vs baseline: 1.7227x; 1.1411x over previous
//
#include <hip/hip_runtime.h>

// GWNet on MI355X — round 10.
// - attn LDS: round-3 coalesced staging + FULL-spread XOR (yt: g^((nl>>1)&3),
//   was g^(nl&3) = 4-way conflicted; zk: g^(lo&7) already free). Both sides
//   swizzled per rule 21 (inverse-XOR global source, linear gload_lds dest).
// - s_setprio(1) around PV MFMA cluster (T5).
// - Launch-count cuts: dual-matrix CSR build (10->4 dispatches), k_recip
//   inlined, node-mean fused into layer-2 head (HT + k_reduce deleted).

#define NN 8192
#define NNZE 131072
#define CSHIFT 48.0f

typedef float4 f4;
typedef __attribute__((ext_vector_type(8))) short bf16x8;
typedef __attribute__((ext_vector_type(4))) float f32x4;

typedef __attribute__((address_space(3))) short lds_short;
typedef __attribute__((address_space(1))) const short glb_short;

struct P8s { short* p[8]; };

__device__ inline short f2b(float x){
  unsigned u = __float_as_uint(x);
  unsigned r = (u + 0x7fffu + ((u >> 16) & 1u)) >> 16;
  return (short)r;
}
__device__ inline float b2f(unsigned short b){
  return __uint_as_float(((unsigned)b) << 16);
}

// ---------------- CSR build (dual-matrix fused) ----------------
__global__ __launch_bounds__(256) void k_count2(const int* __restrict__ i1, const int* __restrict__ i2,
                                                int* __restrict__ c1, int* __restrict__ c2){
  int e = blockIdx.x*256 + threadIdx.x;
  if (blockIdx.y == 0) atomicAdd(&c1[i1[e]], 1);
  else                 atomicAdd(&c2[i2[e]], 1);
}

__global__ __launch_bounds__(1024) void k_scan2(const int* __restrict__ cnt1, const int* __restrict__ cnt2,
                                                int* __restrict__ ptr1, int* __restrict__ ptr2,
                                                int* __restrict__ cur1, int* __restrict__ cur2){
  __shared__ int sums[1024];
  const int* cnt = blockIdx.x ? cnt2 : cnt1;
  int* ptr = blockIdx.x ? ptr2 : ptr1;
  int* cur = blockIdx.x ? cur2 : cur1;
  int t = threadIdx.x;
  int loc[8]; int s = 0;
  #pragma unroll
  for (int i=0;i<8;i++){ loc[i]=s; s += cnt[t*8+i]; }
  sums[t]=s; __syncthreads();
  for (int off=1; off<1024; off<<=1){
    int v = (t>=off) ? sums[t-off] : 0;
    __syncthreads();
    sums[t] += v;
    __syncthreads();
  }
  int excl = sums[t]-s;
  #pragma unroll
  for (int i=0;i<8;i++){ int v = excl + loc[i]; ptr[t*8+i] = v; cur[t*8+i] = v; }
  if (t==1023) ptr[NN] = sums[1023];
}

__global__ __launch_bounds__(256) void k_fill2(const int* __restrict__ i1, const float* __restrict__ v1,
                                               const int* __restrict__ i2, const float* __restrict__ v2,
                                               int* __restrict__ cur1, int* __restrict__ cur2,
                                               int* __restrict__ cidx1, float* __restrict__ cval1,
                                               int* __restrict__ cidx2, float* __restrict__ cval2){
  int e = blockIdx.x*256 + threadIdx.x;
  const int* idx; const float* vals; int* cur; int* cidx; float* cval;
  if (blockIdx.y == 0){ idx=i1; vals=v1; cur=cur1; cidx=cidx1; cval=cval1; }
  else                { idx=i2; vals=v2; cur=cur2; cidx=cidx2; cval=cval2; }
  int r = idx[e], c = idx[NNZE+e];
  int p = atomicAdd(&cur[r], 1);
  cidx[p] = c; cval[p] = vals[e];
}

// ---------------- transpose X (R,NN)->(NN,R) bf16 ----------------
template<int R>
__global__ __launch_bounds__(256) void k_transb(const float* __restrict__ src, short* __restrict__ dstb){
  __shared__ float tile[32][33];
  int tx = threadIdx.x & 31, ty = threadIdx.x >> 5;
  int j0 = blockIdx.x*32, f0 = blockIdx.y*32;
  #pragma unroll
  for (int u=0;u<32;u+=8) tile[ty+u][tx] = src[(size_t)(f0+ty+u)*NN + j0+tx];
  __syncthreads();
  #pragma unroll
  for (int u=0;u<32;u+=8) dstb[(size_t)(j0+ty+u)*R + f0+tx] = f2b(tile[tx][ty+u]);
}

// ---------------- Z -> bf16 ----------------
__global__ __launch_bounds__(256) void k_zb(const float* __restrict__ Z, short* __restrict__ Zb){
  int i = blockIdx.x*256 + threadIdx.x;
  Zb[i] = f2b(Z[i]);
}

// ---------------- column sums via MFMA: sb[j] = sum_i exp(relu(zi.zj) - C) ----------------
__global__ __launch_bounds__(512) void k_colsum_mfma(const short* __restrict__ Zb, float* __restrict__ sb){
  int t = threadIdx.x;
  int w = t >> 6, l = t & 63;
  int lo = l & 15, g = l >> 4;
  int j = blockIdx.x*128 + w*16 + lo;
  const bf16x8* Zb8 = (const bf16x8*)Zb;
  bf16x8 bj0 = Zb8[j*8 + g];
  bf16x8 bj1 = Zb8[j*8 + g + 4];
  int i0 = blockIdx.y * (NN/8);
  float sum = 0.f;
  for (int i = i0; i < i0 + NN/8; i += 16){
    bf16x8 a0 = Zb8[(size_t)(i+lo)*8 + g];
    bf16x8 a1 = Zb8[(size_t)(i+lo)*8 + g + 4];
    f32x4 s = (f32x4){0.f,0.f,0.f,0.f};
    s = __builtin_amdgcn_mfma_f32_16x16x32_bf16(a0, bj0, s, 0,0,0);
    s = __builtin_amdgcn_mfma_f32_16x16x32_bf16(a1, bj1, s, 0,0,0);
    #pragma unroll
    for (int r=0;r<4;r++) sum += __expf(fmaxf(s[r],0.f) - CSHIFT);
  }
  sum += __shfl_xor(sum, 16);
  sum += __shfl_xor(sum, 32);
  if (g == 0) atomicAdd(sb + j, sum);
}

// ---------------- dual spmm: out{A,B}[r][:] = bf16( A{1,2}.Yb ), 4-deep unroll ----------------
template<int F>
__global__ __launch_bounds__(256) void k_spmm2(
    const int* __restrict__ ptrA, const int* __restrict__ cidxA, const float* __restrict__ cvalA,
    const int* __restrict__ ptrB, const int* __restrict__ cidxB, const float* __restrict__ cvalB,
    const short* __restrict__ Yb, short* __restrict__ outA, short* __restrict__ outB)
{
  constexpr int LPR = F/8;
  constexpr int RPB = 256/LPR;
  int t = threadIdx.x;
  int r = blockIdx.x*RPB + t/LPR;
  int ts = t % LPR;
  const int* ptr; const int* cidx; const float* cval; short* outb;
  if (blockIdx.y == 0){ ptr=ptrA; cidx=cidxA; cval=cvalA; outb=outA; }
  else                { ptr=ptrB; cidx=cidxB; cval=cvalB; outb=outB; }
  const bf16x8* Y8 = (const bf16x8*)Yb;
  int p0 = ptr[r], p1 = ptr[r+1];
  float a[8];
  #pragma unroll
  for (int j=0;j<8;j++) a[j]=0.f;
  int p = p0;
  for (; p+3 < p1; p += 4){
    int   c0=cidx[p], c1=cidx[p+1], c2=cidx[p+2], c3=cidx[p+3];
    float v0=cval[p], v1=cval[p+1], v2=cval[p+2], v3=cval[p+3];
    bf16x8 x0 = Y8[(size_t)c0*LPR + ts];
    bf16x8 x1 = Y8[(size_t)c1*LPR + ts];
    bf16x8 x2 = Y8[(size_t)c2*LPR + ts];
    bf16x8 x3 = Y8[(size_t)c3*LPR + ts];
    #pragma unroll
    for (int j=0;j<8;j++) a[j] += v0*b2f((unsigned short)x0[j]);
    #pragma unroll
    for (int j=0;j<8;j++) a[j] += v1*b2f((unsigned short)x1[j]);
    #pragma unroll
    for (int j=0;j<8;j++) a[j] += v2*b2f((unsigned short)x2[j]);
    #pragma unroll
    for (int j=0;j<8;j++) a[j] += v3*b2f((unsigned short)x3[j]);
  }
  for (; p < p1; ++p){
    int c0 = cidx[p]; float v0 = cval[p];
    bf16x8 x0 = Y8[(size_t)c0*LPR + ts];
    #pragma unroll
    for (int j=0;j<8;j++) a[j] += v0*b2f((unsigned short)x0[j]);
  }
  bf16x8 o;
  #pragma unroll
  for (int j=0;j<8;j++) o[j] = f2b(a[j]);
  ((bf16x8*)outb)[(size_t)r*LPR + ts] = o;
}

// ---------------- fused cheb: T = x1a + x1b + 2*A1.x1a + 2*A2.x1b - Yb ----------------
template<int F>
__global__ __launch_bounds__(256) void k_cheb2(
    const int* __restrict__ ptr1, const int* __restrict__ cidx1, const float* __restrict__ cval1,
    const int* __restrict__ ptr2, const int* __restrict__ cidx2, const float* __restrict__ cval2,
    const short* __restrict__ x1a, const short* __restrict__ x1b,
    const short* __restrict__ Yb, float* __restrict__ T)
{
  constexpr int LPR = F/8;
  constexpr int RPB = 256/LPR;
  int t = threadIdx.x;
  int r = blockIdx.x*RPB + t/LPR;
  int ts = t % LPR;
  const bf16x8* Xa = (const bf16x8*)x1a;
  const bf16x8* Xb = (const bf16x8*)x1b;
  float a[8];
  #pragma unroll
  for (int j=0;j<8;j++) a[j]=0.f;
  {
    int p0 = ptr1[r], p1 = ptr1[r+1];
    int p = p0;
    for (; p+3 < p1; p += 4){
      int   c0=cidx1[p], c1=cidx1[p+1], c2=cidx1[p+2], c3=cidx1[p+3];
      float v0=cval1[p], v1=cval1[p+1], v2=cval1[p+2], v3=cval1[p+3];
      bf16x8 x0 = Xa[(size_t)c0*LPR + ts];
      bf16x8 x1 = Xa[(size_t)c1*LPR + ts];
      bf16x8 x2 = Xa[(size_t)c2*LPR + ts];
      bf16x8 x3 = Xa[(size_t)c3*LPR + ts];
      #pragma unroll
      for (int j=0;j<8;j++) a[j] += v0*b2f((unsigned short)x0[j]);
      #pragma unroll
      for (int j=0;j<8;j++) a[j] += v1*b2f((unsigned short)x1[j]);
      #pragma unroll
      for (int j=0;j<8;j++) a[j] += v2*b2f((unsigned short)x2[j]);
      #pragma unroll
      for (int j=0;j<8;j++) a[j] += v3*b2f((unsigned short)x3[j]);
    }
    for (; p < p1; ++p){
      int c0 = cidx1[p]; float v0 = cval1[p];
      bf16x8 x0 = Xa[(size_t)c0*LPR + ts];
      #pragma unroll
      for (int j=0;j<8;j++) a[j] += v0*b2f((unsigned short)x0[j]);
    }
  }
  {
    int p0 = ptr2[r], p1 = ptr2[r+1];
    int p = p0;
    for (; p+3 < p1; p += 4){
      int   c0=cidx2[p], c1=cidx2[p+1], c2=cidx2[p+2], c3=cidx2[p+3];
      float v0=cval2[p], v1=cval2[p+1], v2=cval2[p+2], v3=cval2[p+3];
      bf16x8 x0 = Xb[(size_t)c0*LPR + ts];
      bf16x8 x1 = Xb[(size_t)c1*LPR + ts];
      bf16x8 x2 = Xb[(size_t)c2*LPR + ts];
      bf16x8 x3 = Xb[(size_t)c3*LPR + ts];
      #pragma unroll
      for (int j=0;j<8;j++) a[j] += v0*b2f((unsigned short)x0[j]);
      #pragma unroll
      for (int j=0;j<8;j++) a[j] += v1*b2f((unsigned short)x1[j]);
      #pragma unroll
      for (int j=0;j<8;j++) a[j] += v2*b2f((unsigned short)x2[j]);
      #pragma unroll
      for (int j=0;j<8;j++) a[j] += v3*b2f((unsigned short)x3[j]);
    }
    for (; p < p1; ++p){
      int c0 = cidx2[p]; float v0 = cval2[p];
      bf16x8 x0 = Xb[(size_t)c0*LPR + ts];
      #pragma unroll
      for (int j=0;j<8;j++) a[j] += v0*b2f((unsigned short)x0[j]);
    }
  }
  bf16x8 sa = Xa[(size_t)r*LPR + ts];
  bf16x8 sbv = Xb[(size_t)r*LPR + ts];
  bf16x8 yv = ((const bf16x8*)Yb)[(size_t)r*LPR + ts];
  float o[8];
  #pragma unroll
  for (int j=0;j<8;j++)
    o[j] = 2.f*a[j] + b2f((unsigned short)sa[j]) + b2f((unsigned short)sbv[j]) - b2f((unsigned short)yv[j]);
  size_t o4 = ((size_t)r*F + ts*8) >> 2;
  ((f4*)T)[o4]   = (f4){o[0],o[1],o[2],o[3]};
  ((f4*)T)[o4+1] = (f4){o[4],o[5],o[6],o[7]};
}

// ---------------- layer-1 Yt: Yt[f][node] = bf16(X[f][node] / s[node]) ----------------
__global__ __launch_bounds__(256) void k_scaleb(const float* __restrict__ X, const float* __restrict__ sb,
                                                short* __restrict__ Yt){
  int i = blockIdx.x*256 + threadIdx.x;     // f4 index over 512*NN/4
  int node4 = i & (NN/4 - 1);
  f4 x = ((const f4*)X)[i];
  f4 sv = ((const f4*)sb)[node4];
  short4 o;
  o.x = f2b(x.x*(1.0f/sv.x)); o.y = f2b(x.y*(1.0f/sv.y));
  o.z = f2b(x.z*(1.0f/sv.z)); o.w = f2b(x.w*(1.0f/sv.w));
  ((short4*)Yt)[i] = o;
}

// ---------------- layer-2 Yt: transpose bf16 H, scale by 1/s. Yt[f][node] ----------------
__global__ __launch_bounds__(256) void k_downt2(const short* __restrict__ Hb, const float* __restrict__ sb,
                                                short* __restrict__ Yt){
  __shared__ float tile[32][33];
  int tx = threadIdx.x & 31, ty = threadIdx.x >> 5;
  int k0 = blockIdx.x*32, n0 = blockIdx.y*32;   // k = node, n = feat
  #pragma unroll
  for (int u=0;u<32;u+=8) tile[ty+u][tx] = b2f((unsigned short)Hb[(size_t)(k0+ty+u)*1024 + n0+tx]);
  __syncthreads();
  float sv = 1.0f / sb[k0+tx];
  #pragma unroll
  for (int u=0;u<32;u+=8) Yt[(size_t)(n0+ty+u)*NN + k0+tx] = f2b(tile[tx][ty+u] * sv);
}

// ---------------- fused attention: bf16 partial[kz] = P @ Ys (k-slice) ----------------
// BM=128, BN=256, BK=32, 512 threads = 8 waves (2M x 4N).
// LDS: coalesced staging + full-spread XOR (zk: c^(r&7); yt: c^((r>>1)&3)).
template<int F>
__global__ __launch_bounds__(512, 4) void k_attn2(
    const short* __restrict__ Zb, const short* __restrict__ Ytg,
    P8s pp, int ksize)
{
  __shared__ __align__(16) short zk[2][32*64];     // [row][chunk^(row&7)] 16B units
  __shared__ __align__(16) short yt[2][256*32];    // [row][chunk^((row>>1)&3)]
  __shared__ __align__(16) short p_lds[128*40];
  int t = threadIdx.x;
  int w = t >> 6, l = t & 63;
  int lo = l & 15, g = l >> 4;
  int m0 = blockIdx.x * 128;
  int n0 = blockIdx.y * 256;
  int kz = blockIdx.z;
  int kbeg = kz * ksize, kend = kbeg + ksize;
  int wm = w >> 2, wn = w & 3;

  const bf16x8* Zb8 = (const bf16x8*)Zb;
  int zirow = m0 + w*16 + lo;
  bf16x8 ziA0 = Zb8[(size_t)zirow*8 + g];
  bf16x8 ziA1 = Zb8[(size_t)zirow*8 + g + 4];

  f32x4 acc[4][4];
  #pragma unroll
  for (int i=0;i<4;i++)
    #pragma unroll
    for (int j=0;j<4;j++) acc[i][j] = (f32x4){0.f,0.f,0.f,0.f};

  auto STAGE = [&](int b, int kk){
    if (t < 256){
      int r = t >> 3, c = t & 7;          // 8 consecutive lanes = 8 chunks of row r (128B)
      const short* src = Zb + (((size_t)(kk + r)) << 6) + ((c ^ (r & 7)) << 3);
      __builtin_amdgcn_global_load_lds((glb_short*)src, (lds_short*)&zk[b][t*8], 16, 0, 0);
    }
    #pragma unroll
    for (int p=0;p<2;p++){
      int cc = p*512 + t;
      int r = cc >> 2, c = cc & 3;        // 4 consecutive lanes = 4 chunks of row r (64B)
      const short* src = Ytg + (size_t)(n0 + r)*NN + kk + ((c ^ ((r >> 1) & 3)) << 3);
      __builtin_amdgcn_global_load_lds((glb_short*)src, (lds_short*)&yt[b][cc*8], 16, 0, 0);
    }
  };

  STAGE(0, kbeg);
  __syncthreads();

  int cur = 0;
  for (int k0 = kbeg; k0 < kend; k0 += 32){
    // ---- S phase (zk reads conflict-free: bank base (g^(lo&7))*4, 2-way) ----
    int xa = g ^ (lo & 7), xb = (g + 4) ^ (lo & 7);
    bf16x8 b00 = *(const bf16x8*)&zk[cur][(lo*8 + xa)*8];
    bf16x8 b01 = *(const bf16x8*)&zk[cur][(lo*8 + xb)*8];
    bf16x8 b10 = *(const bf16x8*)&zk[cur][((16+lo)*8 + xa)*8];
    bf16x8 b11 = *(const bf16x8*)&zk[cur][((16+lo)*8 + xb)*8];
    f32x4 s0 = (f32x4){0.f,0.f,0.f,0.f};
    f32x4 s1 = (f32x4){0.f,0.f,0.f,0.f};
    s0 = __builtin_amdgcn_mfma_f32_16x16x32_bf16(ziA0, b00, s0, 0,0,0);
    s0 = __builtin_amdgcn_mfma_f32_16x16x32_bf16(ziA1, b01, s0, 0,0,0);
    s1 = __builtin_amdgcn_mfma_f32_16x16x32_bf16(ziA0, b10, s1, 0,0,0);
    s1 = __builtin_amdgcn_mfma_f32_16x16x32_bf16(ziA1, b11, s1, 0,0,0);
    short e0[4], e1[4];
    #pragma unroll
    for (int r=0;r<4;r++){
      e0[r] = f2b(__expf(fmaxf(s0[r],0.f) - CSHIFT));
      e1[r] = f2b(__expf(fmaxf(s1[r],0.f) - CSHIFT));
    }
    __syncthreads();                 // B1: all reads of both buffers retired
    if (k0 + 32 < kend) STAGE(cur ^ 1, k0 + 32);
    int prow = w*16 + g*4;
    #pragma unroll
    for (int r=0;r<4;r++){
      p_lds[(prow+r)*40 + lo]      = e0[r];
      p_lds[(prow+r)*40 + 16 + lo] = e1[r];
    }
    __syncthreads();                 // B2: staging drained, P visible
    // ---- PV phase (yt reads: bank base (lo&1)*16+(g^((nl>>1)&3))*4, 2-way) ----
    bf16x8 aP[4];
    #pragma unroll
    for (int mf=0; mf<4; mf++)
      aP[mf] = *(const bf16x8*)&p_lds[(wm*64 + mf*16 + lo)*40 + g*8];
    __builtin_amdgcn_s_setprio(1);
    #pragma unroll
    for (int nf=0; nf<4; nf++){
      int nl = wn*64 + nf*16 + lo;
      bf16x8 bY = *(const bf16x8*)&yt[cur][(nl*4 + (g ^ ((nl >> 1) & 3)))*8];
      #pragma unroll
      for (int mf=0; mf<4; mf++)
        acc[mf][nf] = __builtin_amdgcn_mfma_f32_16x16x32_bf16(aP[mf], bY, acc[mf][nf], 0,0,0);
    }
    __builtin_amdgcn_s_setprio(0);
    cur ^= 1;
  }
  short* outp = pp.p[kz];
  #pragma unroll
  for (int mf=0; mf<4; mf++){
    int row = m0 + wm*64 + mf*16 + g*4;
    #pragma unroll
    for (int nf=0; nf<4; nf++){
      int col = n0 + wn*64 + nf*16 + lo;
      #pragma unroll
      for (int r=0;r<4;r++)
        outp[(size_t)(row+r)*F + col] = f2b(acc[mf][nf][r]);
    }
  }
}

// ---------------- head GEMM with fused partial merge; bf16 H out (layer 1) ----------------
template<int DIN, int FIN>
__global__ __launch_bounds__(256) void k_headm(const float* __restrict__ T, P8s parts, int np,
                                               const float* __restrict__ W,
                                               short* __restrict__ HoutB){
  __shared__ float tt[16*DIN];
  int t = threadIdx.x;
  int j0 = blockIdx.x*16, b = blockIdx.y;
  for (int u=t; u<16*DIN/8; u+=256){
    int jj = u / (DIN/8), k8 = u % (DIN/8);
    size_t base = (size_t)(j0+jj)*FIN + b*DIN + k8*8;
    f4 x0 = *(const f4*)(T + base);
    f4 x1 = *(const f4*)(T + base + 4);
    float v[8] = {x0.x,x0.y,x0.z,x0.w,x1.x,x1.y,x1.z,x1.w};
    for (int j=0;j<np;j++){
      bf16x8 p = *(const bf16x8*)(parts.p[j] + base);
      #pragma unroll
      for (int q=0;q<8;q++) v[q] += b2f((unsigned short)p[q]);
    }
    #pragma unroll
    for (int q=0;q<8;q++) tt[jj*DIN + k8*8 + q] = v[q];
  }
  __syncthreads();
  int oq = t & 31, jg = t >> 5;
  f4 a0 = {0,0,0,0}, a1 = {0,0,0,0};
  const f4* W4 = (const f4*)W;
  for (int k=0;k<DIN;k++){
    f4 wv = W4[k*32 + oq];
    float t0 = tt[(jg*2+0)*DIN + k];
    float t1 = tt[(jg*2+1)*DIN + k];
    a0.x += t0*wv.x; a0.y += t0*wv.y; a0.z += t0*wv.z; a0.w += t0*wv.w;
    a1.x += t1*wv.x; a1.y += t1*wv.y; a1.z += t1*wv.z; a1.w += t1*wv.w;
  }
  a0.x=fmaxf(a0.x,0.f); a0.y=fmaxf(a0.y,0.f); a0.z=fmaxf(a0.z,0.f); a0.w=fmaxf(a0.w,0.f);
  a1.x=fmaxf(a1.x,0.f); a1.y=fmaxf(a1.y,0.f); a1.z=fmaxf(a1.z,0.f); a1.w=fmaxf(a1.w,0.f);
  int j1 = j0 + jg*2, col = b*32 + oq;
  short4 s0, s1;
  s0.x=f2b(a0.x); s0.y=f2b(a0.y); s0.z=f2b(a0.z); s0.w=f2b(a0.w);
  s1.x=f2b(a1.x); s1.y=f2b(a1.y); s1.z=f2b(a1.z); s1.w=f2b(a1.w);
  *(short4*)(HoutB + (size_t)(j1+0)*1024 + col*4) = s0;
  *(short4*)(HoutB + (size_t)(j1+1)*1024 + col*4) = s1;
}

// ---------------- layer-2 head with fused node-mean: out += relu(..)/NN ----------------
template<int DIN, int FIN>
__global__ __launch_bounds__(256) void k_heads(const float* __restrict__ T, P8s parts, int np,
                                               const float* __restrict__ W, float* __restrict__ out){
  __shared__ float tt[16*DIN];
  __shared__ f4 red[256];
  int t = threadIdx.x;
  int j0 = blockIdx.x*16, b = blockIdx.y;
  for (int u=t; u<16*DIN/8; u+=256){
    int jj = u / (DIN/8), k8 = u % (DIN/8);
    size_t base = (size_t)(j0+jj)*FIN + b*DIN + k8*8;
    f4 x0 = *(const f4*)(T + base);
    f4 x1 = *(const f4*)(T + base + 4);
    float v[8] = {x0.x,x0.y,x0.z,x0.w,x1.x,x1.y,x1.z,x1.w};
    for (int j=0;j<np;j++){
      bf16x8 p = *(const bf16x8*)(parts.p[j] + base);
      #pragma unroll
      for (int q=0;q<8;q++) v[q] += b2f((unsigned short)p[q]);
    }
    #pragma unroll
    for (int q=0;q<8;q++) tt[jj*DIN + k8*8 + q] = v[q];
  }
  __syncthreads();
  int oq = t & 31, jg = t >> 5;
  f4 a0 = {0,0,0,0}, a1 = {0,0,0,0};
  const f4* W4 = (const f4*)W;
  for (int k=0;k<DIN;k++){
    f4 wv = W4[k*32 + oq];
    float t0 = tt[(jg*2+0)*DIN + k];
    float t1 = tt[(jg*2+1)*DIN + k];
    a0.x += t0*wv.x; a0.y += t0*wv.y; a0.z += t0*wv.z; a0.w += t0*wv.w;
    a1.x += t1*wv.x; a1.y += t1*wv.y; a1.z += t1*wv.z; a1.w += t1*wv.w;
  }
  f4 s;
  s.x = fmaxf(a0.x,0.f) + fmaxf(a1.x,0.f);
  s.y = fmaxf(a0.y,0.f) + fmaxf(a1.y,0.f);
  s.z = fmaxf(a0.z,0.f) + fmaxf(a1.z,0.f);
  s.w = fmaxf(a0.w,0.f) + fmaxf(a1.w,0.f);
  red[t] = s;
  __syncthreads();
  if (t < 32){
    f4 tot = red[t];
    #pragma unroll
    for (int u=1;u<8;u++){
      f4 x = red[u*32 + t];
      tot.x+=x.x; tot.y+=x.y; tot.z+=x.z; tot.w+=x.w;
    }
    const float sc = 1.0f/8192.0f;
    atomicAdd(&out[b*128 + t*4 + 0], tot.x*sc);
    atomicAdd(&out[b*128 + t*4 + 1], tot.y*sc);
    atomicAdd(&out[b*128 + t*4 + 2], tot.z*sc);
    atomicAdd(&out[b*128 + t*4 + 3], tot.w*sc);
  }
}

// ---------------- launcher ----------------
extern "C" void kernel_launch(void* const* d_in, const int* in_sizes, int n_in,
                              void* d_out, int out_size, void* d_ws, size_t ws_size,
                              hipStream_t stream){
  const int*   A1i = (const int*)d_in[0];
  const float* A1v = (const float*)d_in[1];
  const int*   A2i = (const int*)d_in[2];
  const float* A2v = (const float*)d_in[3];
  const float* X   = (const float*)d_in[4];
  const float* Z   = (const float*)d_in[5];
  const float* W1  = (const float*)d_in[6];
  const float* W2  = (const float*)d_in[7];
  float* out = (float*)d_out;

  char* w = (char*)d_ws;
  size_t off = 0;
  auto alloc = [&](size_t b)->char* {
    char* p = w + off;
    off += (b + 1023) & ~(size_t)1023;
    return p;
  };
  const size_t MB = 1024*1024;
  float* sb    = (float*)alloc(NN*4);
  int*   ptr1  = (int*)  alloc((NN+1)*4);
  int*   ptr2  = (int*)  alloc((NN+1)*4);
  int*   cnt   = (int*)  alloc(2*NN*4);               // cnt1|cnt2 adjacent
  int*   cur1  = (int*)  alloc(NN*4);
  int*   cur2  = (int*)  alloc(NN*4);
  int*   cidx1 = (int*)  alloc(NNZE*4);
  float* cval1 = (float*)alloc(NNZE*4);
  int*   cidx2 = (int*)  alloc(NNZE*4);
  float* cval2 = (float*)alloc(NNZE*4);
  short* Zbf   = (short*)alloc((size_t)NN*64*2);      // 1 MB
  short* XT1b  = (short*)alloc((size_t)NN*512*2);     // 8 MB  X^T bf16
  short* BUFA  = (short*)alloc((size_t)NN*1024*2);    // 16 MB x1a
  short* BUFB  = (short*)alloc((size_t)NN*1024*2);    // 16 MB x1b
  short* HTb   = (short*)alloc((size_t)NN*1024*2);    // 16 MB H bf16 (layer bridge)
  short* YS    = (short*)alloc((size_t)NN*1024*2);    // 16 MB Yt
  float* T1    = (float*)alloc((size_t)NN*512*4);     // 16 MB
  float* T2    = (float*)alloc((size_t)NN*1024*4);    // 32 MB
  char*  PART  = alloc((size_t)32*MB);                // attn bf16 partials
  (void)ws_size;
  int* cnt1 = cnt;
  int* cnt2 = cnt + NN;

  // CSR for A1+A2 (fused dual-matrix build: 4 dispatches)
  hipMemsetAsync(cnt, 0, 2*NN*4, stream);
  k_count2<<<dim3(NNZE/256, 2), 256, 0, stream>>>(A1i, A2i, cnt1, cnt2);
  k_scan2<<<2, 1024, 0, stream>>>(cnt1, cnt2, ptr1, ptr2, cur1, cur2);
  k_fill2<<<dim3(NNZE/256, 2), 256, 0, stream>>>(A1i, A1v, A2i, A2v, cur1, cur2,
                                                 cidx1, cval1, cidx2, cval2);

  // Z bf16, softmax column sums, X^T bf16, out zero
  k_zb<<<NN*64/256, 256, 0, stream>>>(Z, Zbf);
  hipMemsetAsync(sb, 0, NN*4, stream);
  hipMemsetAsync(out, 0, 1024*4, stream);
  k_colsum_mfma<<<dim3(NN/128, 8), 512, 0, stream>>>(Zbf, sb);
  k_transb<512><<<dim3(NN/32, 512/32), 256, 0, stream>>>(X, XT1b);

  // ---- layer 1 (F=512) ----
  k_spmm2<512><<<dim3(NN/4, 2), 256, 0, stream>>>(ptr1, cidx1, cval1, ptr2, cidx2, cval2,
                                                  XT1b, BUFA, BUFB);
  k_cheb2<512><<<NN/4, 256, 0, stream>>>(ptr1, cidx1, cval1, ptr2, cidx2, cval2,
                                         BUFA, BUFB, XT1b, T1);
  k_scaleb<<<512*NN/4/256, 256, 0, stream>>>(X, sb, YS);     // Yt1 = X[f][n]/s[n]
  {
    P8s pp{};
    for (int i=0;i<4;i++) pp.p[i] = (short*)(PART + (size_t)i*8*MB);
    k_attn2<512><<<dim3(NN/128, 2, 4), 512, 0, stream>>>(Zbf, YS, pp, NN/4);
    k_headm<64,512><<<dim3(NN/16, 8), 256, 0, stream>>>(T1, pp, 4, W1, HTb);
  }

  // ---- layer 2 (F=1024) ----
  k_spmm2<1024><<<dim3(NN/2, 2), 256, 0, stream>>>(ptr1, cidx1, cval1, ptr2, cidx2, cval2,
                                                   HTb, BUFA, BUFB);
  k_cheb2<1024><<<NN/2, 256, 0, stream>>>(ptr1, cidx1, cval1, ptr2, cidx2, cval2,
                                          BUFA, BUFB, HTb, T2);
  k_downt2<<<dim3(NN/32, 1024/32), 256, 0, stream>>>(HTb, sb, YS);
  {
    P8s pp{};
    pp.p[0] = (short*)PART;
    pp.p[1] = (short*)(PART + (size_t)16*MB);
    k_attn2<1024><<<dim3(NN/128, 4, 2), 512, 0, stream>>>(Zbf, YS, pp, NN/2);
    k_heads<128,1024><<<dim3(NN/16, 8), 256, 0, stream>>>(T2, pp, 2, W2, out);
  }
}

// Round 11
// 716.321 us; speedup vs baseline: 1.8212x; 1.0571x over previous
//
#include <hip/hip_runtime.h>

// GWNet on MI355X — round 11.
// - Co-scheduled kernels: grid-partitioned [attn blocks | gather blocks].
//   Per layer: fused<F,0> = attn(kz half A) ∥ dual-spmm; fused<F,1> =
//   attn(kz half B) ∥ cheb. Gather work hides under attn's stall cycles
//   (attn: 6.7% HBM, 38% MFMA — huge idle memory capacity).
// - relu dropped inside exp (attn + colsum consistently): colmax >= ~21
//   via the diagonal, so relu'd entries carry weight <= e^-21. Saves VALU.
// - Everything else from round 10 (bf16 partials, full-spread XOR, setprio,
//   fused CSR build, fused node-mean head).

#define NN 8192
#define NNZE 131072
#define CSHIFT 48.0f

typedef float4 f4;
typedef __attribute__((ext_vector_type(8))) short bf16x8;
typedef __attribute__((ext_vector_type(4))) float f32x4;

typedef __attribute__((address_space(3))) short lds_short;
typedef __attribute__((address_space(1))) const short glb_short;

struct P8s { short* p[8]; };

__device__ inline short f2b(float x){
  unsigned u = __float_as_uint(x);
  unsigned r = (u + 0x7fffu + ((u >> 16) & 1u)) >> 16;
  return (short)r;
}
__device__ inline float b2f(unsigned short b){
  return __uint_as_float(((unsigned)b) << 16);
}

// ---------------- CSR build (dual-matrix fused) ----------------
__global__ __launch_bounds__(256) void k_count2(const int* __restrict__ i1, const int* __restrict__ i2,
                                                int* __restrict__ c1, int* __restrict__ c2){
  int e = blockIdx.x*256 + threadIdx.x;
  if (blockIdx.y == 0) atomicAdd(&c1[i1[e]], 1);
  else                 atomicAdd(&c2[i2[e]], 1);
}

__global__ __launch_bounds__(1024) void k_scan2(const int* __restrict__ cnt1, const int* __restrict__ cnt2,
                                                int* __restrict__ ptr1, int* __restrict__ ptr2,
                                                int* __restrict__ cur1, int* __restrict__ cur2){
  __shared__ int sums[1024];
  const int* cnt = blockIdx.x ? cnt2 : cnt1;
  int* ptr = blockIdx.x ? ptr2 : ptr1;
  int* cur = blockIdx.x ? cur2 : cur1;
  int t = threadIdx.x;
  int loc[8]; int s = 0;
  #pragma unroll
  for (int i=0;i<8;i++){ loc[i]=s; s += cnt[t*8+i]; }
  sums[t]=s; __syncthreads();
  for (int off=1; off<1024; off<<=1){
    int v = (t>=off) ? sums[t-off] : 0;
    __syncthreads();
    sums[t] += v;
    __syncthreads();
  }
  int excl = sums[t]-s;
  #pragma unroll
  for (int i=0;i<8;i++){ int v = excl + loc[i]; ptr[t*8+i] = v; cur[t*8+i] = v; }
  if (t==1023) ptr[NN] = sums[1023];
}

__global__ __launch_bounds__(256) void k_fill2(const int* __restrict__ i1, const float* __restrict__ v1,
                                               const int* __restrict__ i2, const float* __restrict__ v2,
                                               int* __restrict__ cur1, int* __restrict__ cur2,
                                               int* __restrict__ cidx1, float* __restrict__ cval1,
                                               int* __restrict__ cidx2, float* __restrict__ cval2){
  int e = blockIdx.x*256 + threadIdx.x;
  const int* idx; const float* vals; int* cur; int* cidx; float* cval;
  if (blockIdx.y == 0){ idx=i1; vals=v1; cur=cur1; cidx=cidx1; cval=cval1; }
  else                { idx=i2; vals=v2; cur=cur2; cidx=cidx2; cval=cval2; }
  int r = idx[e], c = idx[NNZE+e];
  int p = atomicAdd(&cur[r], 1);
  cidx[p] = c; cval[p] = vals[e];
}

// ---------------- transpose X (R,NN)->(NN,R) bf16 ----------------
template<int R>
__global__ __launch_bounds__(256) void k_transb(const float* __restrict__ src, short* __restrict__ dstb){
  __shared__ float tile[32][33];
  int tx = threadIdx.x & 31, ty = threadIdx.x >> 5;
  int j0 = blockIdx.x*32, f0 = blockIdx.y*32;
  #pragma unroll
  for (int u=0;u<32;u+=8) tile[ty+u][tx] = src[(size_t)(f0+ty+u)*NN + j0+tx];
  __syncthreads();
  #pragma unroll
  for (int u=0;u<32;u+=8) dstb[(size_t)(j0+ty+u)*R + f0+tx] = f2b(tile[tx][ty+u]);
}

// ---------------- Z -> bf16 ----------------
__global__ __launch_bounds__(256) void k_zb(const float* __restrict__ Z, short* __restrict__ Zb){
  int i = blockIdx.x*256 + threadIdx.x;
  Zb[i] = f2b(Z[i]);
}

// ---------------- column sums via MFMA: sb[j] = sum_i exp(zi.zj - C) ----------------
__global__ __launch_bounds__(512) void k_colsum_mfma(const short* __restrict__ Zb, float* __restrict__ sb){
  int t = threadIdx.x;
  int w = t >> 6, l = t & 63;
  int lo = l & 15, g = l >> 4;
  int j = blockIdx.x*128 + w*16 + lo;
  const bf16x8* Zb8 = (const bf16x8*)Zb;
  bf16x8 bj0 = Zb8[j*8 + g];
  bf16x8 bj1 = Zb8[j*8 + g + 4];
  int i0 = blockIdx.y * (NN/8);
  float sum = 0.f;
  for (int i = i0; i < i0 + NN/8; i += 16){
    bf16x8 a0 = Zb8[(size_t)(i+lo)*8 + g];
    bf16x8 a1 = Zb8[(size_t)(i+lo)*8 + g + 4];
    f32x4 s = (f32x4){0.f,0.f,0.f,0.f};
    s = __builtin_amdgcn_mfma_f32_16x16x32_bf16(a0, bj0, s, 0,0,0);
    s = __builtin_amdgcn_mfma_f32_16x16x32_bf16(a1, bj1, s, 0,0,0);
    #pragma unroll
    for (int r=0;r<4;r++) sum += __expf(s[r] - CSHIFT);
  }
  sum += __shfl_xor(sum, 16);
  sum += __shfl_xor(sum, 32);
  if (g == 0) atomicAdd(sb + j, sum);
}

// ---------------- layer-1 Yt: Yt[f][node] = bf16(X[f][node] / s[node]) ----------------
__global__ __launch_bounds__(256) void k_scaleb(const float* __restrict__ X, const float* __restrict__ sb,
                                                short* __restrict__ Yt){
  int i = blockIdx.x*256 + threadIdx.x;
  int node4 = i & (NN/4 - 1);
  f4 x = ((const f4*)X)[i];
  f4 sv = ((const f4*)sb)[node4];
  short4 o;
  o.x = f2b(x.x*(1.0f/sv.x)); o.y = f2b(x.y*(1.0f/sv.y));
  o.z = f2b(x.z*(1.0f/sv.z)); o.w = f2b(x.w*(1.0f/sv.w));
  ((short4*)Yt)[i] = o;
}

// ---------------- layer-2 Yt: transpose bf16 H, scale by 1/s ----------------
__global__ __launch_bounds__(256) void k_downt2(const short* __restrict__ Hb, const float* __restrict__ sb,
                                                short* __restrict__ Yt){
  __shared__ float tile[32][33];
  int tx = threadIdx.x & 31, ty = threadIdx.x >> 5;
  int k0 = blockIdx.x*32, n0 = blockIdx.y*32;
  #pragma unroll
  for (int u=0;u<32;u+=8) tile[ty+u][tx] = b2f((unsigned short)Hb[(size_t)(k0+ty+u)*1024 + n0+tx]);
  __syncthreads();
  float sv = 1.0f / sb[k0+tx];
  #pragma unroll
  for (int u=0;u<32;u+=8) Yt[(size_t)(n0+ty+u)*NN + k0+tx] = f2b(tile[tx][ty+u] * sv);
}

// ---------------- fused: [attn blocks | gather blocks] ----------------
// attn: BM=128/BN=256/BK=32, 8 waves, full-spread XOR LDS, bf16 partials.
// MODE 0 gather = dual spmm (A1.g1->so1, A2.g1->so2, bf16 out).
// MODE 1 gather = cheb (T = g1 + g2 + 2A1.g1 + 2A2.g2 - gy, f32 out).
template<int F, int MODE>
__global__ __launch_bounds__(512, 4) void k_fused(
    const short* __restrict__ Zb, const short* __restrict__ YS, P8s pp, int ksize, int kzbase, int nattn,
    const int* __restrict__ ptr1, const int* __restrict__ cidx1, const float* __restrict__ cval1,
    const int* __restrict__ ptr2, const int* __restrict__ cidx2, const float* __restrict__ cval2,
    const short* __restrict__ g1, const short* __restrict__ g2, const short* __restrict__ gy,
    short* __restrict__ so1, short* __restrict__ so2, float* __restrict__ T)
{
  __shared__ __align__(16) short zk[2][32*64];
  __shared__ __align__(16) short yt[2][256*32];
  __shared__ __align__(16) short p_lds[128*40];
  int t = threadIdx.x;

  if ((int)blockIdx.x < nattn){
    // ================= attention path =================
    constexpr int NBY = F/256;
    int id = blockIdx.x;
    int bx = id & 63, rest = id >> 6;
    int m0 = bx * 128;
    int n0 = (rest % NBY) * 256;
    int kz = kzbase + rest / NBY;
    int kbeg = kz * ksize, kend = kbeg + ksize;
    int w = t >> 6, l = t & 63;
    int lo = l & 15, g = l >> 4;
    int wm = w >> 2, wn = w & 3;

    const bf16x8* Zb8 = (const bf16x8*)Zb;
    int zirow = m0 + w*16 + lo;
    bf16x8 ziA0 = Zb8[(size_t)zirow*8 + g];
    bf16x8 ziA1 = Zb8[(size_t)zirow*8 + g + 4];

    f32x4 acc[4][4];
    #pragma unroll
    for (int i=0;i<4;i++)
      #pragma unroll
      for (int j=0;j<4;j++) acc[i][j] = (f32x4){0.f,0.f,0.f,0.f};

    auto STAGE = [&](int b, int kk){
      if (t < 256){
        int r = t >> 3, c = t & 7;
        const short* src = Zb + (((size_t)(kk + r)) << 6) + ((c ^ (r & 7)) << 3);
        __builtin_amdgcn_global_load_lds((glb_short*)src, (lds_short*)&zk[b][t*8], 16, 0, 0);
      }
      #pragma unroll
      for (int p=0;p<2;p++){
        int cc = p*512 + t;
        int r = cc >> 2, c = cc & 3;
        const short* src = YS + (size_t)(n0 + r)*NN + kk + ((c ^ ((r >> 1) & 3)) << 3);
        __builtin_amdgcn_global_load_lds((glb_short*)src, (lds_short*)&yt[b][cc*8], 16, 0, 0);
      }
    };

    STAGE(0, kbeg);
    __syncthreads();

    int cur = 0;
    for (int k0 = kbeg; k0 < kend; k0 += 32){
      int xa = g ^ (lo & 7), xb = (g + 4) ^ (lo & 7);
      bf16x8 b00 = *(const bf16x8*)&zk[cur][(lo*8 + xa)*8];
      bf16x8 b01 = *(const bf16x8*)&zk[cur][(lo*8 + xb)*8];
      bf16x8 b10 = *(const bf16x8*)&zk[cur][((16+lo)*8 + xa)*8];
      bf16x8 b11 = *(const bf16x8*)&zk[cur][((16+lo)*8 + xb)*8];
      f32x4 s0 = (f32x4){0.f,0.f,0.f,0.f};
      f32x4 s1 = (f32x4){0.f,0.f,0.f,0.f};
      s0 = __builtin_amdgcn_mfma_f32_16x16x32_bf16(ziA0, b00, s0, 0,0,0);
      s0 = __builtin_amdgcn_mfma_f32_16x16x32_bf16(ziA1, b01, s0, 0,0,0);
      s1 = __builtin_amdgcn_mfma_f32_16x16x32_bf16(ziA0, b10, s1, 0,0,0);
      s1 = __builtin_amdgcn_mfma_f32_16x16x32_bf16(ziA1, b11, s1, 0,0,0);
      short e0[4], e1[4];
      #pragma unroll
      for (int r=0;r<4;r++){
        e0[r] = f2b(__expf(s0[r] - CSHIFT));   // relu dropped: weight diff <= e^-21
        e1[r] = f2b(__expf(s1[r] - CSHIFT));
      }
      __syncthreads();
      if (k0 + 32 < kend) STAGE(cur ^ 1, k0 + 32);
      int prow = w*16 + g*4;
      #pragma unroll
      for (int r=0;r<4;r++){
        p_lds[(prow+r)*40 + lo]      = e0[r];
        p_lds[(prow+r)*40 + 16 + lo] = e1[r];
      }
      __syncthreads();
      bf16x8 aP[4];
      #pragma unroll
      for (int mf=0; mf<4; mf++)
        aP[mf] = *(const bf16x8*)&p_lds[(wm*64 + mf*16 + lo)*40 + g*8];
      __builtin_amdgcn_s_setprio(1);
      #pragma unroll
      for (int nf=0; nf<4; nf++){
        int nl = wn*64 + nf*16 + lo;
        bf16x8 bY = *(const bf16x8*)&yt[cur][(nl*4 + (g ^ ((nl >> 1) & 3)))*8];
        #pragma unroll
        for (int mf=0; mf<4; mf++)
          acc[mf][nf] = __builtin_amdgcn_mfma_f32_16x16x32_bf16(aP[mf], bY, acc[mf][nf], 0,0,0);
      }
      __builtin_amdgcn_s_setprio(0);
      cur ^= 1;
    }
    short* outp = pp.p[kz];
    #pragma unroll
    for (int mf=0; mf<4; mf++){
      int row = m0 + wm*64 + mf*16 + g*4;
      #pragma unroll
      for (int nf=0; nf<4; nf++){
        int col = n0 + wn*64 + nf*16 + lo;
        #pragma unroll
        for (int r=0;r<4;r++)
          outp[(size_t)(row+r)*F + col] = f2b(acc[mf][nf][r]);
      }
    }
  } else {
    // ================= gather path =================
    constexpr int LPR = F/8;
    constexpr int RPB = 512/LPR;
    int gid = blockIdx.x - nattn;
    int ts = t % LPR, rl = t / LPR;
    if (MODE == 0){
      constexpr int M = NN/RPB;
      int mat = gid / M;
      int blk = gid - mat*M;
      const int*   ptr  = mat ? ptr2  : ptr1;
      const int*   cidx = mat ? cidx2 : cidx1;
      const float* cval = mat ? cval2 : cval1;
      short* outb = mat ? so2 : so1;
      int r = blk*RPB + rl;
      const bf16x8* Y8 = (const bf16x8*)g1;
      int p0 = ptr[r], p1 = ptr[r+1];
      float a[8];
      #pragma unroll
      for (int j=0;j<8;j++) a[j]=0.f;
      int p = p0;
      for (; p+3 < p1; p += 4){
        int   c0=cidx[p], c1=cidx[p+1], c2=cidx[p+2], c3=cidx[p+3];
        float v0=cval[p], v1=cval[p+1], v2=cval[p+2], v3=cval[p+3];
        bf16x8 x0 = Y8[(size_t)c0*LPR + ts];
        bf16x8 x1 = Y8[(size_t)c1*LPR + ts];
        bf16x8 x2 = Y8[(size_t)c2*LPR + ts];
        bf16x8 x3 = Y8[(size_t)c3*LPR + ts];
        #pragma unroll
        for (int j=0;j<8;j++) a[j] += v0*b2f((unsigned short)x0[j]);
        #pragma unroll
        for (int j=0;j<8;j++) a[j] += v1*b2f((unsigned short)x1[j]);
        #pragma unroll
        for (int j=0;j<8;j++) a[j] += v2*b2f((unsigned short)x2[j]);
        #pragma unroll
        for (int j=0;j<8;j++) a[j] += v3*b2f((unsigned short)x3[j]);
      }
      for (; p < p1; ++p){
        int c0 = cidx[p]; float v0 = cval[p];
        bf16x8 x0 = Y8[(size_t)c0*LPR + ts];
        #pragma unroll
        for (int j=0;j<8;j++) a[j] += v0*b2f((unsigned short)x0[j]);
      }
      bf16x8 o;
      #pragma unroll
      for (int j=0;j<8;j++) o[j] = f2b(a[j]);
      ((bf16x8*)outb)[(size_t)r*LPR + ts] = o;
    } else {
      int r = gid*RPB + rl;
      const bf16x8* Xa = (const bf16x8*)g1;
      const bf16x8* Xb = (const bf16x8*)g2;
      float a[8];
      #pragma unroll
      for (int j=0;j<8;j++) a[j]=0.f;
      {
        int p0 = ptr1[r], p1 = ptr1[r+1];
        int p = p0;
        for (; p+3 < p1; p += 4){
          int   c0=cidx1[p], c1=cidx1[p+1], c2=cidx1[p+2], c3=cidx1[p+3];
          float v0=cval1[p], v1=cval1[p+1], v2=cval1[p+2], v3=cval1[p+3];
          bf16x8 x0 = Xa[(size_t)c0*LPR + ts];
          bf16x8 x1 = Xa[(size_t)c1*LPR + ts];
          bf16x8 x2 = Xa[(size_t)c2*LPR + ts];
          bf16x8 x3 = Xa[(size_t)c3*LPR + ts];
          #pragma unroll
          for (int j=0;j<8;j++) a[j] += v0*b2f((unsigned short)x0[j]);
          #pragma unroll
          for (int j=0;j<8;j++) a[j] += v1*b2f((unsigned short)x1[j]);
          #pragma unroll
          for (int j=0;j<8;j++) a[j] += v2*b2f((unsigned short)x2[j]);
          #pragma unroll
          for (int j=0;j<8;j++) a[j] += v3*b2f((unsigned short)x3[j]);
        }
        for (; p < p1; ++p){
          int c0 = cidx1[p]; float v0 = cval1[p];
          bf16x8 x0 = Xa[(size_t)c0*LPR + ts];
          #pragma unroll
          for (int j=0;j<8;j++) a[j] += v0*b2f((unsigned short)x0[j]);
        }
      }
      {
        int p0 = ptr2[r], p1 = ptr2[r+1];
        int p = p0;
        for (; p+3 < p1; p += 4){
          int   c0=cidx2[p], c1=cidx2[p+1], c2=cidx2[p+2], c3=cidx2[p+3];
          float v0=cval2[p], v1=cval2[p+1], v2=cval2[p+2], v3=cval2[p+3];
          bf16x8 x0 = Xb[(size_t)c0*LPR + ts];
          bf16x8 x1 = Xb[(size_t)c1*LPR + ts];
          bf16x8 x2 = Xb[(size_t)c2*LPR + ts];
          bf16x8 x3 = Xb[(size_t)c3*LPR + ts];
          #pragma unroll
          for (int j=0;j<8;j++) a[j] += v0*b2f((unsigned short)x0[j]);
          #pragma unroll
          for (int j=0;j<8;j++) a[j] += v1*b2f((unsigned short)x1[j]);
          #pragma unroll
          for (int j=0;j<8;j++) a[j] += v2*b2f((unsigned short)x2[j]);
          #pragma unroll
          for (int j=0;j<8;j++) a[j] += v3*b2f((unsigned short)x3[j]);
        }
        for (; p < p1; ++p){
          int c0 = cidx2[p]; float v0 = cval2[p];
          bf16x8 x0 = Xb[(size_t)c0*LPR + ts];
          #pragma unroll
          for (int j=0;j<8;j++) a[j] += v0*b2f((unsigned short)x0[j]);
        }
      }
      bf16x8 sa = Xa[(size_t)r*LPR + ts];
      bf16x8 sbv = Xb[(size_t)r*LPR + ts];
      bf16x8 yv = ((const bf16x8*)gy)[(size_t)r*LPR + ts];
      float o[8];
      #pragma unroll
      for (int j=0;j<8;j++)
        o[j] = 2.f*a[j] + b2f((unsigned short)sa[j]) + b2f((unsigned short)sbv[j]) - b2f((unsigned short)yv[j]);
      size_t o4 = ((size_t)r*F + ts*8) >> 2;
      ((f4*)T)[o4]   = (f4){o[0],o[1],o[2],o[3]};
      ((f4*)T)[o4+1] = (f4){o[4],o[5],o[6],o[7]};
    }
  }
}

// ---------------- head GEMM with fused partial merge; bf16 H out (layer 1) ----------------
template<int DIN, int FIN>
__global__ __launch_bounds__(256) void k_headm(const float* __restrict__ T, P8s parts, int np,
                                               const float* __restrict__ W,
                                               short* __restrict__ HoutB){
  __shared__ float tt[16*DIN];
  int t = threadIdx.x;
  int j0 = blockIdx.x*16, b = blockIdx.y;
  for (int u=t; u<16*DIN/8; u+=256){
    int jj = u / (DIN/8), k8 = u % (DIN/8);
    size_t base = (size_t)(j0+jj)*FIN + b*DIN + k8*8;
    f4 x0 = *(const f4*)(T + base);
    f4 x1 = *(const f4*)(T + base + 4);
    float v[8] = {x0.x,x0.y,x0.z,x0.w,x1.x,x1.y,x1.z,x1.w};
    for (int j=0;j<np;j++){
      bf16x8 p = *(const bf16x8*)(parts.p[j] + base);
      #pragma unroll
      for (int q=0;q<8;q++) v[q] += b2f((unsigned short)p[q]);
    }
    #pragma unroll
    for (int q=0;q<8;q++) tt[jj*DIN + k8*8 + q] = v[q];
  }
  __syncthreads();
  int oq = t & 31, jg = t >> 5;
  f4 a0 = {0,0,0,0}, a1 = {0,0,0,0};
  const f4* W4 = (const f4*)W;
  for (int k=0;k<DIN;k++){
    f4 wv = W4[k*32 + oq];
    float t0 = tt[(jg*2+0)*DIN + k];
    float t1 = tt[(jg*2+1)*DIN + k];
    a0.x += t0*wv.x; a0.y += t0*wv.y; a0.z += t0*wv.z; a0.w += t0*wv.w;
    a1.x += t1*wv.x; a1.y += t1*wv.y; a1.z += t1*wv.z; a1.w += t1*wv.w;
  }
  a0.x=fmaxf(a0.x,0.f); a0.y=fmaxf(a0.y,0.f); a0.z=fmaxf(a0.z,0.f); a0.w=fmaxf(a0.w,0.f);
  a1.x=fmaxf(a1.x,0.f); a1.y=fmaxf(a1.y,0.f); a1.z=fmaxf(a1.z,0.f); a1.w=fmaxf(a1.w,0.f);
  int j1 = j0 + jg*2, col = b*32 + oq;
  short4 s0, s1;
  s0.x=f2b(a0.x); s0.y=f2b(a0.y); s0.z=f2b(a0.z); s0.w=f2b(a0.w);
  s1.x=f2b(a1.x); s1.y=f2b(a1.y); s1.z=f2b(a1.z); s1.w=f2b(a1.w);
  *(short4*)(HoutB + (size_t)(j1+0)*1024 + col*4) = s0;
  *(short4*)(HoutB + (size_t)(j1+1)*1024 + col*4) = s1;
}

// ---------------- layer-2 head with fused node-mean ----------------
template<int DIN, int FIN>
__global__ __launch_bounds__(256) void k_heads(const float* __restrict__ T, P8s parts, int np,
                                               const float* __restrict__ W, float* __restrict__ out){
  __shared__ float tt[16*DIN];
  __shared__ f4 red[256];
  int t = threadIdx.x;
  int j0 = blockIdx.x*16, b = blockIdx.y;
  for (int u=t; u<16*DIN/8; u+=256){
    int jj = u / (DIN/8), k8 = u % (DIN/8);
    size_t base = (size_t)(j0+jj)*FIN + b*DIN + k8*8;
    f4 x0 = *(const f4*)(T + base);
    f4 x1 = *(const f4*)(T + base + 4);
    float v[8] = {x0.x,x0.y,x0.z,x0.w,x1.x,x1.y,x1.z,x1.w};
    for (int j=0;j<np;j++){
      bf16x8 p = *(const bf16x8*)(parts.p[j] + base);
      #pragma unroll
      for (int q=0;q<8;q++) v[q] += b2f((unsigned short)p[q]);
    }
    #pragma unroll
    for (int q=0;q<8;q++) tt[jj*DIN + k8*8 + q] = v[q];
  }
  __syncthreads();
  int oq = t & 31, jg = t >> 5;
  f4 a0 = {0,0,0,0}, a1 = {0,0,0,0};
  const f4* W4 = (const f4*)W;
  for (int k=0;k<DIN;k++){
    f4 wv = W4[k*32 + oq];
    float t0 = tt[(jg*2+0)*DIN + k];
    float t1 = tt[(jg*2+1)*DIN + k];
    a0.x += t0*wv.x; a0.y += t0*wv.y; a0.z += t0*wv.z; a0.w += t0*wv.w;
    a1.x += t1*wv.x; a1.y += t1*wv.y; a1.z += t1*wv.z; a1.w += t1*wv.w;
  }
  f4 s;
  s.x = fmaxf(a0.x,0.f) + fmaxf(a1.x,0.f);
  s.y = fmaxf(a0.y,0.f) + fmaxf(a1.y,0.f);
  s.z = fmaxf(a0.z,0.f) + fmaxf(a1.z,0.f);
  s.w = fmaxf(a0.w,0.f) + fmaxf(a1.w,0.f);
  red[t] = s;
  __syncthreads();
  if (t < 32){
    f4 tot = red[t];
    #pragma unroll
    for (int u=1;u<8;u++){
      f4 x = red[u*32 + t];
      tot.x+=x.x; tot.y+=x.y; tot.z+=x.z; tot.w+=x.w;
    }
    const float sc = 1.0f/8192.0f;
    atomicAdd(&out[b*128 + t*4 + 0], tot.x*sc);
    atomicAdd(&out[b*128 + t*4 + 1], tot.y*sc);
    atomicAdd(&out[b*128 + t*4 + 2], tot.z*sc);
    atomicAdd(&out[b*128 + t*4 + 3], tot.w*sc);
  }
}

// ---------------- launcher ----------------
extern "C" void kernel_launch(void* const* d_in, const int* in_sizes, int n_in,
                              void* d_out, int out_size, void* d_ws, size_t ws_size,
                              hipStream_t stream){
  const int*   A1i = (const int*)d_in[0];
  const float* A1v = (const float*)d_in[1];
  const int*   A2i = (const int*)d_in[2];
  const float* A2v = (const float*)d_in[3];
  const float* X   = (const float*)d_in[4];
  const float* Z   = (const float*)d_in[5];
  const float* W1  = (const float*)d_in[6];
  const float* W2  = (const float*)d_in[7];
  float* out = (float*)d_out;

  char* w = (char*)d_ws;
  size_t off = 0;
  auto alloc = [&](size_t b)->char* {
    char* p = w + off;
    off += (b + 1023) & ~(size_t)1023;
    return p;
  };
  const size_t MB = 1024*1024;
  float* sb    = (float*)alloc(NN*4);
  int*   ptr1  = (int*)  alloc((NN+1)*4);
  int*   ptr2  = (int*)  alloc((NN+1)*4);
  int*   cnt   = (int*)  alloc(2*NN*4);
  int*   cur1  = (int*)  alloc(NN*4);
  int*   cur2  = (int*)  alloc(NN*4);
  int*   cidx1 = (int*)  alloc(NNZE*4);
  float* cval1 = (float*)alloc(NNZE*4);
  int*   cidx2 = (int*)  alloc(NNZE*4);
  float* cval2 = (float*)alloc(NNZE*4);
  short* Zbf   = (short*)alloc((size_t)NN*64*2);
  short* XT1b  = (short*)alloc((size_t)NN*512*2);
  short* BUFA  = (short*)alloc((size_t)NN*1024*2);
  short* BUFB  = (short*)alloc((size_t)NN*1024*2);
  short* HTb   = (short*)alloc((size_t)NN*1024*2);
  short* YS    = (short*)alloc((size_t)NN*1024*2);
  float* T1    = (float*)alloc((size_t)NN*512*4);
  float* T2    = (float*)alloc((size_t)NN*1024*4);
  char*  PART  = alloc((size_t)32*MB);
  (void)ws_size;
  int* cnt1 = cnt;
  int* cnt2 = cnt + NN;

  // CSR build (fused dual-matrix)
  hipMemsetAsync(cnt, 0, 2*NN*4, stream);
  k_count2<<<dim3(NNZE/256, 2), 256, 0, stream>>>(A1i, A2i, cnt1, cnt2);
  k_scan2<<<2, 1024, 0, stream>>>(cnt1, cnt2, ptr1, ptr2, cur1, cur2);
  k_fill2<<<dim3(NNZE/256, 2), 256, 0, stream>>>(A1i, A1v, A2i, A2v, cur1, cur2,
                                                 cidx1, cval1, cidx2, cval2);

  // Z bf16, column sums, X^T bf16, out zero
  k_zb<<<NN*64/256, 256, 0, stream>>>(Z, Zbf);
  hipMemsetAsync(sb, 0, NN*4, stream);
  hipMemsetAsync(out, 0, 1024*4, stream);
  k_colsum_mfma<<<dim3(NN/128, 8), 512, 0, stream>>>(Zbf, sb);
  k_transb<512><<<dim3(NN/32, 512/32), 256, 0, stream>>>(X, XT1b);
  k_scaleb<<<512*NN/4/256, 256, 0, stream>>>(X, sb, YS);   // Yt1 = X[f][n]/s[n]

  // ---- layer 1 (F=512): attn kz 0..3 split across two co-scheduled launches ----
  P8s pp1{};
  for (int i=0;i<4;i++) pp1.p[i] = (short*)(PART + (size_t)i*8*MB);
  k_fused<512,0><<<256 + 2048, 512, 0, stream>>>(Zbf, YS, pp1, NN/4, 0, 256,
      ptr1, cidx1, cval1, ptr2, cidx2, cval2,
      XT1b, nullptr, nullptr, BUFA, BUFB, nullptr);
  k_fused<512,1><<<256 + 1024, 512, 0, stream>>>(Zbf, YS, pp1, NN/4, 2, 256,
      ptr1, cidx1, cval1, ptr2, cidx2, cval2,
      BUFA, BUFB, XT1b, nullptr, nullptr, T1);
  k_headm<64,512><<<dim3(NN/16, 8), 256, 0, stream>>>(T1, pp1, 4, W1, HTb);

  // ---- layer 2 (F=1024) ----
  k_downt2<<<dim3(NN/32, 1024/32), 256, 0, stream>>>(HTb, sb, YS);
  P8s pp2{};
  pp2.p[0] = (short*)PART;
  pp2.p[1] = (short*)(PART + (size_t)16*MB);
  k_fused<1024,0><<<256 + 4096, 512, 0, stream>>>(Zbf, YS, pp2, NN/2, 0, 256,
      ptr1, cidx1, cval1, ptr2, cidx2, cval2,
      HTb, nullptr, nullptr, BUFA, BUFB, nullptr);
  k_fused<1024,1><<<256 + 2048, 512, 0, stream>>>(Zbf, YS, pp2, NN/2, 1, 256,
      ptr1, cidx1, cval1, ptr2, cidx2, cval2,
      BUFA, BUFB, HTb, nullptr, nullptr, T2);
  k_heads<128,1024><<<dim3(NN/16, 8), 256, 0, stream>>>(T2, pp2, 2, W2, out);
}

// Round 12
// 596.678 us; speedup vs baseline: 2.1863x; 1.2005x over previous
//
#include <hip/hip_runtime.h>

// GWNet on MI355X — round 12.
// - Head GEMMs rewritten on MFMA (were scalar-VALU, latency-bound: 158 µs
//   @ MfmaUtil=0). A = merged (T + partials) bf16 in XOR-swizzled LDS;
//   B = precomputed transposed bf16 W (direct-global, L2-hot); C layout per
//   the proven attn conventions. Layer-1 head also emits the layer-2 Yt
//   (transpose+scale via LDS tile) — k_downt2 deleted.
// - Everything else identical to round 11 (co-scheduled fused attn+gather,
//   bf16 partials, full-spread XOR, fused CSR build).

#define NN 8192
#define NNZE 131072
#define CSHIFT 48.0f

typedef float4 f4;
typedef __attribute__((ext_vector_type(8))) short bf16x8;
typedef __attribute__((ext_vector_type(4))) float f32x4;

typedef __attribute__((address_space(3))) short lds_short;
typedef __attribute__((address_space(1))) const short glb_short;

struct P8s { short* p[8]; };

__device__ inline short f2b(float x){
  unsigned u = __float_as_uint(x);
  unsigned r = (u + 0x7fffu + ((u >> 16) & 1u)) >> 16;
  return (short)r;
}
__device__ inline float b2f(unsigned short b){
  return __uint_as_float(((unsigned)b) << 16);
}

// ---------------- CSR build (dual-matrix fused) ----------------
__global__ __launch_bounds__(256) void k_count2(const int* __restrict__ i1, const int* __restrict__ i2,
                                                int* __restrict__ c1, int* __restrict__ c2){
  int e = blockIdx.x*256 + threadIdx.x;
  if (blockIdx.y == 0) atomicAdd(&c1[i1[e]], 1);
  else                 atomicAdd(&c2[i2[e]], 1);
}

__global__ __launch_bounds__(1024) void k_scan2(const int* __restrict__ cnt1, const int* __restrict__ cnt2,
                                                int* __restrict__ ptr1, int* __restrict__ ptr2,
                                                int* __restrict__ cur1, int* __restrict__ cur2){
  __shared__ int sums[1024];
  const int* cnt = blockIdx.x ? cnt2 : cnt1;
  int* ptr = blockIdx.x ? ptr2 : ptr1;
  int* cur = blockIdx.x ? cur2 : cur1;
  int t = threadIdx.x;
  int loc[8]; int s = 0;
  #pragma unroll
  for (int i=0;i<8;i++){ loc[i]=s; s += cnt[t*8+i]; }
  sums[t]=s; __syncthreads();
  for (int off=1; off<1024; off<<=1){
    int v = (t>=off) ? sums[t-off] : 0;
    __syncthreads();
    sums[t] += v;
    __syncthreads();
  }
  int excl = sums[t]-s;
  #pragma unroll
  for (int i=0;i<8;i++){ int v = excl + loc[i]; ptr[t*8+i] = v; cur[t*8+i] = v; }
  if (t==1023) ptr[NN] = sums[1023];
}

__global__ __launch_bounds__(256) void k_fill2(const int* __restrict__ i1, const float* __restrict__ v1,
                                               const int* __restrict__ i2, const float* __restrict__ v2,
                                               int* __restrict__ cur1, int* __restrict__ cur2,
                                               int* __restrict__ cidx1, float* __restrict__ cval1,
                                               int* __restrict__ cidx2, float* __restrict__ cval2){
  int e = blockIdx.x*256 + threadIdx.x;
  const int* idx; const float* vals; int* cur; int* cidx; float* cval;
  if (blockIdx.y == 0){ idx=i1; vals=v1; cur=cur1; cidx=cidx1; cval=cval1; }
  else                { idx=i2; vals=v2; cur=cur2; cidx=cidx2; cval=cval2; }
  int r = idx[e], c = idx[NNZE+e];
  int p = atomicAdd(&cur[r], 1);
  cidx[p] = c; cval[p] = vals[e];
}

// ---------------- transpose X (R,NN)->(NN,R) bf16 ----------------
template<int R>
__global__ __launch_bounds__(256) void k_transb(const float* __restrict__ src, short* __restrict__ dstb){
  __shared__ float tile[32][33];
  int tx = threadIdx.x & 31, ty = threadIdx.x >> 5;
  int j0 = blockIdx.x*32, f0 = blockIdx.y*32;
  #pragma unroll
  for (int u=0;u<32;u+=8) tile[ty+u][tx] = src[(size_t)(f0+ty+u)*NN + j0+tx];
  __syncthreads();
  #pragma unroll
  for (int u=0;u<32;u+=8) dstb[(size_t)(j0+ty+u)*R + f0+tx] = f2b(tile[tx][ty+u]);
}

// ---------------- Z -> bf16 ----------------
__global__ __launch_bounds__(256) void k_zb(const float* __restrict__ Z, short* __restrict__ Zb){
  int i = blockIdx.x*256 + threadIdx.x;
  Zb[i] = f2b(Z[i]);
}

// ---------------- W -> transposed bf16: Wt[o][k] ----------------
__global__ __launch_bounds__(256) void k_wt(const float* __restrict__ W1, const float* __restrict__ W2,
                                            short* __restrict__ W1t, short* __restrict__ W2t){
  int t = threadIdx.x;
  if (blockIdx.x == 0){
    for (int i=t; i<64*128; i+=256){ int k=i>>7, o=i&127; W1t[o*64+k] = f2b(W1[i]); }
  } else {
    for (int i=t; i<128*128; i+=256){ int k=i>>7, o=i&127; W2t[o*128+k] = f2b(W2[i]); }
  }
}

// ---------------- column sums via MFMA: sb[j] = sum_i exp(zi.zj - C) ----------------
__global__ __launch_bounds__(512) void k_colsum_mfma(const short* __restrict__ Zb, float* __restrict__ sb){
  int t = threadIdx.x;
  int w = t >> 6, l = t & 63;
  int lo = l & 15, g = l >> 4;
  int j = blockIdx.x*128 + w*16 + lo;
  const bf16x8* Zb8 = (const bf16x8*)Zb;
  bf16x8 bj0 = Zb8[j*8 + g];
  bf16x8 bj1 = Zb8[j*8 + g + 4];
  int i0 = blockIdx.y * (NN/8);
  float sum = 0.f;
  for (int i = i0; i < i0 + NN/8; i += 16){
    bf16x8 a0 = Zb8[(size_t)(i+lo)*8 + g];
    bf16x8 a1 = Zb8[(size_t)(i+lo)*8 + g + 4];
    f32x4 s = (f32x4){0.f,0.f,0.f,0.f};
    s = __builtin_amdgcn_mfma_f32_16x16x32_bf16(a0, bj0, s, 0,0,0);
    s = __builtin_amdgcn_mfma_f32_16x16x32_bf16(a1, bj1, s, 0,0,0);
    #pragma unroll
    for (int r=0;r<4;r++) sum += __expf(s[r] - CSHIFT);
  }
  sum += __shfl_xor(sum, 16);
  sum += __shfl_xor(sum, 32);
  if (g == 0) atomicAdd(sb + j, sum);
}

// ---------------- layer-1 Yt: Yt[f][node] = bf16(X[f][node] / s[node]) ----------------
__global__ __launch_bounds__(256) void k_scaleb(const float* __restrict__ X, const float* __restrict__ sb,
                                                short* __restrict__ Yt){
  int i = blockIdx.x*256 + threadIdx.x;
  int node4 = i & (NN/4 - 1);
  f4 x = ((const f4*)X)[i];
  f4 sv = ((const f4*)sb)[node4];
  short4 o;
  o.x = f2b(x.x*(1.0f/sv.x)); o.y = f2b(x.y*(1.0f/sv.y));
  o.z = f2b(x.z*(1.0f/sv.z)); o.w = f2b(x.w*(1.0f/sv.w));
  ((short4*)Yt)[i] = o;
}

// ---------------- fused: [attn blocks | gather blocks] (unchanged, r11) ----------------
template<int F, int MODE>
__global__ __launch_bounds__(512, 4) void k_fused(
    const short* __restrict__ Zb, const short* __restrict__ YS, P8s pp, int ksize, int kzbase, int nattn,
    const int* __restrict__ ptr1, const int* __restrict__ cidx1, const float* __restrict__ cval1,
    const int* __restrict__ ptr2, const int* __restrict__ cidx2, const float* __restrict__ cval2,
    const short* __restrict__ g1, const short* __restrict__ g2, const short* __restrict__ gy,
    short* __restrict__ so1, short* __restrict__ so2, float* __restrict__ T)
{
  __shared__ __align__(16) short zk[2][32*64];
  __shared__ __align__(16) short yt[2][256*32];
  __shared__ __align__(16) short p_lds[128*40];
  int t = threadIdx.x;

  if ((int)blockIdx.x < nattn){
    constexpr int NBY = F/256;
    int id = blockIdx.x;
    int bx = id & 63, rest = id >> 6;
    int m0 = bx * 128;
    int n0 = (rest % NBY) * 256;
    int kz = kzbase + rest / NBY;
    int kbeg = kz * ksize, kend = kbeg + ksize;
    int w = t >> 6, l = t & 63;
    int lo = l & 15, g = l >> 4;
    int wm = w >> 2, wn = w & 3;

    const bf16x8* Zb8 = (const bf16x8*)Zb;
    int zirow = m0 + w*16 + lo;
    bf16x8 ziA0 = Zb8[(size_t)zirow*8 + g];
    bf16x8 ziA1 = Zb8[(size_t)zirow*8 + g + 4];

    f32x4 acc[4][4];
    #pragma unroll
    for (int i=0;i<4;i++)
      #pragma unroll
      for (int j=0;j<4;j++) acc[i][j] = (f32x4){0.f,0.f,0.f,0.f};

    auto STAGE = [&](int b, int kk){
      if (t < 256){
        int r = t >> 3, c = t & 7;
        const short* src = Zb + (((size_t)(kk + r)) << 6) + ((c ^ (r & 7)) << 3);
        __builtin_amdgcn_global_load_lds((glb_short*)src, (lds_short*)&zk[b][t*8], 16, 0, 0);
      }
      #pragma unroll
      for (int p=0;p<2;p++){
        int cc = p*512 + t;
        int r = cc >> 2, c = cc & 3;
        const short* src = YS + (size_t)(n0 + r)*NN + kk + ((c ^ ((r >> 1) & 3)) << 3);
        __builtin_amdgcn_global_load_lds((glb_short*)src, (lds_short*)&yt[b][cc*8], 16, 0, 0);
      }
    };

    STAGE(0, kbeg);
    __syncthreads();

    int cur = 0;
    for (int k0 = kbeg; k0 < kend; k0 += 32){
      int xa = g ^ (lo & 7), xb = (g + 4) ^ (lo & 7);
      bf16x8 b00 = *(const bf16x8*)&zk[cur][(lo*8 + xa)*8];
      bf16x8 b01 = *(const bf16x8*)&zk[cur][(lo*8 + xb)*8];
      bf16x8 b10 = *(const bf16x8*)&zk[cur][((16+lo)*8 + xa)*8];
      bf16x8 b11 = *(const bf16x8*)&zk[cur][((16+lo)*8 + xb)*8];
      f32x4 s0 = (f32x4){0.f,0.f,0.f,0.f};
      f32x4 s1 = (f32x4){0.f,0.f,0.f,0.f};
      s0 = __builtin_amdgcn_mfma_f32_16x16x32_bf16(ziA0, b00, s0, 0,0,0);
      s0 = __builtin_amdgcn_mfma_f32_16x16x32_bf16(ziA1, b01, s0, 0,0,0);
      s1 = __builtin_amdgcn_mfma_f32_16x16x32_bf16(ziA0, b10, s1, 0,0,0);
      s1 = __builtin_amdgcn_mfma_f32_16x16x32_bf16(ziA1, b11, s1, 0,0,0);
      short e0[4], e1[4];
      #pragma unroll
      for (int r=0;r<4;r++){
        e0[r] = f2b(__expf(s0[r] - CSHIFT));
        e1[r] = f2b(__expf(s1[r] - CSHIFT));
      }
      __syncthreads();
      if (k0 + 32 < kend) STAGE(cur ^ 1, k0 + 32);
      int prow = w*16 + g*4;
      #pragma unroll
      for (int r=0;r<4;r++){
        p_lds[(prow+r)*40 + lo]      = e0[r];
        p_lds[(prow+r)*40 + 16 + lo] = e1[r];
      }
      __syncthreads();
      bf16x8 aP[4];
      #pragma unroll
      for (int mf=0; mf<4; mf++)
        aP[mf] = *(const bf16x8*)&p_lds[(wm*64 + mf*16 + lo)*40 + g*8];
      __builtin_amdgcn_s_setprio(1);
      #pragma unroll
      for (int nf=0; nf<4; nf++){
        int nl = wn*64 + nf*16 + lo;
        bf16x8 bY = *(const bf16x8*)&yt[cur][(nl*4 + (g ^ ((nl >> 1) & 3)))*8];
        #pragma unroll
        for (int mf=0; mf<4; mf++)
          acc[mf][nf] = __builtin_amdgcn_mfma_f32_16x16x32_bf16(aP[mf], bY, acc[mf][nf], 0,0,0);
      }
      __builtin_amdgcn_s_setprio(0);
      cur ^= 1;
    }
    short* outp = pp.p[kz];
    #pragma unroll
    for (int mf=0; mf<4; mf++){
      int row = m0 + wm*64 + mf*16 + g*4;
      #pragma unroll
      for (int nf=0; nf<4; nf++){
        int col = n0 + wn*64 + nf*16 + lo;
        #pragma unroll
        for (int r=0;r<4;r++)
          outp[(size_t)(row+r)*F + col] = f2b(acc[mf][nf][r]);
      }
    }
  } else {
    constexpr int LPR = F/8;
    constexpr int RPB = 512/LPR;
    int gid = blockIdx.x - nattn;
    int ts = t % LPR, rl = t / LPR;
    if (MODE == 0){
      constexpr int M = NN/RPB;
      int mat = gid / M;
      int blk = gid - mat*M;
      const int*   ptr  = mat ? ptr2  : ptr1;
      const int*   cidx = mat ? cidx2 : cidx1;
      const float* cval = mat ? cval2 : cval1;
      short* outb = mat ? so2 : so1;
      int r = blk*RPB + rl;
      const bf16x8* Y8 = (const bf16x8*)g1;
      int p0 = ptr[r], p1 = ptr[r+1];
      float a[8];
      #pragma unroll
      for (int j=0;j<8;j++) a[j]=0.f;
      int p = p0;
      for (; p+3 < p1; p += 4){
        int   c0=cidx[p], c1=cidx[p+1], c2=cidx[p+2], c3=cidx[p+3];
        float v0=cval[p], v1=cval[p+1], v2=cval[p+2], v3=cval[p+3];
        bf16x8 x0 = Y8[(size_t)c0*LPR + ts];
        bf16x8 x1 = Y8[(size_t)c1*LPR + ts];
        bf16x8 x2 = Y8[(size_t)c2*LPR + ts];
        bf16x8 x3 = Y8[(size_t)c3*LPR + ts];
        #pragma unroll
        for (int j=0;j<8;j++) a[j] += v0*b2f((unsigned short)x0[j]);
        #pragma unroll
        for (int j=0;j<8;j++) a[j] += v1*b2f((unsigned short)x1[j]);
        #pragma unroll
        for (int j=0;j<8;j++) a[j] += v2*b2f((unsigned short)x2[j]);
        #pragma unroll
        for (int j=0;j<8;j++) a[j] += v3*b2f((unsigned short)x3[j]);
      }
      for (; p < p1; ++p){
        int c0 = cidx[p]; float v0 = cval[p];
        bf16x8 x0 = Y8[(size_t)c0*LPR + ts];
        #pragma unroll
        for (int j=0;j<8;j++) a[j] += v0*b2f((unsigned short)x0[j]);
      }
      bf16x8 o;
      #pragma unroll
      for (int j=0;j<8;j++) o[j] = f2b(a[j]);
      ((bf16x8*)outb)[(size_t)r*LPR + ts] = o;
    } else {
      int r = gid*RPB + rl;
      const bf16x8* Xa = (const bf16x8*)g1;
      const bf16x8* Xb = (const bf16x8*)g2;
      float a[8];
      #pragma unroll
      for (int j=0;j<8;j++) a[j]=0.f;
      {
        int p0 = ptr1[r], p1 = ptr1[r+1];
        int p = p0;
        for (; p+3 < p1; p += 4){
          int   c0=cidx1[p], c1=cidx1[p+1], c2=cidx1[p+2], c3=cidx1[p+3];
          float v0=cval1[p], v1=cval1[p+1], v2=cval1[p+2], v3=cval1[p+3];
          bf16x8 x0 = Xa[(size_t)c0*LPR + ts];
          bf16x8 x1 = Xa[(size_t)c1*LPR + ts];
          bf16x8 x2 = Xa[(size_t)c2*LPR + ts];
          bf16x8 x3 = Xa[(size_t)c3*LPR + ts];
          #pragma unroll
          for (int j=0;j<8;j++) a[j] += v0*b2f((unsigned short)x0[j]);
          #pragma unroll
          for (int j=0;j<8;j++) a[j] += v1*b2f((unsigned short)x1[j]);
          #pragma unroll
          for (int j=0;j<8;j++) a[j] += v2*b2f((unsigned short)x2[j]);
          #pragma unroll
          for (int j=0;j<8;j++) a[j] += v3*b2f((unsigned short)x3[j]);
        }
        for (; p < p1; ++p){
          int c0 = cidx1[p]; float v0 = cval1[p];
          bf16x8 x0 = Xa[(size_t)c0*LPR + ts];
          #pragma unroll
          for (int j=0;j<8;j++) a[j] += v0*b2f((unsigned short)x0[j]);
        }
      }
      {
        int p0 = ptr2[r], p1 = ptr2[r+1];
        int p = p0;
        for (; p+3 < p1; p += 4){
          int   c0=cidx2[p], c1=cidx2[p+1], c2=cidx2[p+2], c3=cidx2[p+3];
          float v0=cval2[p], v1=cval2[p+1], v2=cval2[p+2], v3=cval2[p+3];
          bf16x8 x0 = Xb[(size_t)c0*LPR + ts];
          bf16x8 x1 = Xb[(size_t)c1*LPR + ts];
          bf16x8 x2 = Xb[(size_t)c2*LPR + ts];
          bf16x8 x3 = Xb[(size_t)c3*LPR + ts];
          #pragma unroll
          for (int j=0;j<8;j++) a[j] += v0*b2f((unsigned short)x0[j]);
          #pragma unroll
          for (int j=0;j<8;j++) a[j] += v1*b2f((unsigned short)x1[j]);
          #pragma unroll
          for (int j=0;j<8;j++) a[j] += v2*b2f((unsigned short)x2[j]);
          #pragma unroll
          for (int j=0;j<8;j++) a[j] += v3*b2f((unsigned short)x3[j]);
        }
        for (; p < p1; ++p){
          int c0 = cidx2[p]; float v0 = cval2[p];
          bf16x8 x0 = Xb[(size_t)c0*LPR + ts];
          #pragma unroll
          for (int j=0;j<8;j++) a[j] += v0*b2f((unsigned short)x0[j]);
        }
      }
      bf16x8 sa = Xa[(size_t)r*LPR + ts];
      bf16x8 sbv = Xb[(size_t)r*LPR + ts];
      bf16x8 yv = ((const bf16x8*)gy)[(size_t)r*LPR + ts];
      float o[8];
      #pragma unroll
      for (int j=0;j<8;j++)
        o[j] = 2.f*a[j] + b2f((unsigned short)sa[j]) + b2f((unsigned short)sbv[j]) - b2f((unsigned short)yv[j]);
      size_t o4 = ((size_t)r*F + ts*8) >> 2;
      ((f4*)T)[o4]   = (f4){o[0],o[1],o[2],o[3]};
      ((f4*)T)[o4+1] = (f4){o[4],o[5],o[6],o[7]};
    }
  }
}

// ---------------- layer-1 head (MFMA): H = relu((T1+Σp) @ W1), + layer-2 Yt ----------------
// Block: 128 nodes x batch b. A[128][64] bf16 swizzled in LDS; B from W1t[o][k].
__global__ __launch_bounds__(512) void k_headm_mfma(
    const float* __restrict__ T, P8s parts, const short* __restrict__ W1t,
    const float* __restrict__ sbv, short* __restrict__ Hb, short* __restrict__ Yt)
{
  __shared__ __align__(16) short hl[128*136];   // trans tile (34.8 KB); A = first 8192 shorts
  __shared__ float rsl[128];
  int t = threadIdx.x;
  int j0 = blockIdx.x*128, b = blockIdx.y;
  // A fill: 1024 slots (row, 8 chunks of 8), swizzled chunk c ^ (row&7)
  for (int u = t; u < 1024; u += 512){
    int row = u >> 3, c = u & 7;
    size_t base = (size_t)(j0+row)*512 + b*64 + c*8;
    f4 x0 = *(const f4*)(T + base);
    f4 x1 = *(const f4*)(T + base + 4);
    float v[8] = {x0.x,x0.y,x0.z,x0.w,x1.x,x1.y,x1.z,x1.w};
    #pragma unroll
    for (int j=0;j<4;j++){
      bf16x8 p = *(const bf16x8*)(parts.p[j] + base);
      #pragma unroll
      for (int q=0;q<8;q++) v[q] += b2f((unsigned short)p[q]);
    }
    bf16x8 o;
    #pragma unroll
    for (int q=0;q<8;q++) o[q] = f2b(v[q]);
    *(bf16x8*)&hl[(row*8 + (c ^ (row & 7)))*8] = o;
  }
  if (t < 128) rsl[t] = 1.0f / sbv[j0 + t];
  __syncthreads();
  int w = t >> 6, l = t & 63, lo = l & 15, g = l >> 4;
  int arow = w*16 + lo;
  f32x4 acc[8];
  #pragma unroll
  for (int nf=0;nf<8;nf++) acc[nf] = (f32x4){0.f,0.f,0.f,0.f};
  #pragma unroll
  for (int ks=0; ks<2; ks++){
    bf16x8 aA = *(const bf16x8*)&hl[(arow*8 + ((ks*4+g) ^ (arow & 7)))*8];
    #pragma unroll
    for (int nf=0; nf<8; nf++){
      bf16x8 bW = *(const bf16x8*)(W1t + (size_t)(nf*16+lo)*64 + ks*32 + g*8);
      acc[nf] = __builtin_amdgcn_mfma_f32_16x16x32_bf16(aA, bW, acc[nf], 0,0,0);
    }
  }
  __syncthreads();   // all A reads retired; hl reusable
  int m = w*16 + g*4;
  #pragma unroll
  for (int nf=0; nf<8; nf++){
    int o = nf*16 + lo;
    #pragma unroll
    for (int r=0;r<4;r++){
      short hv = f2b(fmaxf(acc[nf][r], 0.f));
      hl[o*136 + m + r] = hv;
      Hb[(size_t)(j0+m+r)*1024 + b*128 + o] = hv;
    }
  }
  __syncthreads();
  // Yt[(b*128+o)][j0+node] = hl[o][node] / s[node]
  for (int u = t; u < 2048; u += 512){
    int o = u >> 4, m8 = (u & 15)*8;
    bf16x8 hv = *(const bf16x8*)&hl[o*136 + m8];
    bf16x8 ov;
    #pragma unroll
    for (int q=0;q<8;q++) ov[q] = f2b(b2f((unsigned short)hv[q]) * rsl[m8+q]);
    *(bf16x8*)(Yt + (size_t)(b*128+o)*NN + j0 + m8) = ov;
  }
}

// ---------------- layer-2 head (MFMA) with fused node-mean ----------------
__global__ __launch_bounds__(512) void k_heads_mfma(
    const float* __restrict__ T, P8s parts, const short* __restrict__ W2t,
    const float* __restrict__ W2unused, float* __restrict__ out)
{
  __shared__ __align__(16) short al[128*16*8];  // A[128][16 chunks] swizzled, 32 KB
  __shared__ float red[8*128];
  int t = threadIdx.x;
  int j0 = blockIdx.x*128, b = blockIdx.y;
  // A fill: 2048 slots (row, 16 chunks of 8), swizzled chunk c ^ (row&7)
  for (int u = t; u < 2048; u += 512){
    int row = u >> 4, c = u & 15;
    size_t base = (size_t)(j0+row)*1024 + b*128 + c*8;
    f4 x0 = *(const f4*)(T + base);
    f4 x1 = *(const f4*)(T + base + 4);
    float v[8] = {x0.x,x0.y,x0.z,x0.w,x1.x,x1.y,x1.z,x1.w};
    #pragma unroll
    for (int j=0;j<2;j++){
      bf16x8 p = *(const bf16x8*)(parts.p[j] + base);
      #pragma unroll
      for (int q=0;q<8;q++) v[q] += b2f((unsigned short)p[q]);
    }
    bf16x8 o;
    #pragma unroll
    for (int q=0;q<8;q++) o[q] = f2b(v[q]);
    *(bf16x8*)&al[(row*16 + (c ^ (row & 7)))*8] = o;
  }
  __syncthreads();
  int w = t >> 6, l = t & 63, lo = l & 15, g = l >> 4;
  int arow = w*16 + lo;
  f32x4 acc[8];
  #pragma unroll
  for (int nf=0;nf<8;nf++) acc[nf] = (f32x4){0.f,0.f,0.f,0.f};
  #pragma unroll
  for (int ks=0; ks<4; ks++){
    bf16x8 aA = *(const bf16x8*)&al[(arow*16 + ((ks*4+g) ^ (arow & 7)))*8];
    #pragma unroll
    for (int nf=0; nf<8; nf++){
      bf16x8 bW = *(const bf16x8*)(W2t + (size_t)(nf*16+lo)*128 + ks*32 + g*8);
      acc[nf] = __builtin_amdgcn_mfma_f32_16x16x32_bf16(aA, bW, acc[nf], 0,0,0);
    }
  }
  // relu + node-sum: reduce over r (4 rows) then g-groups via shfl
  #pragma unroll
  for (int nf=0; nf<8; nf++){
    float s = fmaxf(acc[nf][0],0.f) + fmaxf(acc[nf][1],0.f)
            + fmaxf(acc[nf][2],0.f) + fmaxf(acc[nf][3],0.f);
    s += __shfl_xor(s, 16);
    s += __shfl_xor(s, 32);
    if (g == 0) red[w*128 + nf*16 + lo] = s;
  }
  __syncthreads();
  if (t < 128){
    float tot = 0.f;
    #pragma unroll
    for (int ww=0; ww<8; ww++) tot += red[ww*128 + t];
    atomicAdd(&out[b*128 + t], tot * (1.0f/8192.0f));
  }
}

// ---------------- launcher ----------------
extern "C" void kernel_launch(void* const* d_in, const int* in_sizes, int n_in,
                              void* d_out, int out_size, void* d_ws, size_t ws_size,
                              hipStream_t stream){
  const int*   A1i = (const int*)d_in[0];
  const float* A1v = (const float*)d_in[1];
  const int*   A2i = (const int*)d_in[2];
  const float* A2v = (const float*)d_in[3];
  const float* X   = (const float*)d_in[4];
  const float* Z   = (const float*)d_in[5];
  const float* W1  = (const float*)d_in[6];
  const float* W2  = (const float*)d_in[7];
  float* out = (float*)d_out;

  char* w = (char*)d_ws;
  size_t off = 0;
  auto alloc = [&](size_t b)->char* {
    char* p = w + off;
    off += (b + 1023) & ~(size_t)1023;
    return p;
  };
  const size_t MB = 1024*1024;
  float* sb    = (float*)alloc(NN*4);
  int*   ptr1  = (int*)  alloc((NN+1)*4);
  int*   ptr2  = (int*)  alloc((NN+1)*4);
  int*   cnt   = (int*)  alloc(2*NN*4);
  int*   cur1  = (int*)  alloc(NN*4);
  int*   cur2  = (int*)  alloc(NN*4);
  int*   cidx1 = (int*)  alloc(NNZE*4);
  float* cval1 = (float*)alloc(NNZE*4);
  int*   cidx2 = (int*)  alloc(NNZE*4);
  float* cval2 = (float*)alloc(NNZE*4);
  short* Zbf   = (short*)alloc((size_t)NN*64*2);
  short* W1t   = (short*)alloc(128*64*2);
  short* W2t   = (short*)alloc(128*128*2);
  short* XT1b  = (short*)alloc((size_t)NN*512*2);
  short* BUFA  = (short*)alloc((size_t)NN*1024*2);
  short* BUFB  = (short*)alloc((size_t)NN*1024*2);
  short* HTb   = (short*)alloc((size_t)NN*1024*2);
  short* YS    = (short*)alloc((size_t)NN*1024*2);
  float* T1    = (float*)alloc((size_t)NN*512*4);
  float* T2    = (float*)alloc((size_t)NN*1024*4);
  char*  PART  = alloc((size_t)32*MB);
  (void)ws_size;
  int* cnt1 = cnt;
  int* cnt2 = cnt + NN;

  // CSR build (fused dual-matrix)
  hipMemsetAsync(cnt, 0, 2*NN*4, stream);
  k_count2<<<dim3(NNZE/256, 2), 256, 0, stream>>>(A1i, A2i, cnt1, cnt2);
  k_scan2<<<2, 1024, 0, stream>>>(cnt1, cnt2, ptr1, ptr2, cur1, cur2);
  k_fill2<<<dim3(NNZE/256, 2), 256, 0, stream>>>(A1i, A1v, A2i, A2v, cur1, cur2,
                                                 cidx1, cval1, cidx2, cval2);

  // prep: Z bf16, W transposes, column sums, X^T bf16, Yt1, out zero
  k_zb<<<NN*64/256, 256, 0, stream>>>(Z, Zbf);
  k_wt<<<2, 256, 0, stream>>>(W1, W2, W1t, W2t);
  hipMemsetAsync(sb, 0, NN*4, stream);
  hipMemsetAsync(out, 0, 1024*4, stream);
  k_colsum_mfma<<<dim3(NN/128, 8), 512, 0, stream>>>(Zbf, sb);
  k_transb<512><<<dim3(NN/32, 512/32), 256, 0, stream>>>(X, XT1b);
  k_scaleb<<<512*NN/4/256, 256, 0, stream>>>(X, sb, YS);

  // ---- layer 1 (F=512) ----
  P8s pp1{};
  for (int i=0;i<4;i++) pp1.p[i] = (short*)(PART + (size_t)i*8*MB);
  k_fused<512,0><<<256 + 2048, 512, 0, stream>>>(Zbf, YS, pp1, NN/4, 0, 256,
      ptr1, cidx1, cval1, ptr2, cidx2, cval2,
      XT1b, nullptr, nullptr, BUFA, BUFB, nullptr);
  k_fused<512,1><<<256 + 1024, 512, 0, stream>>>(Zbf, YS, pp1, NN/4, 2, 256,
      ptr1, cidx1, cval1, ptr2, cidx2, cval2,
      BUFA, BUFB, XT1b, nullptr, nullptr, T1);
  k_headm_mfma<<<dim3(NN/128, 8), 512, 0, stream>>>(T1, pp1, W1t, sb, HTb, YS);

  // ---- layer 2 (F=1024) ----
  P8s pp2{};
  pp2.p[0] = (short*)PART;
  pp2.p[1] = (short*)(PART + (size_t)16*MB);
  k_fused<1024,0><<<256 + 4096, 512, 0, stream>>>(Zbf, YS, pp2, NN/2, 0, 256,
      ptr1, cidx1, cval1, ptr2, cidx2, cval2,
      HTb, nullptr, nullptr, BUFA, BUFB, nullptr);
  k_fused<1024,1><<<256 + 2048, 512, 0, stream>>>(Zbf, YS, pp2, NN/2, 1, 256,
      ptr1, cidx1, cval1, ptr2, cidx2, cval2,
      BUFA, BUFB, HTb, nullptr, nullptr, T2);
  k_heads_mfma<<<dim3(NN/128, 8), 512, 0, stream>>>(T2, pp2, W2t, W2, out);
}

// Round 13
// 545.401 us; speedup vs baseline: 2.3919x; 1.0940x over previous
//
#include <hip/hip_runtime.h>

// GWNet on MI355X — round 13.
// - attn loop rebuilt with counted waits (T4): TOP{vmcnt(0)+raw barrier} ->
//   STAGE(next) -> S -> exp -> p_lds -> {lgkm(0)+raw barrier} -> PV.
//   The vm drain moves past the whole PV phase (was: right after issue).
//   Barrier ledger: p_lds rewrite & [cur^1] overwrite race only with
//   iter-(i-1) readers, all retired before TOP_i.
// - XCD-bijective swizzle of attn block ids (T1); gather 8-deep unroll.
// - Rest identical to round 12 (co-scheduled fused, MFMA heads, bf16 partials).

#define NN 8192
#define NNZE 131072
#define CSHIFT 48.0f

typedef float4 f4;
typedef __attribute__((ext_vector_type(8))) short bf16x8;
typedef __attribute__((ext_vector_type(4))) float f32x4;

typedef __attribute__((address_space(3))) short lds_short;
typedef __attribute__((address_space(1))) const short glb_short;

struct P8s { short* p[8]; };

__device__ inline short f2b(float x){
  unsigned u = __float_as_uint(x);
  unsigned r = (u + 0x7fffu + ((u >> 16) & 1u)) >> 16;
  return (short)r;
}
__device__ inline float b2f(unsigned short b){
  return __uint_as_float(((unsigned)b) << 16);
}

// ---------------- CSR build (dual-matrix fused) ----------------
__global__ __launch_bounds__(256) void k_count2(const int* __restrict__ i1, const int* __restrict__ i2,
                                                int* __restrict__ c1, int* __restrict__ c2){
  int e = blockIdx.x*256 + threadIdx.x;
  if (blockIdx.y == 0) atomicAdd(&c1[i1[e]], 1);
  else                 atomicAdd(&c2[i2[e]], 1);
}

__global__ __launch_bounds__(1024) void k_scan2(const int* __restrict__ cnt1, const int* __restrict__ cnt2,
                                                int* __restrict__ ptr1, int* __restrict__ ptr2,
                                                int* __restrict__ cur1, int* __restrict__ cur2){
  __shared__ int sums[1024];
  const int* cnt = blockIdx.x ? cnt2 : cnt1;
  int* ptr = blockIdx.x ? ptr2 : ptr1;
  int* cur = blockIdx.x ? cur2 : cur1;
  int t = threadIdx.x;
  int loc[8]; int s = 0;
  #pragma unroll
  for (int i=0;i<8;i++){ loc[i]=s; s += cnt[t*8+i]; }
  sums[t]=s; __syncthreads();
  for (int off=1; off<1024; off<<=1){
    int v = (t>=off) ? sums[t-off] : 0;
    __syncthreads();
    sums[t] += v;
    __syncthreads();
  }
  int excl = sums[t]-s;
  #pragma unroll
  for (int i=0;i<8;i++){ int v = excl + loc[i]; ptr[t*8+i] = v; cur[t*8+i] = v; }
  if (t==1023) ptr[NN] = sums[1023];
}

__global__ __launch_bounds__(256) void k_fill2(const int* __restrict__ i1, const float* __restrict__ v1,
                                               const int* __restrict__ i2, const float* __restrict__ v2,
                                               int* __restrict__ cur1, int* __restrict__ cur2,
                                               int* __restrict__ cidx1, float* __restrict__ cval1,
                                               int* __restrict__ cidx2, float* __restrict__ cval2){
  int e = blockIdx.x*256 + threadIdx.x;
  const int* idx; const float* vals; int* cur; int* cidx; float* cval;
  if (blockIdx.y == 0){ idx=i1; vals=v1; cur=cur1; cidx=cidx1; cval=cval1; }
  else                { idx=i2; vals=v2; cur=cur2; cidx=cidx2; cval=cval2; }
  int r = idx[e], c = idx[NNZE+e];
  int p = atomicAdd(&cur[r], 1);
  cidx[p] = c; cval[p] = vals[e];
}

// ---------------- transpose X (R,NN)->(NN,R) bf16 ----------------
template<int R>
__global__ __launch_bounds__(256) void k_transb(const float* __restrict__ src, short* __restrict__ dstb){
  __shared__ float tile[32][33];
  int tx = threadIdx.x & 31, ty = threadIdx.x >> 5;
  int j0 = blockIdx.x*32, f0 = blockIdx.y*32;
  #pragma unroll
  for (int u=0;u<32;u+=8) tile[ty+u][tx] = src[(size_t)(f0+ty+u)*NN + j0+tx];
  __syncthreads();
  #pragma unroll
  for (int u=0;u<32;u+=8) dstb[(size_t)(j0+ty+u)*R + f0+tx] = f2b(tile[tx][ty+u]);
}

// ---------------- Z -> bf16 ----------------
__global__ __launch_bounds__(256) void k_zb(const float* __restrict__ Z, short* __restrict__ Zb){
  int i = blockIdx.x*256 + threadIdx.x;
  Zb[i] = f2b(Z[i]);
}

// ---------------- W -> transposed bf16: Wt[o][k] ----------------
__global__ __launch_bounds__(256) void k_wt(const float* __restrict__ W1, const float* __restrict__ W2,
                                            short* __restrict__ W1t, short* __restrict__ W2t){
  int t = threadIdx.x;
  if (blockIdx.x == 0){
    for (int i=t; i<64*128; i+=256){ int k=i>>7, o=i&127; W1t[o*64+k] = f2b(W1[i]); }
  } else {
    for (int i=t; i<128*128; i+=256){ int k=i>>7, o=i&127; W2t[o*128+k] = f2b(W2[i]); }
  }
}

// ---------------- column sums via MFMA: sb[j] = sum_i exp(zi.zj - C) ----------------
__global__ __launch_bounds__(512) void k_colsum_mfma(const short* __restrict__ Zb, float* __restrict__ sb){
  int t = threadIdx.x;
  int w = t >> 6, l = t & 63;
  int lo = l & 15, g = l >> 4;
  int j = blockIdx.x*128 + w*16 + lo;
  const bf16x8* Zb8 = (const bf16x8*)Zb;
  bf16x8 bj0 = Zb8[j*8 + g];
  bf16x8 bj1 = Zb8[j*8 + g + 4];
  int i0 = blockIdx.y * (NN/8);
  float sum = 0.f;
  for (int i = i0; i < i0 + NN/8; i += 16){
    bf16x8 a0 = Zb8[(size_t)(i+lo)*8 + g];
    bf16x8 a1 = Zb8[(size_t)(i+lo)*8 + g + 4];
    f32x4 s = (f32x4){0.f,0.f,0.f,0.f};
    s = __builtin_amdgcn_mfma_f32_16x16x32_bf16(a0, bj0, s, 0,0,0);
    s = __builtin_amdgcn_mfma_f32_16x16x32_bf16(a1, bj1, s, 0,0,0);
    #pragma unroll
    for (int r=0;r<4;r++) sum += __expf(s[r] - CSHIFT);
  }
  sum += __shfl_xor(sum, 16);
  sum += __shfl_xor(sum, 32);
  if (g == 0) atomicAdd(sb + j, sum);
}

// ---------------- layer-1 Yt: Yt[f][node] = bf16(X[f][node] / s[node]) ----------------
__global__ __launch_bounds__(256) void k_scaleb(const float* __restrict__ X, const float* __restrict__ sb,
                                                short* __restrict__ Yt){
  int i = blockIdx.x*256 + threadIdx.x;
  int node4 = i & (NN/4 - 1);
  f4 x = ((const f4*)X)[i];
  f4 sv = ((const f4*)sb)[node4];
  short4 o;
  o.x = f2b(x.x*(1.0f/sv.x)); o.y = f2b(x.y*(1.0f/sv.y));
  o.z = f2b(x.z*(1.0f/sv.z)); o.w = f2b(x.w*(1.0f/sv.w));
  ((short4*)Yt)[i] = o;
}

// ---------------- fused: [attn blocks | gather blocks] ----------------
template<int F, int MODE>
__global__ __launch_bounds__(512, 4) void k_fused(
    const short* __restrict__ Zb, const short* __restrict__ YS, P8s pp, int ksize, int kzbase, int nattn,
    const int* __restrict__ ptr1, const int* __restrict__ cidx1, const float* __restrict__ cval1,
    const int* __restrict__ ptr2, const int* __restrict__ cidx2, const float* __restrict__ cval2,
    const short* __restrict__ g1, const short* __restrict__ g2, const short* __restrict__ gy,
    short* __restrict__ so1, short* __restrict__ so2, float* __restrict__ T)
{
  __shared__ __align__(16) short zk[2][32*64];
  __shared__ __align__(16) short yt[2][256*32];
  __shared__ __align__(16) short p_lds[128*40];
  int t = threadIdx.x;

  if ((int)blockIdx.x < nattn){
    // ================= attention path =================
    constexpr int NBY = F/256;
    int id0 = blockIdx.x;
    int id = (id0 & 7)*32 + (id0 >> 3);          // XCD-bijective swizzle (256 = 8*32)
    int bx = id & 63, rest = id >> 6;
    int m0 = bx * 128;
    int n0 = (rest % NBY) * 256;
    int kz = kzbase + rest / NBY;
    int kbeg = kz * ksize, kend = kbeg + ksize;
    int w = t >> 6, l = t & 63;
    int lo = l & 15, g = l >> 4;
    int wm = w >> 2, wn = w & 3;

    const bf16x8* Zb8 = (const bf16x8*)Zb;
    int zirow = m0 + w*16 + lo;
    bf16x8 ziA0 = Zb8[(size_t)zirow*8 + g];
    bf16x8 ziA1 = Zb8[(size_t)zirow*8 + g + 4];

    f32x4 acc[4][4];
    #pragma unroll
    for (int i=0;i<4;i++)
      #pragma unroll
      for (int j=0;j<4;j++) acc[i][j] = (f32x4){0.f,0.f,0.f,0.f};

    auto STAGE = [&](int b, int kk){
      if (t < 256){
        int r = t >> 3, c = t & 7;
        const short* src = Zb + (((size_t)(kk + r)) << 6) + ((c ^ (r & 7)) << 3);
        __builtin_amdgcn_global_load_lds((glb_short*)src, (lds_short*)&zk[b][t*8], 16, 0, 0);
      }
      #pragma unroll
      for (int p=0;p<2;p++){
        int cc = p*512 + t;
        int r = cc >> 2, c = cc & 3;
        const short* src = YS + (size_t)(n0 + r)*NN + kk + ((c ^ ((r >> 1) & 3)) << 3);
        __builtin_amdgcn_global_load_lds((glb_short*)src, (lds_short*)&yt[b][cc*8], 16, 0, 0);
      }
    };

    STAGE(0, kbeg);

    int cur = 0;
    for (int k0 = kbeg; k0 < kend; k0 += 32){
      // TOP: drain loads for buffer [cur] (issued last iter, covered by its
      // p_lds writes + B2 + PV) and make them visible block-wide. Also
      // retires all iter-(i-1) readers of p_lds and [cur^1].
      asm volatile("s_waitcnt vmcnt(0)" ::: "memory");
      __builtin_amdgcn_s_barrier();
      __builtin_amdgcn_sched_barrier(0);
      if (k0 + 32 < kend) STAGE(cur ^ 1, k0 + 32);   // max cover: rest of iter
      // ---- S phase (reads zk[cur]) ----
      int xa = g ^ (lo & 7), xb = (g + 4) ^ (lo & 7);
      bf16x8 b00 = *(const bf16x8*)&zk[cur][(lo*8 + xa)*8];
      bf16x8 b01 = *(const bf16x8*)&zk[cur][(lo*8 + xb)*8];
      bf16x8 b10 = *(const bf16x8*)&zk[cur][((16+lo)*8 + xa)*8];
      bf16x8 b11 = *(const bf16x8*)&zk[cur][((16+lo)*8 + xb)*8];
      f32x4 s0 = (f32x4){0.f,0.f,0.f,0.f};
      f32x4 s1 = (f32x4){0.f,0.f,0.f,0.f};
      s0 = __builtin_amdgcn_mfma_f32_16x16x32_bf16(ziA0, b00, s0, 0,0,0);
      s0 = __builtin_amdgcn_mfma_f32_16x16x32_bf16(ziA1, b01, s0, 0,0,0);
      s1 = __builtin_amdgcn_mfma_f32_16x16x32_bf16(ziA0, b10, s1, 0,0,0);
      s1 = __builtin_amdgcn_mfma_f32_16x16x32_bf16(ziA1, b11, s1, 0,0,0);
      int prow = w*16 + g*4;
      #pragma unroll
      for (int r=0;r<4;r++){
        p_lds[(prow+r)*40 + lo]      = f2b(__expf(s0[r] - CSHIFT));
        p_lds[(prow+r)*40 + 16 + lo] = f2b(__expf(s1[r] - CSHIFT));
      }
      // B2: p_lds writes visible (lgkm only — vm loads stay in flight)
      asm volatile("s_waitcnt lgkmcnt(0)" ::: "memory");
      __builtin_amdgcn_s_barrier();
      // ---- PV phase (reads p_lds + yt[cur]) ----
      bf16x8 aP[4];
      #pragma unroll
      for (int mf=0; mf<4; mf++)
        aP[mf] = *(const bf16x8*)&p_lds[(wm*64 + mf*16 + lo)*40 + g*8];
      __builtin_amdgcn_s_setprio(1);
      #pragma unroll
      for (int nf=0; nf<4; nf++){
        int nl = wn*64 + nf*16 + lo;
        bf16x8 bY = *(const bf16x8*)&yt[cur][(nl*4 + (g ^ ((nl >> 1) & 3)))*8];
        #pragma unroll
        for (int mf=0; mf<4; mf++)
          acc[mf][nf] = __builtin_amdgcn_mfma_f32_16x16x32_bf16(aP[mf], bY, acc[mf][nf], 0,0,0);
      }
      __builtin_amdgcn_s_setprio(0);
      cur ^= 1;
    }
    short* outp = pp.p[kz];
    #pragma unroll
    for (int mf=0; mf<4; mf++){
      int row = m0 + wm*64 + mf*16 + g*4;
      #pragma unroll
      for (int nf=0; nf<4; nf++){
        int col = n0 + wn*64 + nf*16 + lo;
        #pragma unroll
        for (int r=0;r<4;r++)
          outp[(size_t)(row+r)*F + col] = f2b(acc[mf][nf][r]);
      }
    }
  } else {
    // ================= gather path (8-deep unroll) =================
    constexpr int LPR = F/8;
    constexpr int RPB = 512/LPR;
    int gid = blockIdx.x - nattn;
    int ts = t % LPR, rl = t / LPR;
    if (MODE == 0){
      constexpr int M = NN/RPB;
      int mat = gid / M;
      int blk = gid - mat*M;
      const int*   ptr  = mat ? ptr2  : ptr1;
      const int*   cidx = mat ? cidx2 : cidx1;
      const float* cval = mat ? cval2 : cval1;
      short* outb = mat ? so2 : so1;
      int r = blk*RPB + rl;
      const bf16x8* Y8 = (const bf16x8*)g1;
      int p0 = ptr[r], p1 = ptr[r+1];
      float a[8];
      #pragma unroll
      for (int j=0;j<8;j++) a[j]=0.f;
      int p = p0;
      for (; p+7 < p1; p += 8){
        int   c[8]; float v[8]; bf16x8 x[8];
        #pragma unroll
        for (int q=0;q<8;q++){ c[q]=cidx[p+q]; v[q]=cval[p+q]; }
        #pragma unroll
        for (int q=0;q<8;q++) x[q] = Y8[(size_t)c[q]*LPR + ts];
        #pragma unroll
        for (int q=0;q<8;q++)
          #pragma unroll
          for (int j=0;j<8;j++) a[j] += v[q]*b2f((unsigned short)x[q][j]);
      }
      for (; p < p1; ++p){
        int c0 = cidx[p]; float v0 = cval[p];
        bf16x8 x0 = Y8[(size_t)c0*LPR + ts];
        #pragma unroll
        for (int j=0;j<8;j++) a[j] += v0*b2f((unsigned short)x0[j]);
      }
      bf16x8 o;
      #pragma unroll
      for (int j=0;j<8;j++) o[j] = f2b(a[j]);
      ((bf16x8*)outb)[(size_t)r*LPR + ts] = o;
    } else {
      int r = gid*RPB + rl;
      const bf16x8* Xa = (const bf16x8*)g1;
      const bf16x8* Xb = (const bf16x8*)g2;
      float a[8];
      #pragma unroll
      for (int j=0;j<8;j++) a[j]=0.f;
      {
        int p0 = ptr1[r], p1 = ptr1[r+1];
        int p = p0;
        for (; p+7 < p1; p += 8){
          int   c[8]; float v[8]; bf16x8 x[8];
          #pragma unroll
          for (int q=0;q<8;q++){ c[q]=cidx1[p+q]; v[q]=cval1[p+q]; }
          #pragma unroll
          for (int q=0;q<8;q++) x[q] = Xa[(size_t)c[q]*LPR + ts];
          #pragma unroll
          for (int q=0;q<8;q++)
            #pragma unroll
            for (int j=0;j<8;j++) a[j] += v[q]*b2f((unsigned short)x[q][j]);
        }
        for (; p < p1; ++p){
          int c0 = cidx1[p]; float v0 = cval1[p];
          bf16x8 x0 = Xa[(size_t)c0*LPR + ts];
          #pragma unroll
          for (int j=0;j<8;j++) a[j] += v0*b2f((unsigned short)x0[j]);
        }
      }
      {
        int p0 = ptr2[r], p1 = ptr2[r+1];
        int p = p0;
        for (; p+7 < p1; p += 8){
          int   c[8]; float v[8]; bf16x8 x[8];
          #pragma unroll
          for (int q=0;q<8;q++){ c[q]=cidx2[p+q]; v[q]=cval2[p+q]; }
          #pragma unroll
          for (int q=0;q<8;q++) x[q] = Xb[(size_t)c[q]*LPR + ts];
          #pragma unroll
          for (int q=0;q<8;q++)
            #pragma unroll
            for (int j=0;j<8;j++) a[j] += v[q]*b2f((unsigned short)x[q][j]);
        }
        for (; p < p1; ++p){
          int c0 = cidx2[p]; float v0 = cval2[p];
          bf16x8 x0 = Xb[(size_t)c0*LPR + ts];
          #pragma unroll
          for (int j=0;j<8;j++) a[j] += v0*b2f((unsigned short)x0[j]);
        }
      }
      bf16x8 sa = Xa[(size_t)r*LPR + ts];
      bf16x8 sbv = Xb[(size_t)r*LPR + ts];
      bf16x8 yv = ((const bf16x8*)gy)[(size_t)r*LPR + ts];
      float o[8];
      #pragma unroll
      for (int j=0;j<8;j++)
        o[j] = 2.f*a[j] + b2f((unsigned short)sa[j]) + b2f((unsigned short)sbv[j]) - b2f((unsigned short)yv[j]);
      size_t o4 = ((size_t)r*F + ts*8) >> 2;
      ((f4*)T)[o4]   = (f4){o[0],o[1],o[2],o[3]};
      ((f4*)T)[o4+1] = (f4){o[4],o[5],o[6],o[7]};
    }
  }
}

// ---------------- layer-1 head (MFMA): H = relu((T1+Σp) @ W1), + layer-2 Yt ----------------
__global__ __launch_bounds__(512) void k_headm_mfma(
    const float* __restrict__ T, P8s parts, const short* __restrict__ W1t,
    const float* __restrict__ sbv, short* __restrict__ Hb, short* __restrict__ Yt)
{
  __shared__ __align__(16) short hl[128*136];
  __shared__ float rsl[128];
  int t = threadIdx.x;
  int j0 = blockIdx.x*128, b = blockIdx.y;
  for (int u = t; u < 1024; u += 512){
    int row = u >> 3, c = u & 7;
    size_t base = (size_t)(j0+row)*512 + b*64 + c*8;
    f4 x0 = *(const f4*)(T + base);
    f4 x1 = *(const f4*)(T + base + 4);
    float v[8] = {x0.x,x0.y,x0.z,x0.w,x1.x,x1.y,x1.z,x1.w};
    #pragma unroll
    for (int j=0;j<4;j++){
      bf16x8 p = *(const bf16x8*)(parts.p[j] + base);
      #pragma unroll
      for (int q=0;q<8;q++) v[q] += b2f((unsigned short)p[q]);
    }
    bf16x8 o;
    #pragma unroll
    for (int q=0;q<8;q++) o[q] = f2b(v[q]);
    *(bf16x8*)&hl[(row*8 + (c ^ (row & 7)))*8] = o;
  }
  if (t < 128) rsl[t] = 1.0f / sbv[j0 + t];
  __syncthreads();
  int w = t >> 6, l = t & 63, lo = l & 15, g = l >> 4;
  int arow = w*16 + lo;
  f32x4 acc[8];
  #pragma unroll
  for (int nf=0;nf<8;nf++) acc[nf] = (f32x4){0.f,0.f,0.f,0.f};
  #pragma unroll
  for (int ks=0; ks<2; ks++){
    bf16x8 aA = *(const bf16x8*)&hl[(arow*8 + ((ks*4+g) ^ (arow & 7)))*8];
    #pragma unroll
    for (int nf=0; nf<8; nf++){
      bf16x8 bW = *(const bf16x8*)(W1t + (size_t)(nf*16+lo)*64 + ks*32 + g*8);
      acc[nf] = __builtin_amdgcn_mfma_f32_16x16x32_bf16(aA, bW, acc[nf], 0,0,0);
    }
  }
  __syncthreads();
  int m = w*16 + g*4;
  #pragma unroll
  for (int nf=0; nf<8; nf++){
    int o = nf*16 + lo;
    #pragma unroll
    for (int r=0;r<4;r++){
      short hv = f2b(fmaxf(acc[nf][r], 0.f));
      hl[o*136 + m + r] = hv;
      Hb[(size_t)(j0+m+r)*1024 + b*128 + o] = hv;
    }
  }
  __syncthreads();
  for (int u = t; u < 2048; u += 512){
    int o = u >> 4, m8 = (u & 15)*8;
    bf16x8 hv = *(const bf16x8*)&hl[o*136 + m8];
    bf16x8 ov;
    #pragma unroll
    for (int q=0;q<8;q++) ov[q] = f2b(b2f((unsigned short)hv[q]) * rsl[m8+q]);
    *(bf16x8*)(Yt + (size_t)(b*128+o)*NN + j0 + m8) = ov;
  }
}

// ---------------- layer-2 head (MFMA) with fused node-mean ----------------
__global__ __launch_bounds__(512) void k_heads_mfma(
    const float* __restrict__ T, P8s parts, const short* __restrict__ W2t,
    const float* __restrict__ W2unused, float* __restrict__ out)
{
  __shared__ __align__(16) short al[128*16*8];
  __shared__ float red[8*128];
  int t = threadIdx.x;
  int j0 = blockIdx.x*128, b = blockIdx.y;
  for (int u = t; u < 2048; u += 512){
    int row = u >> 4, c = u & 15;
    size_t base = (size_t)(j0+row)*1024 + b*128 + c*8;
    f4 x0 = *(const f4*)(T + base);
    f4 x1 = *(const f4*)(T + base + 4);
    float v[8] = {x0.x,x0.y,x0.z,x0.w,x1.x,x1.y,x1.z,x1.w};
    #pragma unroll
    for (int j=0;j<2;j++){
      bf16x8 p = *(const bf16x8*)(parts.p[j] + base);
      #pragma unroll
      for (int q=0;q<8;q++) v[q] += b2f((unsigned short)p[q]);
    }
    bf16x8 o;
    #pragma unroll
    for (int q=0;q<8;q++) o[q] = f2b(v[q]);
    *(bf16x8*)&al[(row*16 + (c ^ (row & 7)))*8] = o;
  }
  __syncthreads();
  int w = t >> 6, l = t & 63, lo = l & 15, g = l >> 4;
  int arow = w*16 + lo;
  f32x4 acc[8];
  #pragma unroll
  for (int nf=0;nf<8;nf++) acc[nf] = (f32x4){0.f,0.f,0.f,0.f};
  #pragma unroll
  for (int ks=0; ks<4; ks++){
    bf16x8 aA = *(const bf16x8*)&al[(arow*16 + ((ks*4+g) ^ (arow & 7)))*8];
    #pragma unroll
    for (int nf=0; nf<8; nf++){
      bf16x8 bW = *(const bf16x8*)(W2t + (size_t)(nf*16+lo)*128 + ks*32 + g*8);
      acc[nf] = __builtin_amdgcn_mfma_f32_16x16x32_bf16(aA, bW, acc[nf], 0,0,0);
    }
  }
  #pragma unroll
  for (int nf=0; nf<8; nf++){
    float s = fmaxf(acc[nf][0],0.f) + fmaxf(acc[nf][1],0.f)
            + fmaxf(acc[nf][2],0.f) + fmaxf(acc[nf][3],0.f);
    s += __shfl_xor(s, 16);
    s += __shfl_xor(s, 32);
    if (g == 0) red[w*128 + nf*16 + lo] = s;
  }
  __syncthreads();
  if (t < 128){
    float tot = 0.f;
    #pragma unroll
    for (int ww=0; ww<8; ww++) tot += red[ww*128 + t];
    atomicAdd(&out[b*128 + t], tot * (1.0f/8192.0f));
  }
}

// ---------------- launcher ----------------
extern "C" void kernel_launch(void* const* d_in, const int* in_sizes, int n_in,
                              void* d_out, int out_size, void* d_ws, size_t ws_size,
                              hipStream_t stream){
  const int*   A1i = (const int*)d_in[0];
  const float* A1v = (const float*)d_in[1];
  const int*   A2i = (const int*)d_in[2];
  const float* A2v = (const float*)d_in[3];
  const float* X   = (const float*)d_in[4];
  const float* Z   = (const float*)d_in[5];
  const float* W1  = (const float*)d_in[6];
  const float* W2  = (const float*)d_in[7];
  float* out = (float*)d_out;

  char* w = (char*)d_ws;
  size_t off = 0;
  auto alloc = [&](size_t b)->char* {
    char* p = w + off;
    off += (b + 1023) & ~(size_t)1023;
    return p;
  };
  const size_t MB = 1024*1024;
  float* sb    = (float*)alloc(NN*4);
  int*   ptr1  = (int*)  alloc((NN+1)*4);
  int*   ptr2  = (int*)  alloc((NN+1)*4);
  int*   cnt   = (int*)  alloc(2*NN*4);
  int*   cur1  = (int*)  alloc(NN*4);
  int*   cur2  = (int*)  alloc(NN*4);
  int*   cidx1 = (int*)  alloc(NNZE*4);
  float* cval1 = (float*)alloc(NNZE*4);
  int*   cidx2 = (int*)  alloc(NNZE*4);
  float* cval2 = (float*)alloc(NNZE*4);
  short* Zbf   = (short*)alloc((size_t)NN*64*2);
  short* W1t   = (short*)alloc(128*64*2);
  short* W2t   = (short*)alloc(128*128*2);
  short* XT1b  = (short*)alloc((size_t)NN*512*2);
  short* BUFA  = (short*)alloc((size_t)NN*1024*2);
  short* BUFB  = (short*)alloc((size_t)NN*1024*2);
  short* HTb   = (short*)alloc((size_t)NN*1024*2);
  short* YS    = (short*)alloc((size_t)NN*1024*2);
  float* T1    = (float*)alloc((size_t)NN*512*4);
  float* T2    = (float*)alloc((size_t)NN*1024*4);
  char*  PART  = alloc((size_t)32*MB);
  (void)ws_size;
  int* cnt1 = cnt;
  int* cnt2 = cnt + NN;

  // CSR build (fused dual-matrix)
  hipMemsetAsync(cnt, 0, 2*NN*4, stream);
  k_count2<<<dim3(NNZE/256, 2), 256, 0, stream>>>(A1i, A2i, cnt1, cnt2);
  k_scan2<<<2, 1024, 0, stream>>>(cnt1, cnt2, ptr1, ptr2, cur1, cur2);
  k_fill2<<<dim3(NNZE/256, 2), 256, 0, stream>>>(A1i, A1v, A2i, A2v, cur1, cur2,
                                                 cidx1, cval1, cidx2, cval2);

  // prep
  k_zb<<<NN*64/256, 256, 0, stream>>>(Z, Zbf);
  k_wt<<<2, 256, 0, stream>>>(W1, W2, W1t, W2t);
  hipMemsetAsync(sb, 0, NN*4, stream);
  hipMemsetAsync(out, 0, 1024*4, stream);
  k_colsum_mfma<<<dim3(NN/128, 8), 512, 0, stream>>>(Zbf, sb);
  k_transb<512><<<dim3(NN/32, 512/32), 256, 0, stream>>>(X, XT1b);
  k_scaleb<<<512*NN/4/256, 256, 0, stream>>>(X, sb, YS);

  // ---- layer 1 (F=512) ----
  P8s pp1{};
  for (int i=0;i<4;i++) pp1.p[i] = (short*)(PART + (size_t)i*8*MB);
  k_fused<512,0><<<256 + 2048, 512, 0, stream>>>(Zbf, YS, pp1, NN/4, 0, 256,
      ptr1, cidx1, cval1, ptr2, cidx2, cval2,
      XT1b, nullptr, nullptr, BUFA, BUFB, nullptr);
  k_fused<512,1><<<256 + 1024, 512, 0, stream>>>(Zbf, YS, pp1, NN/4, 2, 256,
      ptr1, cidx1, cval1, ptr2, cidx2, cval2,
      BUFA, BUFB, XT1b, nullptr, nullptr, T1);
  k_headm_mfma<<<dim3(NN/128, 8), 512, 0, stream>>>(T1, pp1, W1t, sb, HTb, YS);

  // ---- layer 2 (F=1024) ----
  P8s pp2{};
  pp2.p[0] = (short*)PART;
  pp2.p[1] = (short*)(PART + (size_t)16*MB);
  k_fused<1024,0><<<256 + 4096, 512, 0, stream>>>(Zbf, YS, pp2, NN/2, 0, 256,
      ptr1, cidx1, cval1, ptr2, cidx2, cval2,
      HTb, nullptr, nullptr, BUFA, BUFB, nullptr);
  k_fused<1024,1><<<256 + 2048, 512, 0, stream>>>(Zbf, YS, pp2, NN/2, 1, 256,
      ptr1, cidx1, cval1, ptr2, cidx2, cval2,
      BUFA, BUFB, HTb, nullptr, nullptr, T2);
  k_heads_mfma<<<dim3(NN/128, 8), 512, 0, stream>>>(T2, pp2, W2t, W2, out);
}